// Round 1
// baseline (2644.674 us; speedup 1.0000x reference)
//
#include <hip/hip_runtime.h>
#include <cstddef>
#include <cstdint>

constexpr int ND = 30000, NG = 60000, NS = 15000;
constexpr float BN_EPS = 1e-5f;

static inline int cdiv(int a, int b){ return (a + b - 1) / b; }

// ---------------- CSR construction ----------------

__global__ __launch_bounds__(256) void count_k(const int* __restrict__ dst, int E, int* __restrict__ cnt){
    int e = blockIdx.x * 256 + threadIdx.x;
    if (e < E) atomicAdd(&cnt[dst[e]], 1);
}

__global__ __launch_bounds__(256) void scan1_k(const int* __restrict__ cnt, int N, int* __restrict__ partials){
    __shared__ int sh[256];
    int tid = threadIdx.x;
    int base = blockIdx.x * 1024 + tid * 4;
    int s = 0;
    #pragma unroll
    for (int j = 0; j < 4; j++) if (base + j < N) s += cnt[base + j];
    sh[tid] = s; __syncthreads();
    for (int d = 128; d > 0; d >>= 1){
        if (tid < d) sh[tid] += sh[tid + d];
        __syncthreads();
    }
    if (tid == 0) partials[blockIdx.x] = sh[0];
}

__global__ void scan2_k(int* partials, int B, int* offs, int N){
    if (threadIdx.x == 0 && blockIdx.x == 0){
        int run = 0;
        for (int i = 0; i < B; i++){ int t = partials[i]; partials[i] = run; run += t; }
        offs[N] = run;
    }
}

__global__ __launch_bounds__(256) void scan3_k(const int* __restrict__ cnt, const int* __restrict__ partials,
                                               int* __restrict__ offs, int* __restrict__ cursor, int N){
    __shared__ int sh[256];
    int tid = threadIdx.x;
    int base = blockIdx.x * 1024 + tid * 4;
    int c[4]; int s = 0;
    #pragma unroll
    for (int j = 0; j < 4; j++){ c[j] = (base + j < N) ? cnt[base + j] : 0; s += c[j]; }
    sh[tid] = s; __syncthreads();
    for (int d = 1; d < 256; d <<= 1){
        int v = sh[tid];
        int add = (tid >= d) ? sh[tid - d] : 0;
        __syncthreads();
        sh[tid] = v + add;
        __syncthreads();
    }
    int excl = sh[tid] - s;
    int run = partials[blockIdx.x] + excl;
    #pragma unroll
    for (int j = 0; j < 4; j++){
        if (base + j < N){ offs[base + j] = run; cursor[base + j] = run; run += c[j]; }
    }
}

__global__ __launch_bounds__(256) void fill_k(const int* __restrict__ src, const int* __restrict__ dst, int E,
                                              int* __restrict__ cursor, int* __restrict__ csr){
    int e = blockIdx.x * 256 + threadIdx.x;
    if (e < E){
        int d = dst[e];
        int pos = atomicAdd(&cursor[d], 1);
        csr[pos] = src[e];
    }
}

// ---------------- gather-mean: A[node*256 + colOff + c] = mean_{j in N(node)} h[src_j][c] ----------------

__global__ __launch_bounds__(256) void gather_k(const float* __restrict__ h, const int* __restrict__ csr,
                                                const int* __restrict__ offs, float* __restrict__ A,
                                                int N, int colOff){
    int node = blockIdx.x * 2 + (threadIdx.x >> 7);
    int c = threadIdx.x & 127;
    if (node >= N) return;
    int s = offs[node], e = offs[node + 1];
    float acc = 0.f;
    for (int j = s; j < e; ++j){
        int si = csr[j];
        acc += h[(size_t)si * 128 + c];
    }
    float inv = (e > s) ? 1.0f / (float)(e - s) : 0.f;
    A[(size_t)node * 256 + colOff + c] = acc * inv;
}

// ---------------- W_cat build: [Wl_e1 ; Wl_e2 ; Wr_e1 + Wr_e2] per (layer, dst type) ----------------

__global__ __launch_bounds__(256) void wcat_k(const float* __restrict__ Wl, const float* __restrict__ Wr,
                                              float* __restrict__ Wcat){
    int idx = blockIdx.x * 256 + threadIdx.x;
    constexpr int TOT = 9 * 384 * 128;
    if (idx >= TOT) return;
    int g = idx / (384 * 128);
    int rem = idx - g * (384 * 128);
    int k = rem >> 7;
    int c = rem & 127;
    int L = g / 3, t = g - L * 3;
    const int e1s[3] = {1, 0, 2}, e2s[3] = {5, 3, 4};
    int e1 = e1s[t], e2 = e2s[t];
    float v;
    if (k < 128)      v = Wl[(((size_t)L * 6 + e1) * 128 + k) * 128 + c];
    else if (k < 256) v = Wl[(((size_t)L * 6 + e2) * 128 + (k - 128)) * 128 + c];
    else {
        int kr = k - 256;
        v = Wr[(((size_t)L * 6 + e1) * 128 + kr) * 128 + c]
          + Wr[(((size_t)L * 6 + e2) * 128 + kr) * 128 + c];
    }
    Wcat[idx] = v;
}

// ---------------- GEMM: out = scale * (A @ W + b1 + b2), dual A-source split at ksplit ----------------
// A1: N x lda1 (k < ksplit), A2: N x lda2 (k >= ksplit). W: K x NCOL row-major. 64-row x NCOL tile / block.

template<int NCOL>
__global__ __launch_bounds__(256) void gemm_k(const float* __restrict__ A1, int lda1,
                                              const float* __restrict__ A2, int lda2, int ksplit,
                                              const float* __restrict__ W,
                                              const float* __restrict__ b1, const float* __restrict__ b2,
                                              float* __restrict__ out, int ldo,
                                              int N, int K, float scale){
    __shared__ float As[64][33];
    __shared__ float Ws[32][NCOL];
    constexpr int CG  = NCOL / 8;          // col groups (8 cols each)
    constexpr int RPT = (64 * CG) / 256;   // rows per thread: 4 (NCOL=128), 2 (NCOL=64)
    int tid  = threadIdx.x;
    int row0 = blockIdx.x * 64;
    int tcol = tid % CG;
    int trow = tid / CG;
    float acc[RPT][8];
    #pragma unroll
    for (int i = 0; i < RPT; i++)
        #pragma unroll
        for (int j = 0; j < 8; j++) acc[i][j] = 0.f;

    for (int k0 = 0; k0 < K; k0 += 32){
        const float* Ab; int lda, kloc;
        if (k0 < ksplit){ Ab = A1; lda = lda1; kloc = k0; }
        else            { Ab = A2; lda = lda2; kloc = k0 - ksplit; }
        // stage A tile 64x32
        #pragma unroll
        for (int t = 0; t < 2; t++){
            int f  = tid + t * 256;
            int r  = f >> 3;
            int c4 = (f & 7) * 4;
            int gr = row0 + r;
            float4 v = make_float4(0.f, 0.f, 0.f, 0.f);
            if (gr < N) v = *reinterpret_cast<const float4*>(Ab + (size_t)gr * lda + kloc + c4);
            As[r][c4 + 0] = v.x; As[r][c4 + 1] = v.y; As[r][c4 + 2] = v.z; As[r][c4 + 3] = v.w;
        }
        // stage W tile 32xNCOL
        constexpr int WF4 = (32 * NCOL) / (4 * 256);
        #pragma unroll
        for (int t = 0; t < WF4; t++){
            int f  = tid + t * 256;
            int kr = f / (NCOL / 4);
            int c4 = (f % (NCOL / 4)) * 4;
            float4 v = *reinterpret_cast<const float4*>(W + (size_t)(k0 + kr) * NCOL + c4);
            *reinterpret_cast<float4*>(&Ws[kr][c4]) = v;
        }
        __syncthreads();
        #pragma unroll
        for (int kk = 0; kk < 32; kk++){
            float a[RPT];
            #pragma unroll
            for (int i = 0; i < RPT; i++) a[i] = As[trow * RPT + i][kk];
            float4 w0 = *reinterpret_cast<const float4*>(&Ws[kk][tcol * 8]);
            float4 w1 = *reinterpret_cast<const float4*>(&Ws[kk][tcol * 8 + 4]);
            float bv[8] = {w0.x, w0.y, w0.z, w0.w, w1.x, w1.y, w1.z, w1.w};
            #pragma unroll
            for (int i = 0; i < RPT; i++)
                #pragma unroll
                for (int j = 0; j < 8; j++)
                    acc[i][j] = fmaf(a[i], bv[j], acc[i][j]);
        }
        __syncthreads();
    }
    float bias[8];
    #pragma unroll
    for (int j = 0; j < 8; j++){
        float bb = 0.f;
        if (b1) bb += b1[tcol * 8 + j];
        if (b2) bb += b2[tcol * 8 + j];
        bias[j] = bb;
    }
    #pragma unroll
    for (int i = 0; i < RPT; i++){
        int gr = row0 + trow * RPT + i;
        if (gr < N){
            float4 r0, r1;
            r0.x = scale * (acc[i][0] + bias[0]);
            r0.y = scale * (acc[i][1] + bias[1]);
            r0.z = scale * (acc[i][2] + bias[2]);
            r0.w = scale * (acc[i][3] + bias[3]);
            r1.x = scale * (acc[i][4] + bias[4]);
            r1.y = scale * (acc[i][5] + bias[5]);
            r1.z = scale * (acc[i][6] + bias[6]);
            r1.w = scale * (acc[i][7] + bias[7]);
            *reinterpret_cast<float4*>(out + (size_t)gr * ldo + tcol * 8)     = r0;
            *reinterpret_cast<float4*>(out + (size_t)gr * ldo + tcol * 8 + 4) = r1;
        }
    }
}

// ---------------- column stats (sum, sumsq) ----------------

__global__ __launch_bounds__(128) void stats_k(const float* __restrict__ o, int N, float* __restrict__ stats){
    int c = threadIdx.x;
    float s = 0.f, q = 0.f;
    for (int r = blockIdx.x; r < N; r += gridDim.x){
        float v = o[(size_t)r * 128 + c];
        s += v; q += v * v;
    }
    atomicAdd(&stats[c], s);
    atomicAdd(&stats[128 + c], q);
}

// ---------------- BN apply + ReLU (+ residual), writes h ----------------

__global__ __launch_bounds__(256) void bn_k(const float* __restrict__ o, const float* __restrict__ stats,
                                            const float* __restrict__ g, const float* __restrict__ b,
                                            float* __restrict__ h, int N, float invN, int residual){
    int idx = blockIdx.x * 256 + threadIdx.x;
    if (idx >= N * 32) return;
    int n  = idx >> 5;
    int c4 = (idx & 31) * 4;
    float4 ov = *reinterpret_cast<const float4*>(o + (size_t)n * 128 + c4);
    float4 sv = *reinterpret_cast<const float4*>(stats + c4);
    float4 qv = *reinterpret_cast<const float4*>(stats + 128 + c4);
    float4 gv = *reinterpret_cast<const float4*>(g + c4);
    float4 bv = *reinterpret_cast<const float4*>(b + c4);
    auto f1 = [&](float o_, float s_, float q_, float g_, float b_) -> float {
        float mu  = s_ * invN;
        float var = q_ * invN - mu * mu;
        float r = (o_ - mu) * rsqrtf(var + BN_EPS) * g_ + b_;
        return r > 0.f ? r : 0.f;
    };
    float4 res;
    res.x = f1(ov.x, sv.x, qv.x, gv.x, bv.x);
    res.y = f1(ov.y, sv.y, qv.y, gv.y, bv.y);
    res.z = f1(ov.z, sv.z, qv.z, gv.z, bv.z);
    res.w = f1(ov.w, sv.w, qv.w, gv.w, bv.w);
    float* hp = h + (size_t)n * 128 + c4;
    if (residual){
        float4 hv = *reinterpret_cast<const float4*>(hp);
        res.x += hv.x; res.y += hv.y; res.z += hv.z; res.w += hv.w;
    }
    *reinterpret_cast<float4*>(hp) = res;
}

// ---------------- host orchestration ----------------

extern "C" void kernel_launch(void* const* d_in, const int* in_sizes, int n_in,
                              void* d_out, int out_size, void* d_ws, size_t ws_size,
                              hipStream_t stream){
    const float* x_drug = (const float*)d_in[0];
    const float* x_gene = (const float*)d_in[1];
    const float* x_dis  = (const float*)d_in[2];
    const int* srcP[6] = {(const int*)d_in[3], (const int*)d_in[5], (const int*)d_in[7],
                          (const int*)d_in[9], (const int*)d_in[11], (const int*)d_in[13]};
    const int* dstP[6] = {(const int*)d_in[4], (const int*)d_in[6], (const int*)d_in[8],
                          (const int*)d_in[10], (const int*)d_in[12], (const int*)d_in[14]};
    const int  Et[6]   = {in_sizes[3], in_sizes[5], in_sizes[7], in_sizes[9], in_sizes[11], in_sizes[13]};
    const float* W_in[3] = {(const float*)d_in[15], (const float*)d_in[17], (const float*)d_in[19]};
    const float* b_in[3] = {(const float*)d_in[16], (const float*)d_in[18], (const float*)d_in[20]};
    const float* g_in  = (const float*)d_in[21];
    const float* bt_in = (const float*)d_in[22];
    const float* Wl    = (const float*)d_in[23];
    const float* Wr    = (const float*)d_in[24];
    const float* bl    = (const float*)d_in[25];
    const float* g_conv  = (const float*)d_in[26];
    const float* bt_conv = (const float*)d_in[27];
    const float* W_fin = (const float*)d_in[28];
    const float* b_fin = (const float*)d_in[29];
    float* out = (float*)d_out;

    // edge-type metadata (order: dg, gd, gs, sg, ds, sd)
    const int Ndst_t[6]   = {NG, ND, NS, NG, NS, ND};
    const int srcT[6]     = {0, 1, 1, 2, 0, 2};
    const int dstT[6]     = {1, 0, 2, 1, 2, 0};
    const int colOff_t[6] = {0, 0, 0, 128, 128, 128};

    // ---- workspace carve (floats first, then ints) ----
    float* base = (float*)d_ws;
    size_t off = 0;
    auto allocf = [&](size_t n){ float* p = base + off; off += (n + 63) & ~(size_t)63; return p; };
    float* h[3]; h[0] = allocf((size_t)ND * 128); h[1] = allocf((size_t)NG * 128); h[2] = allocf((size_t)NS * 128);
    float* A[3]; A[0] = allocf((size_t)ND * 256); A[1] = allocf((size_t)NG * 256); A[2] = allocf((size_t)NS * 256);
    float* o    = allocf((size_t)NG * 128);
    float* Wcat = allocf((size_t)9 * 384 * 128);
    float* stats = allocf(12 * 256);
    int* ibase = (int*)(base + off);
    size_t ioff = 0;
    auto alloci = [&](size_t n){ int* p = ibase + ioff; ioff += (n + 63) & ~(size_t)63; return p; };
    int *cnt[6], *offs[6], *cursor[6], *csr[6], *partials[6];
    for (int t = 0; t < 6; t++){
        cnt[t]      = alloci(Ndst_t[t]);
        offs[t]     = alloci(Ndst_t[t] + 1);
        cursor[t]   = alloci(Ndst_t[t]);
        partials[t] = alloci(64);
        csr[t]      = alloci(Et[t]);
    }

    // ---- zero counters + stat slots ----
    for (int t = 0; t < 6; t++)
        hipMemsetAsync(cnt[t], 0, (size_t)Ndst_t[t] * 4, stream);
    hipMemsetAsync(stats, 0, 12 * 256 * 4, stream);

    // ---- CSR build (edges are launch-constant) ----
    for (int t = 0; t < 6; t++){
        int N = Ndst_t[t], E = Et[t];
        int B = cdiv(N, 1024);
        count_k<<<cdiv(E, 256), 256, 0, stream>>>(dstP[t], E, cnt[t]);
        scan1_k<<<B, 256, 0, stream>>>(cnt[t], N, partials[t]);
        scan2_k<<<1, 64, 0, stream>>>(partials[t], B, offs[t], N);
        scan3_k<<<B, 256, 0, stream>>>(cnt[t], partials[t], offs[t], cursor[t], N);
        fill_k<<<cdiv(E, 256), 256, 0, stream>>>(srcP[t], dstP[t], E, cursor[t], csr[t]);
    }
    wcat_k<<<cdiv(9 * 384 * 128, 256), 256, 0, stream>>>(Wl, Wr, Wcat);

    const int Nn[3]  = {ND, NG, NS};
    const int Kin[3] = {256, 128, 64};
    const float* xin[3] = {x_drug, x_gene, x_dis};

    // ---- input stage: h_t = relu(bn(x_t @ W_in_t + b_in_t)) ----
    for (int t = 0; t < 3; t++){
        gemm_k<128><<<cdiv(Nn[t], 64), 256, 0, stream>>>(xin[t], Kin[t], xin[t], Kin[t], Kin[t],
            W_in[t], b_in[t], nullptr, o, 128, Nn[t], Kin[t], 1.0f);
        stats_k<<<512, 128, 0, stream>>>(o, Nn[t], stats + t * 256);
        bn_k<<<cdiv(Nn[t] * 32, 256), 256, 0, stream>>>(o, stats + t * 256,
            g_in + t * 128, bt_in + t * 128, h[t], Nn[t], 1.0f / Nn[t], 0);
    }

    // ---- 3 conv layers ----
    const int e1s[3] = {1, 0, 2}, e2s[3] = {5, 3, 4};
    for (int L = 0; L < 3; L++){
        for (int t = 0; t < 6; t++)
            gather_k<<<cdiv(Ndst_t[t], 2), 256, 0, stream>>>(h[srcT[t]], csr[t], offs[t],
                A[dstT[t]], Ndst_t[t], colOff_t[t]);
        for (int t = 0; t < 3; t++){
            int e1 = e1s[t], e2 = e2s[t];
            const float* wc = Wcat + (size_t)(L * 3 + t) * 384 * 128;
            gemm_k<128><<<cdiv(Nn[t], 64), 256, 0, stream>>>(A[t], 256, h[t], 128, 256, wc,
                bl + (size_t)(L * 6 + e1) * 128, bl + (size_t)(L * 6 + e2) * 128,
                o, 128, Nn[t], 384, 0.5f);
            float* st = stats + (size_t)(3 + L * 3 + t) * 256;
            stats_k<<<512, 128, 0, stream>>>(o, Nn[t], st);
            bn_k<<<cdiv(Nn[t] * 32, 256), 256, 0, stream>>>(o, st,
                g_conv + (size_t)(L * 3 + t) * 128, bt_conv + (size_t)(L * 3 + t) * 128,
                h[t], Nn[t], 1.0f / Nn[t], 1);
        }
    }

    // ---- final projection ----
    size_t oofs[3] = {0, (size_t)ND * 64, (size_t)(ND + NG) * 64};
    for (int t = 0; t < 3; t++)
        gemm_k<64><<<cdiv(Nn[t], 64), 256, 0, stream>>>(h[t], 128, h[t], 128, 128,
            W_fin, b_fin, nullptr, out + oofs[t], 64, Nn[t], 128, 1.0f);
}

// Round 2
// 1323.737 us; speedup vs baseline: 1.9979x; 1.9979x over previous
//
#include <hip/hip_runtime.h>
#include <cstddef>
#include <cstdint>

typedef _Float16 f16;
typedef _Float16 f16x8 __attribute__((ext_vector_type(8)));
typedef float f32x4 __attribute__((ext_vector_type(4)));

constexpr int ND = 30000, NG = 60000, NS = 15000;
constexpr float BN_EPS = 1e-5f;

static inline int cdiv(int a, int b){ return (a + b - 1) / b; }

// ---------------- CSR construction (unchanged from round 1, works) ----------------

__global__ __launch_bounds__(256) void count_k(const int* __restrict__ dst, int E, int* __restrict__ cnt){
    int e = blockIdx.x * 256 + threadIdx.x;
    if (e < E) atomicAdd(&cnt[dst[e]], 1);
}

__global__ __launch_bounds__(256) void scan1_k(const int* __restrict__ cnt, int N, int* __restrict__ partials){
    __shared__ int sh[256];
    int tid = threadIdx.x;
    int base = blockIdx.x * 1024 + tid * 4;
    int s = 0;
    #pragma unroll
    for (int j = 0; j < 4; j++) if (base + j < N) s += cnt[base + j];
    sh[tid] = s; __syncthreads();
    for (int d = 128; d > 0; d >>= 1){
        if (tid < d) sh[tid] += sh[tid + d];
        __syncthreads();
    }
    if (tid == 0) partials[blockIdx.x] = sh[0];
}

__global__ void scan2_k(int* partials, int B, int* offs, int N){
    if (threadIdx.x == 0 && blockIdx.x == 0){
        int run = 0;
        for (int i = 0; i < B; i++){ int t = partials[i]; partials[i] = run; run += t; }
        offs[N] = run;
    }
}

__global__ __launch_bounds__(256) void scan3_k(const int* __restrict__ cnt, const int* __restrict__ partials,
                                               int* __restrict__ offs, int* __restrict__ cursor, int N){
    __shared__ int sh[256];
    int tid = threadIdx.x;
    int base = blockIdx.x * 1024 + tid * 4;
    int c[4]; int s = 0;
    #pragma unroll
    for (int j = 0; j < 4; j++){ c[j] = (base + j < N) ? cnt[base + j] : 0; s += c[j]; }
    sh[tid] = s; __syncthreads();
    for (int d = 1; d < 256; d <<= 1){
        int v = sh[tid];
        int add = (tid >= d) ? sh[tid - d] : 0;
        __syncthreads();
        sh[tid] = v + add;
        __syncthreads();
    }
    int excl = sh[tid] - s;
    int run = partials[blockIdx.x] + excl;
    #pragma unroll
    for (int j = 0; j < 4; j++){
        if (base + j < N){ offs[base + j] = run; cursor[base + j] = run; run += c[j]; }
    }
}

__global__ __launch_bounds__(256) void fill_k(const int* __restrict__ src, const int* __restrict__ dst, int E,
                                              int* __restrict__ cursor, int* __restrict__ csr){
    int e = blockIdx.x * 256 + threadIdx.x;
    if (e < E){
        int d = dst[e];
        int pos = atomicAdd(&cursor[d], 1);
        csr[pos] = src[e];
    }
}

// ---------------- prep: fp32 -> f16 cast, weight transpose+cast ----------------

__global__ __launch_bounds__(256) void cast_k(const float* __restrict__ src, f16* __restrict__ dst, int n){
    int i4 = (blockIdx.x * 256 + threadIdx.x) * 4;
    if (i4 >= n) return;
    float4 v = *reinterpret_cast<const float4*>(src + i4);
    union { uint2 u; f16 h[4]; } o;
    o.h[0] = (f16)v.x; o.h[1] = (f16)v.y; o.h[2] = (f16)v.z; o.h[3] = (f16)v.w;
    *reinterpret_cast<uint2*>(dst + i4) = o.u;
}

// W: K x C row-major fp32 -> Wt: C x K f16
__global__ __launch_bounds__(256) void tc_k(const float* __restrict__ W, f16* __restrict__ Wt, int K, int C){
    int idx = blockIdx.x * 256 + threadIdx.x;
    if (idx >= K * C) return;
    int k = idx / C, c = idx - k * C;
    Wt[(size_t)c * K + k] = (f16)W[idx];
}

// Wcat_t[g][c][k], g = L*3+t: k<128: Wl[L,e1,k,c]; k<256: Wl[L,e2,k-128,c]; else Wr[L,e1]+Wr[L,e2]
__global__ __launch_bounds__(256) void wcat_k(const float* __restrict__ Wl, const float* __restrict__ Wr,
                                              f16* __restrict__ Wt){
    int idx = blockIdx.x * 256 + threadIdx.x;
    constexpr int TOT = 9 * 384 * 128;
    if (idx >= TOT) return;
    int g = idx / (384 * 128);
    int rem = idx - g * (384 * 128);
    int c = rem / 384;
    int k = rem - c * 384;
    int L = g / 3, t = g - L * 3;
    const int e1s[3] = {1, 0, 2}, e2s[3] = {5, 3, 4};
    int e1 = e1s[t], e2 = e2s[t];
    float v;
    if (k < 128)      v = Wl[(((size_t)L * 6 + e1) * 128 + k) * 128 + c];
    else if (k < 256) v = Wl[(((size_t)L * 6 + e2) * 128 + (k - 128)) * 128 + c];
    else {
        int kr = k - 256;
        v = Wr[(((size_t)L * 6 + e1) * 128 + kr) * 128 + c]
          + Wr[(((size_t)L * 6 + e2) * 128 + kr) * 128 + c];
    }
    Wt[idx] = (f16)v;
}

// ---------------- fused gather-mean over all 6 edge types (f16 h -> f16 A) ----------------

struct GSeg { const int* offs; const int* csr; const unsigned int* h; unsigned int* A; int colPair; int N; int base; };
struct GDesc { GSeg s[6]; };

__global__ __launch_bounds__(256) void gatherall_k(GDesc gd){
    int bid = blockIdx.x;
    int si = 0;
    #pragma unroll
    for (int t = 1; t < 6; t++) if (bid >= gd.s[t].base) si = t;
    GSeg sg = gd.s[si];
    int node = (bid - sg.base) * 4 + (threadIdx.x >> 6);
    int lane = threadIdx.x & 63;
    if (node >= sg.N) return;
    int s = sg.offs[node], e = sg.offs[node + 1];
    float a0 = 0.f, a1 = 0.f;
    for (int j = s; j < e; ++j){
        int srci = sg.csr[j];
        unsigned int v = sg.h[srci * 64 + lane];
        union { unsigned int u; f16 h[2]; } c; c.u = v;
        a0 += (float)c.h[0]; a1 += (float)c.h[1];
    }
    float inv = (e > s) ? 1.0f / (float)(e - s) : 0.f;
    union { unsigned int u; f16 h[2]; } o;
    o.h[0] = (f16)(a0 * inv); o.h[1] = (f16)(a1 * inv);
    sg.A[(size_t)node * 128 + sg.colPair + lane] = o.u;
}

// ---------------- MFMA fp16 GEMM: out = scale*(A@W + b1 + b2), fused BN-stat accumulation ----------------
// A dual-source (k < ksplit from A1, else A2), both f16 row-major. Wt: [BN][K] f16 (pre-transposed).
// Block: 256 threads (4 waves), tile 128 rows x BN cols. mfma_f32_16x16x32_f16.

template<int BN, bool STATS>
__global__ __launch_bounds__(256) void gemm16_k(const f16* __restrict__ A1, int lda1,
                                                const f16* __restrict__ A2, int lda2, int ksplit,
                                                const f16* __restrict__ Wt,
                                                const float* __restrict__ b1, const float* __restrict__ b2,
                                                float* __restrict__ out, int ldo,
                                                int N, int K, float scale, float* __restrict__ stats){
    constexpr int BK = 64, PAD = 72, CF = BN / 16;
    __shared__ f16 As[128 * PAD];
    __shared__ f16 Bs[BN * PAD];
    __shared__ float ssum[BN];
    __shared__ float ssq[BN];
    int tid = threadIdx.x;
    int wv = tid >> 6, lane = tid & 63;
    int row0 = blockIdx.x * 128;
    if (STATS && tid < BN){ ssum[tid] = 0.f; ssq[tid] = 0.f; }

    f32x4 acc[2][CF];
    #pragma unroll
    for (int rf = 0; rf < 2; rf++)
        #pragma unroll
        for (int cf = 0; cf < CF; cf++)
            acc[rf][cf] = (f32x4){0.f, 0.f, 0.f, 0.f};

    for (int k0 = 0; k0 < K; k0 += BK){
        const f16* Ab; int lda, kloc;
        if (k0 < ksplit){ Ab = A1; lda = lda1; kloc = k0; }
        else            { Ab = A2; lda = lda2; kloc = k0 - ksplit; }
        // stage A tile: 128 rows x 64 f16 (8 uint4 per row, 4 per thread)
        #pragma unroll
        for (int p = 0; p < 4; p++){
            int f = tid + p * 256;
            int r = f >> 3, sgm = f & 7;
            int gr = row0 + r;
            uint4 v = make_uint4(0u, 0u, 0u, 0u);
            if (gr < N) v = *reinterpret_cast<const uint4*>(Ab + (size_t)gr * lda + kloc + sgm * 8);
            *reinterpret_cast<uint4*>(As + r * PAD + sgm * 8) = v;
        }
        // stage B tile: BN rows(cols) x 64 f16
        #pragma unroll
        for (int p = 0; p < BN / 32; p++){
            int f = tid + p * 256;
            int r = f >> 3, sgm = f & 7;
            uint4 v = *reinterpret_cast<const uint4*>(Wt + (size_t)r * K + k0 + sgm * 8);
            *reinterpret_cast<uint4*>(Bs + r * PAD + sgm * 8) = v;
        }
        __syncthreads();
        #pragma unroll
        for (int kf = 0; kf < 2; kf++){
            int kb = kf * 32 + (lane >> 4) * 8;
            f16x8 a0 = *reinterpret_cast<const f16x8*>(As + (wv * 32 + (lane & 15)) * PAD + kb);
            f16x8 a1 = *reinterpret_cast<const f16x8*>(As + (wv * 32 + 16 + (lane & 15)) * PAD + kb);
            #pragma unroll
            for (int cf = 0; cf < CF; cf++){
                f16x8 b = *reinterpret_cast<const f16x8*>(Bs + (cf * 16 + (lane & 15)) * PAD + kb);
                acc[0][cf] = __builtin_amdgcn_mfma_f32_16x16x32_f16(a0, b, acc[0][cf], 0, 0, 0);
                acc[1][cf] = __builtin_amdgcn_mfma_f32_16x16x32_f16(a1, b, acc[1][cf], 0, 0, 0);
            }
        }
        __syncthreads();
    }
    // epilogue: C/D layout col = lane&15, row = (lane>>4)*4 + reg
    int rbase = row0 + wv * 32 + ((lane >> 4) << 2);
    #pragma unroll
    for (int cf = 0; cf < CF; cf++){
        int col = cf * 16 + (lane & 15);
        float bias = 0.f;
        if (b1) bias += b1[col];
        if (b2) bias += b2[col];
        float ls = 0.f, lq = 0.f;
        #pragma unroll
        for (int rf = 0; rf < 2; rf++){
            #pragma unroll
            for (int q = 0; q < 4; q++){
                int gr = rbase + rf * 16 + q;
                if (gr < N){
                    float v = scale * (acc[rf][cf][q] + bias);
                    out[(size_t)gr * ldo + col] = v;
                    ls += v; lq += v * v;
                }
            }
        }
        if (STATS){ atomicAdd(&ssum[col], ls); atomicAdd(&ssq[col], lq); }
    }
    if (STATS){
        __syncthreads();
        if (tid < BN){
            atomicAdd(&stats[tid], ssum[tid]);
            atomicAdd(&stats[128 + tid], ssq[tid]);
        }
    }
}

// ---------------- BN apply + ReLU (+ residual), fp32 o -> f16 h ----------------

__global__ __launch_bounds__(256) void bn_k(const float* __restrict__ o, const float* __restrict__ stats,
                                            const float* __restrict__ g, const float* __restrict__ b,
                                            f16* __restrict__ h, int N, float invN, int residual){
    int idx = blockIdx.x * 256 + threadIdx.x;
    if (idx >= N * 16) return;
    int n = idx >> 4, c8 = (idx & 15) * 8;
    const float* op = o + (size_t)n * 128 + c8;
    float4 o0 = *reinterpret_cast<const float4*>(op);
    float4 o1 = *reinterpret_cast<const float4*>(op + 4);
    float ov[8] = {o0.x, o0.y, o0.z, o0.w, o1.x, o1.y, o1.z, o1.w};
    float r[8];
    #pragma unroll
    for (int j = 0; j < 8; j++){
        int c = c8 + j;
        float mu  = stats[c] * invN;
        float var = stats[128 + c] * invN - mu * mu;
        float v = (ov[j] - mu) * rsqrtf(var + BN_EPS) * g[c] + b[c];
        r[j] = v > 0.f ? v : 0.f;
    }
    f16* hp = h + (size_t)n * 128 + c8;
    if (residual){
        uint4 old = *reinterpret_cast<const uint4*>(hp);
        union { uint4 u; f16 h[8]; } ou; ou.u = old;
        #pragma unroll
        for (int j = 0; j < 8; j++) r[j] += (float)ou.h[j];
    }
    union { uint4 u; f16 h[8]; } pk;
    #pragma unroll
    for (int j = 0; j < 8; j++) pk.h[j] = (f16)r[j];
    *reinterpret_cast<uint4*>(hp) = pk.u;
}

// ---------------- host orchestration ----------------

extern "C" void kernel_launch(void* const* d_in, const int* in_sizes, int n_in,
                              void* d_out, int out_size, void* d_ws, size_t ws_size,
                              hipStream_t stream){
    const float* x_drug = (const float*)d_in[0];
    const float* x_gene = (const float*)d_in[1];
    const float* x_dis  = (const float*)d_in[2];
    const int* srcP[6] = {(const int*)d_in[3], (const int*)d_in[5], (const int*)d_in[7],
                          (const int*)d_in[9], (const int*)d_in[11], (const int*)d_in[13]};
    const int* dstP[6] = {(const int*)d_in[4], (const int*)d_in[6], (const int*)d_in[8],
                          (const int*)d_in[10], (const int*)d_in[12], (const int*)d_in[14]};
    const int  Et[6]   = {in_sizes[3], in_sizes[5], in_sizes[7], in_sizes[9], in_sizes[11], in_sizes[13]};
    const float* W_in[3] = {(const float*)d_in[15], (const float*)d_in[17], (const float*)d_in[19]};
    const float* b_in[3] = {(const float*)d_in[16], (const float*)d_in[18], (const float*)d_in[20]};
    const float* g_in  = (const float*)d_in[21];
    const float* bt_in = (const float*)d_in[22];
    const float* Wl    = (const float*)d_in[23];
    const float* Wr    = (const float*)d_in[24];
    const float* bl    = (const float*)d_in[25];
    const float* g_conv  = (const float*)d_in[26];
    const float* bt_conv = (const float*)d_in[27];
    const float* W_fin = (const float*)d_in[28];
    const float* b_fin = (const float*)d_in[29];
    float* out = (float*)d_out;

    // edge-type metadata (order: dg, gd, gs, sg, ds, sd)
    const int Ndst_t[6]   = {NG, ND, NS, NG, NS, ND};
    const int srcT[6]     = {0, 1, 1, 2, 0, 2};
    const int dstT[6]     = {1, 0, 2, 1, 2, 0};
    const int colPair_t[6] = {0, 0, 0, 64, 64, 64};

    const int Nn[3]  = {ND, NG, NS};
    const int Kin[3] = {256, 128, 64};
    const float* xin[3] = {x_drug, x_gene, x_dis};

    // ---- workspace carve (bytes, 256-aligned) ----
    char* base = (char*)d_ws;
    size_t off = 0;
    auto alloc = [&](size_t bytes) -> char* {
        char* p = base + off; off += (bytes + 255) & ~(size_t)255; return p;
    };
    f16* h[3];  for (int t = 0; t < 3; t++) h[t]  = (f16*)alloc((size_t)Nn[t] * 128 * 2);
    f16* A[3];  for (int t = 0; t < 3; t++) A[t]  = (f16*)alloc((size_t)Nn[t] * 256 * 2);
    f16* xb[3]; for (int t = 0; t < 3; t++) xb[t] = (f16*)alloc((size_t)Nn[t] * Kin[t] * 2);
    f16* Wcat_t = (f16*)alloc((size_t)9 * 128 * 384 * 2);
    f16* Wint[3]; for (int t = 0; t < 3; t++) Wint[t] = (f16*)alloc((size_t)128 * Kin[t] * 2);
    f16* Wfin_t = (f16*)alloc((size_t)64 * 128 * 2);
    float* o     = (float*)alloc((size_t)NG * 128 * 4);
    float* stats = (float*)alloc(12 * 256 * 4);
    int *cnt[6], *offs[6], *cursor[6], *csr[6], *partials[6];
    for (int t = 0; t < 6; t++){
        cnt[t]      = (int*)alloc((size_t)Ndst_t[t] * 4);
        offs[t]     = (int*)alloc((size_t)(Ndst_t[t] + 1) * 4);
        cursor[t]   = (int*)alloc((size_t)Ndst_t[t] * 4);
        partials[t] = (int*)alloc(64 * 4);
        csr[t]      = (int*)alloc((size_t)Et[t] * 4);
    }

    // ---- zero counters + stat slots ----
    for (int t = 0; t < 6; t++)
        hipMemsetAsync(cnt[t], 0, (size_t)Ndst_t[t] * 4, stream);
    hipMemsetAsync(stats, 0, 12 * 256 * 4, stream);

    // ---- CSR build ----
    for (int t = 0; t < 6; t++){
        int N = Ndst_t[t], E = Et[t];
        int B = cdiv(N, 1024);
        count_k<<<cdiv(E, 256), 256, 0, stream>>>(dstP[t], E, cnt[t]);
        scan1_k<<<B, 256, 0, stream>>>(cnt[t], N, partials[t]);
        scan2_k<<<1, 64, 0, stream>>>(partials[t], B, offs[t], N);
        scan3_k<<<B, 256, 0, stream>>>(cnt[t], partials[t], offs[t], cursor[t], N);
        fill_k<<<cdiv(E, 256), 256, 0, stream>>>(srcP[t], dstP[t], E, cursor[t], csr[t]);
    }

    // ---- prep: casts + weight transposes ----
    for (int t = 0; t < 3; t++){
        int n = Nn[t] * Kin[t];
        cast_k<<<cdiv(n / 4, 256), 256, 0, stream>>>(xin[t], xb[t], n);
        tc_k<<<cdiv(Kin[t] * 128, 256), 256, 0, stream>>>(W_in[t], Wint[t], Kin[t], 128);
    }
    tc_k<<<cdiv(128 * 64, 256), 256, 0, stream>>>(W_fin, Wfin_t, 128, 64);
    wcat_k<<<cdiv(9 * 384 * 128, 256), 256, 0, stream>>>(Wl, Wr, Wcat_t);

    // ---- input stage ----
    for (int t = 0; t < 3; t++){
        gemm16_k<128, true><<<cdiv(Nn[t], 128), 256, 0, stream>>>(
            xb[t], Kin[t], xb[t], Kin[t], Kin[t], Wint[t],
            b_in[t], nullptr, o, 128, Nn[t], Kin[t], 1.0f, stats + t * 256);
        bn_k<<<cdiv(Nn[t] * 16, 256), 256, 0, stream>>>(o, stats + t * 256,
            g_in + t * 128, bt_in + t * 128, h[t], Nn[t], 1.0f / Nn[t], 0);
    }

    // ---- 3 conv layers ----
    const int e1s[3] = {1, 0, 2}, e2s[3] = {5, 3, 4};
    for (int L = 0; L < 3; L++){
        GDesc gd; int bacc = 0;
        for (int t = 0; t < 6; t++){
            gd.s[t].offs = offs[t];
            gd.s[t].csr  = csr[t];
            gd.s[t].h    = (const unsigned int*)h[srcT[t]];
            gd.s[t].A    = (unsigned int*)A[dstT[t]];
            gd.s[t].colPair = colPair_t[t];
            gd.s[t].N    = Ndst_t[t];
            gd.s[t].base = bacc;
            bacc += cdiv(Ndst_t[t], 4);
        }
        gatherall_k<<<bacc, 256, 0, stream>>>(gd);
        for (int t = 0; t < 3; t++){
            int e1 = e1s[t], e2 = e2s[t];
            const f16* wc = Wcat_t + (size_t)(L * 3 + t) * 128 * 384;
            float* st = stats + (size_t)(3 + L * 3 + t) * 256;
            gemm16_k<128, true><<<cdiv(Nn[t], 128), 256, 0, stream>>>(
                A[t], 256, h[t], 128, 256, wc,
                bl + (size_t)(L * 6 + e1) * 128, bl + (size_t)(L * 6 + e2) * 128,
                o, 128, Nn[t], 384, 0.5f, st);
            bn_k<<<cdiv(Nn[t] * 16, 256), 256, 0, stream>>>(o, st,
                g_conv + (size_t)(L * 3 + t) * 128, bt_conv + (size_t)(L * 3 + t) * 128,
                h[t], Nn[t], 1.0f / Nn[t], 1);
        }
    }

    // ---- final projection (fp32 out) ----
    size_t oofs[3] = {0, (size_t)ND * 64, (size_t)(ND + NG) * 64};
    for (int t = 0; t < 3; t++)
        gemm16_k<64, false><<<cdiv(Nn[t], 128), 256, 0, stream>>>(
            h[t], 128, h[t], 128, 128, Wfin_t,
            b_fin, nullptr, out + oofs[t], 64, Nn[t], 128, 1.0f, nullptr);
}

// Round 3
// 991.055 us; speedup vs baseline: 2.6685x; 1.3357x over previous
//
#include <hip/hip_runtime.h>
#include <cstddef>
#include <cstdint>

typedef _Float16 f16;
typedef _Float16 f16x8 __attribute__((ext_vector_type(8)));
typedef float f32x4 __attribute__((ext_vector_type(4)));

constexpr int ND = 30000, NG = 60000, NS = 15000;
constexpr float BN_EPS = 1e-5f;

static inline int cdiv(int a, int b){ return (a + b - 1) / b; }

// ---------------- CSR construction ----------------

__global__ __launch_bounds__(256) void count_k(const int* __restrict__ dst, int E, int* __restrict__ cnt){
    int e = blockIdx.x * 256 + threadIdx.x;
    if (e < E) atomicAdd(&cnt[dst[e]], 1);
}

__global__ __launch_bounds__(256) void scan1_k(const int* __restrict__ cnt, int N, int* __restrict__ partials){
    __shared__ int sh[256];
    int tid = threadIdx.x;
    int base = blockIdx.x * 1024 + tid * 4;
    int s = 0;
    #pragma unroll
    for (int j = 0; j < 4; j++) if (base + j < N) s += cnt[base + j];
    sh[tid] = s; __syncthreads();
    for (int d = 128; d > 0; d >>= 1){
        if (tid < d) sh[tid] += sh[tid + d];
        __syncthreads();
    }
    if (tid == 0) partials[blockIdx.x] = sh[0];
}

__global__ void scan2_k(int* partials, int B, int* offs, int N){
    if (threadIdx.x == 0 && blockIdx.x == 0){
        int run = 0;
        for (int i = 0; i < B; i++){ int t = partials[i]; partials[i] = run; run += t; }
        offs[N] = run;
    }
}

__global__ __launch_bounds__(256) void scan3_k(const int* __restrict__ cnt, const int* __restrict__ partials,
                                               int* __restrict__ offs, int* __restrict__ cursor, int N){
    __shared__ int sh[256];
    int tid = threadIdx.x;
    int base = blockIdx.x * 1024 + tid * 4;
    int c[4]; int s = 0;
    #pragma unroll
    for (int j = 0; j < 4; j++){ c[j] = (base + j < N) ? cnt[base + j] : 0; s += c[j]; }
    sh[tid] = s; __syncthreads();
    for (int d = 1; d < 256; d <<= 1){
        int v = sh[tid];
        int add = (tid >= d) ? sh[tid - d] : 0;
        __syncthreads();
        sh[tid] = v + add;
        __syncthreads();
    }
    int excl = sh[tid] - s;
    int run = partials[blockIdx.x] + excl;
    #pragma unroll
    for (int j = 0; j < 4; j++){
        if (base + j < N){ offs[base + j] = run; cursor[base + j] = run; run += c[j]; }
    }
}

__global__ __launch_bounds__(256) void fill_k(const int* __restrict__ src, const int* __restrict__ dst, int E,
                                              int* __restrict__ cursor, int* __restrict__ csr){
    int e = blockIdx.x * 256 + threadIdx.x;
    if (e < E){
        int d = dst[e];
        int pos = atomicAdd(&cursor[d], 1);
        csr[pos] = src[e];
    }
}

// ---------------- prep: fp32 -> f16 cast, weight transpose+cast ----------------

__global__ __launch_bounds__(256) void cast_k(const float* __restrict__ src, f16* __restrict__ dst, int n){
    int i4 = (blockIdx.x * 256 + threadIdx.x) * 4;
    if (i4 >= n) return;
    float4 v = *reinterpret_cast<const float4*>(src + i4);
    union { uint2 u; f16 h[4]; } o;
    o.h[0] = (f16)v.x; o.h[1] = (f16)v.y; o.h[2] = (f16)v.z; o.h[3] = (f16)v.w;
    *reinterpret_cast<uint2*>(dst + i4) = o.u;
}

// W: K x C row-major fp32 -> Wt: C x K f16
__global__ __launch_bounds__(256) void tc_k(const float* __restrict__ W, f16* __restrict__ Wt, int K, int C){
    int idx = blockIdx.x * 256 + threadIdx.x;
    if (idx >= K * C) return;
    int k = idx / C, c = idx - k * C;
    Wt[(size_t)c * K + k] = (f16)W[idx];
}

// Wcat_t[g][c][k], g = L*3+t: k<128: Wl[L,e1,k,c]; k<256: Wl[L,e2,k-128,c]; else Wr[L,e1]+Wr[L,e2]
__global__ __launch_bounds__(256) void wcat_k(const float* __restrict__ Wl, const float* __restrict__ Wr,
                                              f16* __restrict__ Wt){
    int idx = blockIdx.x * 256 + threadIdx.x;
    constexpr int TOT = 9 * 384 * 128;
    if (idx >= TOT) return;
    int g = idx / (384 * 128);
    int rem = idx - g * (384 * 128);
    int c = rem / 384;
    int k = rem - c * 384;
    int L = g / 3, t = g - L * 3;
    const int e1s[3] = {1, 0, 2}, e2s[3] = {5, 3, 4};
    int e1 = e1s[t], e2 = e2s[t];
    float v;
    if (k < 128)      v = Wl[(((size_t)L * 6 + e1) * 128 + k) * 128 + c];
    else if (k < 256) v = Wl[(((size_t)L * 6 + e2) * 128 + (k - 128)) * 128 + c];
    else {
        int kr = k - 256;
        v = Wr[(((size_t)L * 6 + e1) * 128 + kr) * 128 + c]
          + Wr[(((size_t)L * 6 + e2) * 128 + kr) * 128 + c];
    }
    Wt[idx] = (f16)v;
}

// ---------------- fused gather-mean over all 6 edge types (f16 h -> f16 A) ----------------
// 8-deep software pipeline: 8 independent row-loads in flight per wave.

struct GSeg { const int* offs; const int* csr; const unsigned int* h; unsigned int* A; int colPair; int N; int base; };
struct GDesc { GSeg s[6]; };

__device__ __forceinline__ void acc_u(unsigned int v, float& a0, float& a1){
    union { unsigned int u; f16 h[2]; } c; c.u = v;
    a0 += (float)c.h[0]; a1 += (float)c.h[1];
}

__global__ __launch_bounds__(256) void gatherall_k(GDesc gd){
    int bid = blockIdx.x;
    int si = 0;
    #pragma unroll
    for (int t = 1; t < 6; t++) if (bid >= gd.s[t].base) si = t;
    GSeg sg = gd.s[si];
    int node = (bid - sg.base) * 4 + (threadIdx.x >> 6);
    int lane = threadIdx.x & 63;
    if (node >= sg.N) return;
    int s = sg.offs[node], e = sg.offs[node + 1];
    const int* cp = sg.csr;
    const unsigned int* hp = sg.h;
    float a0 = 0.f, a1 = 0.f;
    int j = s;
    for (; j + 8 <= e; j += 8){
        int i0 = cp[j+0], i1 = cp[j+1], i2 = cp[j+2], i3 = cp[j+3];
        int i4 = cp[j+4], i5 = cp[j+5], i6 = cp[j+6], i7 = cp[j+7];
        unsigned int w0 = hp[(size_t)i0 * 64 + lane];
        unsigned int w1 = hp[(size_t)i1 * 64 + lane];
        unsigned int w2 = hp[(size_t)i2 * 64 + lane];
        unsigned int w3 = hp[(size_t)i3 * 64 + lane];
        unsigned int w4 = hp[(size_t)i4 * 64 + lane];
        unsigned int w5 = hp[(size_t)i5 * 64 + lane];
        unsigned int w6 = hp[(size_t)i6 * 64 + lane];
        unsigned int w7 = hp[(size_t)i7 * 64 + lane];
        acc_u(w0, a0, a1); acc_u(w1, a0, a1); acc_u(w2, a0, a1); acc_u(w3, a0, a1);
        acc_u(w4, a0, a1); acc_u(w5, a0, a1); acc_u(w6, a0, a1); acc_u(w7, a0, a1);
    }
    if (j + 4 <= e){
        int i0 = cp[j+0], i1 = cp[j+1], i2 = cp[j+2], i3 = cp[j+3];
        unsigned int w0 = hp[(size_t)i0 * 64 + lane];
        unsigned int w1 = hp[(size_t)i1 * 64 + lane];
        unsigned int w2 = hp[(size_t)i2 * 64 + lane];
        unsigned int w3 = hp[(size_t)i3 * 64 + lane];
        acc_u(w0, a0, a1); acc_u(w1, a0, a1); acc_u(w2, a0, a1); acc_u(w3, a0, a1);
        j += 4;
    }
    if (j + 2 <= e){
        int i0 = cp[j+0], i1 = cp[j+1];
        unsigned int w0 = hp[(size_t)i0 * 64 + lane];
        unsigned int w1 = hp[(size_t)i1 * 64 + lane];
        acc_u(w0, a0, a1); acc_u(w1, a0, a1);
        j += 2;
    }
    if (j < e){
        acc_u(hp[(size_t)cp[j] * 64 + lane], a0, a1);
    }
    float inv = (e > s) ? 1.0f / (float)(e - s) : 0.f;
    union { unsigned int u; f16 h[2]; } o;
    o.h[0] = (f16)(a0 * inv); o.h[1] = (f16)(a1 * inv);
    sg.A[(size_t)node * 128 + sg.colPair + lane] = o.u;
}

// ---------------- MFMA fp16 GEMM: out = scale*(A@W + b1 + b2), fused BN-stat accumulation ----------------
// A dual-source (k < ksplit from A1, else A2), both f16 row-major. Wt: [BN][K] f16 (pre-transposed).
// Block: 256 threads (4 waves), tile 128 rows x BN cols. mfma_f32_16x16x32_f16.
// OUT16: write f16 output, else fp32.

template<int BN, bool STATS, bool OUT16>
__global__ __launch_bounds__(256) void gemm16_k(const f16* __restrict__ A1, int lda1,
                                                const f16* __restrict__ A2, int lda2, int ksplit,
                                                const f16* __restrict__ Wt,
                                                const float* __restrict__ b1, const float* __restrict__ b2,
                                                void* __restrict__ outv, int ldo,
                                                int N, int K, float scale, float* __restrict__ stats){
    constexpr int BK = 64, PAD = 72, CF = BN / 16;
    __shared__ f16 As[128 * PAD];
    __shared__ f16 Bs[BN * PAD];
    __shared__ float ssum[BN];
    __shared__ float ssq[BN];
    int tid = threadIdx.x;
    int wv = tid >> 6, lane = tid & 63;
    int row0 = blockIdx.x * 128;
    if (STATS && tid < BN){ ssum[tid] = 0.f; ssq[tid] = 0.f; }

    f32x4 acc[2][CF];
    #pragma unroll
    for (int rf = 0; rf < 2; rf++)
        #pragma unroll
        for (int cf = 0; cf < CF; cf++)
            acc[rf][cf] = (f32x4){0.f, 0.f, 0.f, 0.f};

    for (int k0 = 0; k0 < K; k0 += BK){
        const f16* Ab; int lda, kloc;
        if (k0 < ksplit){ Ab = A1; lda = lda1; kloc = k0; }
        else            { Ab = A2; lda = lda2; kloc = k0 - ksplit; }
        #pragma unroll
        for (int p = 0; p < 4; p++){
            int f = tid + p * 256;
            int r = f >> 3, sgm = f & 7;
            int gr = row0 + r;
            uint4 v = make_uint4(0u, 0u, 0u, 0u);
            if (gr < N) v = *reinterpret_cast<const uint4*>(Ab + (size_t)gr * lda + kloc + sgm * 8);
            *reinterpret_cast<uint4*>(As + r * PAD + sgm * 8) = v;
        }
        #pragma unroll
        for (int p = 0; p < BN / 32; p++){
            int f = tid + p * 256;
            int r = f >> 3, sgm = f & 7;
            uint4 v = *reinterpret_cast<const uint4*>(Wt + (size_t)r * K + k0 + sgm * 8);
            *reinterpret_cast<uint4*>(Bs + r * PAD + sgm * 8) = v;
        }
        __syncthreads();
        #pragma unroll
        for (int kf = 0; kf < 2; kf++){
            int kb = kf * 32 + (lane >> 4) * 8;
            f16x8 a0 = *reinterpret_cast<const f16x8*>(As + (wv * 32 + (lane & 15)) * PAD + kb);
            f16x8 a1 = *reinterpret_cast<const f16x8*>(As + (wv * 32 + 16 + (lane & 15)) * PAD + kb);
            #pragma unroll
            for (int cf = 0; cf < CF; cf++){
                f16x8 b = *reinterpret_cast<const f16x8*>(Bs + (cf * 16 + (lane & 15)) * PAD + kb);
                acc[0][cf] = __builtin_amdgcn_mfma_f32_16x16x32_f16(a0, b, acc[0][cf], 0, 0, 0);
                acc[1][cf] = __builtin_amdgcn_mfma_f32_16x16x32_f16(a1, b, acc[1][cf], 0, 0, 0);
            }
        }
        __syncthreads();
    }
    // epilogue: C/D layout col = lane&15, row = (lane>>4)*4 + reg
    int rbase = row0 + wv * 32 + ((lane >> 4) << 2);
    #pragma unroll
    for (int cf = 0; cf < CF; cf++){
        int col = cf * 16 + (lane & 15);
        float bias = 0.f;
        if (b1) bias += b1[col];
        if (b2) bias += b2[col];
        float ls = 0.f, lq = 0.f;
        #pragma unroll
        for (int rf = 0; rf < 2; rf++){
            #pragma unroll
            for (int q = 0; q < 4; q++){
                int gr = rbase + rf * 16 + q;
                if (gr < N){
                    float v = scale * (acc[rf][cf][q] + bias);
                    if (OUT16) ((f16*)outv)[(size_t)gr * ldo + col] = (f16)v;
                    else       ((float*)outv)[(size_t)gr * ldo + col] = v;
                    ls += v; lq += v * v;
                }
            }
        }
        if (STATS){ atomicAdd(&ssum[col], ls); atomicAdd(&ssq[col], lq); }
    }
    if (STATS){
        __syncthreads();
        if (tid < BN){
            atomicAdd(&stats[tid], ssum[tid]);
            atomicAdd(&stats[128 + tid], ssq[tid]);
        }
    }
}

// ---------------- BN apply + ReLU (+ residual), f16 o -> f16 h ----------------

__global__ __launch_bounds__(256) void bn_k(const f16* __restrict__ o, const float* __restrict__ stats,
                                            const float* __restrict__ g, const float* __restrict__ b,
                                            f16* __restrict__ h, int N, float invN, int residual){
    int idx = blockIdx.x * 256 + threadIdx.x;
    if (idx >= N * 16) return;
    int n = idx >> 4, c8 = (idx & 15) * 8;
    union { uint4 u; f16 h[8]; } ov;
    ov.u = *reinterpret_cast<const uint4*>(o + (size_t)n * 128 + c8);
    float r[8];
    #pragma unroll
    for (int j = 0; j < 8; j++){
        int c = c8 + j;
        float mu  = stats[c] * invN;
        float var = stats[128 + c] * invN - mu * mu;
        float v = ((float)ov.h[j] - mu) * rsqrtf(var + BN_EPS) * g[c] + b[c];
        r[j] = v > 0.f ? v : 0.f;
    }
    f16* hp = h + (size_t)n * 128 + c8;
    if (residual){
        uint4 old = *reinterpret_cast<const uint4*>(hp);
        union { uint4 u; f16 h[8]; } ou; ou.u = old;
        #pragma unroll
        for (int j = 0; j < 8; j++) r[j] += (float)ou.h[j];
    }
    union { uint4 u; f16 h[8]; } pk;
    #pragma unroll
    for (int j = 0; j < 8; j++) pk.h[j] = (f16)r[j];
    *reinterpret_cast<uint4*>(hp) = pk.u;
}

// ---------------- host orchestration ----------------

extern "C" void kernel_launch(void* const* d_in, const int* in_sizes, int n_in,
                              void* d_out, int out_size, void* d_ws, size_t ws_size,
                              hipStream_t stream){
    const float* x_drug = (const float*)d_in[0];
    const float* x_gene = (const float*)d_in[1];
    const float* x_dis  = (const float*)d_in[2];
    const int* srcP[6] = {(const int*)d_in[3], (const int*)d_in[5], (const int*)d_in[7],
                          (const int*)d_in[9], (const int*)d_in[11], (const int*)d_in[13]};
    const int* dstP[6] = {(const int*)d_in[4], (const int*)d_in[6], (const int*)d_in[8],
                          (const int*)d_in[10], (const int*)d_in[12], (const int*)d_in[14]};
    const int  Et[6]   = {in_sizes[3], in_sizes[5], in_sizes[7], in_sizes[9], in_sizes[11], in_sizes[13]};
    const float* W_in[3] = {(const float*)d_in[15], (const float*)d_in[17], (const float*)d_in[19]};
    const float* b_in[3] = {(const float*)d_in[16], (const float*)d_in[18], (const float*)d_in[20]};
    const float* g_in  = (const float*)d_in[21];
    const float* bt_in = (const float*)d_in[22];
    const float* Wl    = (const float*)d_in[23];
    const float* Wr    = (const float*)d_in[24];
    const float* bl    = (const float*)d_in[25];
    const float* g_conv  = (const float*)d_in[26];
    const float* bt_conv = (const float*)d_in[27];
    const float* W_fin = (const float*)d_in[28];
    const float* b_fin = (const float*)d_in[29];
    float* out = (float*)d_out;

    // edge-type metadata (order: dg, gd, gs, sg, ds, sd)
    const int Ndst_t[6]   = {NG, ND, NS, NG, NS, ND};
    const int srcT[6]     = {0, 1, 1, 2, 0, 2};
    const int dstT[6]     = {1, 0, 2, 1, 2, 0};
    const int colPair_t[6] = {0, 0, 0, 64, 64, 64};

    const int Nn[3]  = {ND, NG, NS};
    const int Kin[3] = {256, 128, 64};
    const float* xin[3] = {x_drug, x_gene, x_dis};

    // ---- workspace carve ----
    char* base = (char*)d_ws;
    size_t off = 0;
    auto alloc = [&](size_t bytes) -> char* {
        char* p = base + off; off += (bytes + 255) & ~(size_t)255; return p;
    };
    f16* h[3];  for (int t = 0; t < 3; t++) h[t]  = (f16*)alloc((size_t)Nn[t] * 128 * 2);
    f16* A[3];  for (int t = 0; t < 3; t++) A[t]  = (f16*)alloc((size_t)Nn[t] * 256 * 2);
    f16* xb[3]; for (int t = 0; t < 3; t++) xb[t] = (f16*)alloc((size_t)Nn[t] * Kin[t] * 2);
    f16* Wcat_t = (f16*)alloc((size_t)9 * 128 * 384 * 2);
    f16* Wint[3]; for (int t = 0; t < 3; t++) Wint[t] = (f16*)alloc((size_t)128 * Kin[t] * 2);
    f16* Wfin_t = (f16*)alloc((size_t)64 * 128 * 2);
    f16* o       = (f16*)alloc((size_t)NG * 128 * 2);
    float* stats = (float*)alloc(12 * 256 * 4);
    int *cnt[6], *offs[6], *cursor[6], *csr[6], *partials[6];
    for (int t = 0; t < 6; t++){
        cnt[t]      = (int*)alloc((size_t)Ndst_t[t] * 4);
        offs[t]     = (int*)alloc((size_t)(Ndst_t[t] + 1) * 4);
        cursor[t]   = (int*)alloc((size_t)Ndst_t[t] * 4);
        partials[t] = (int*)alloc(64 * 4);
        csr[t]      = (int*)alloc((size_t)Et[t] * 4);
    }

    // ---- zero counters + stat slots ----
    for (int t = 0; t < 6; t++)
        hipMemsetAsync(cnt[t], 0, (size_t)Ndst_t[t] * 4, stream);
    hipMemsetAsync(stats, 0, 12 * 256 * 4, stream);

    // ---- CSR build ----
    for (int t = 0; t < 6; t++){
        int N = Ndst_t[t], E = Et[t];
        int B = cdiv(N, 1024);
        count_k<<<cdiv(E, 256), 256, 0, stream>>>(dstP[t], E, cnt[t]);
        scan1_k<<<B, 256, 0, stream>>>(cnt[t], N, partials[t]);
        scan2_k<<<1, 64, 0, stream>>>(partials[t], B, offs[t], N);
        scan3_k<<<B, 256, 0, stream>>>(cnt[t], partials[t], offs[t], cursor[t], N);
        fill_k<<<cdiv(E, 256), 256, 0, stream>>>(srcP[t], dstP[t], E, cursor[t], csr[t]);
    }

    // ---- prep: casts + weight transposes ----
    for (int t = 0; t < 3; t++){
        int n = Nn[t] * Kin[t];
        cast_k<<<cdiv(n / 4, 256), 256, 0, stream>>>(xin[t], xb[t], n);
        tc_k<<<cdiv(Kin[t] * 128, 256), 256, 0, stream>>>(W_in[t], Wint[t], Kin[t], 128);
    }
    tc_k<<<cdiv(128 * 64, 256), 256, 0, stream>>>(W_fin, Wfin_t, 128, 64);
    wcat_k<<<cdiv(9 * 384 * 128, 256), 256, 0, stream>>>(Wl, Wr, Wcat_t);

    // ---- input stage ----
    for (int t = 0; t < 3; t++){
        gemm16_k<128, true, true><<<cdiv(Nn[t], 128), 256, 0, stream>>>(
            xb[t], Kin[t], xb[t], Kin[t], Kin[t], Wint[t],
            b_in[t], nullptr, o, 128, Nn[t], Kin[t], 1.0f, stats + t * 256);
        bn_k<<<cdiv(Nn[t] * 16, 256), 256, 0, stream>>>(o, stats + t * 256,
            g_in + t * 128, bt_in + t * 128, h[t], Nn[t], 1.0f / Nn[t], 0);
    }

    // ---- 3 conv layers ----
    const int e1s[3] = {1, 0, 2}, e2s[3] = {5, 3, 4};
    for (int L = 0; L < 3; L++){
        GDesc gd; int bacc = 0;
        for (int t = 0; t < 6; t++){
            gd.s[t].offs = offs[t];
            gd.s[t].csr  = csr[t];
            gd.s[t].h    = (const unsigned int*)h[srcT[t]];
            gd.s[t].A    = (unsigned int*)A[dstT[t]];
            gd.s[t].colPair = colPair_t[t];
            gd.s[t].N    = Ndst_t[t];
            gd.s[t].base = bacc;
            bacc += cdiv(Ndst_t[t], 4);
        }
        gatherall_k<<<bacc, 256, 0, stream>>>(gd);
        for (int t = 0; t < 3; t++){
            int e1 = e1s[t], e2 = e2s[t];
            const f16* wc = Wcat_t + (size_t)(L * 3 + t) * 128 * 384;
            float* st = stats + (size_t)(3 + L * 3 + t) * 256;
            gemm16_k<128, true, true><<<cdiv(Nn[t], 128), 256, 0, stream>>>(
                A[t], 256, h[t], 128, 256, wc,
                bl + (size_t)(L * 6 + e1) * 128, bl + (size_t)(L * 6 + e2) * 128,
                o, 128, Nn[t], 384, 0.5f, st);
            bn_k<<<cdiv(Nn[t] * 16, 256), 256, 0, stream>>>(o, st,
                g_conv + (size_t)(L * 3 + t) * 128, bt_conv + (size_t)(L * 3 + t) * 128,
                h[t], Nn[t], 1.0f / Nn[t], 1);
        }
    }

    // ---- final projection (fp32 out to d_out) ----
    size_t oofs[3] = {0, (size_t)ND * 64, (size_t)(ND + NG) * 64};
    for (int t = 0; t < 3; t++)
        gemm16_k<64, false, false><<<cdiv(Nn[t], 128), 256, 0, stream>>>(
            h[t], 128, h[t], 128, 128, Wfin_t,
            b_fin, nullptr, out + oofs[t], 64, Nn[t], 128, 1.0f, nullptr);
}

// Round 4
// 798.318 us; speedup vs baseline: 3.3128x; 1.2414x over previous
//
#include <hip/hip_runtime.h>
#include <cstddef>
#include <cstdint>

typedef _Float16 f16;
typedef _Float16 f16x2 __attribute__((ext_vector_type(2)));
typedef _Float16 f16x8 __attribute__((ext_vector_type(8)));
typedef float f32x4 __attribute__((ext_vector_type(4)));

#if defined(__has_builtin)
#if __has_builtin(__builtin_amdgcn_fdot2)
#define HAVE_FDOT2 1
#endif
#endif
#ifndef HAVE_FDOT2
#define HAVE_FDOT2 0
#endif

constexpr int ND = 30000, NG = 60000, NS = 15000;
constexpr float BN_EPS = 1e-5f;

static inline int cdiv(int a, int b){ return (a + b - 1) / b; }

// ================= fused CSR construction (all 6 edge types) =================

struct CsrDesc {
    const int* src[6]; const int* dst[6];
    int* cnt[6]; int* offs[6]; int* cursor[6]; int* csr[6]; int* partials[6];
    int Ebase[7];
    int N[6];
    int blkBase[7];   // scan blocks (1024 nodes per block), cumulative
};

__global__ __launch_bounds__(256) void countAll_k(CsrDesc cd){
    int e = blockIdx.x * 256 + threadIdx.x;
    if (e >= cd.Ebase[6]) return;
    int t = 0;
    #pragma unroll
    for (int i = 1; i < 6; i++) if (e >= cd.Ebase[i]) t = i;
    atomicAdd(&cd.cnt[t][cd.dst[t][e - cd.Ebase[t]]], 1);
}

__global__ __launch_bounds__(256) void scan1All_k(CsrDesc cd){
    int t = 0;
    #pragma unroll
    for (int i = 1; i < 6; i++) if ((int)blockIdx.x >= cd.blkBase[i]) t = i;
    int b = blockIdx.x - cd.blkBase[t];
    __shared__ int sh[256];
    int tid = threadIdx.x;
    int base = b * 1024 + tid * 4;
    int s = 0;
    #pragma unroll
    for (int j = 0; j < 4; j++) if (base + j < cd.N[t]) s += cd.cnt[t][base + j];
    sh[tid] = s; __syncthreads();
    for (int d = 128; d > 0; d >>= 1){
        if (tid < d) sh[tid] += sh[tid + d];
        __syncthreads();
    }
    if (tid == 0) cd.partials[t][b] = sh[0];
}

__global__ void scan2All_k(CsrDesc cd){
    int t = blockIdx.x;
    if (threadIdx.x == 0){
        int B = cd.blkBase[t + 1] - cd.blkBase[t];
        int run = 0;
        for (int i = 0; i < B; i++){ int v = cd.partials[t][i]; cd.partials[t][i] = run; run += v; }
        cd.offs[t][cd.N[t]] = run;
    }
}

__global__ __launch_bounds__(256) void scan3All_k(CsrDesc cd){
    int t = 0;
    #pragma unroll
    for (int i = 1; i < 6; i++) if ((int)blockIdx.x >= cd.blkBase[i]) t = i;
    int b = blockIdx.x - cd.blkBase[t];
    __shared__ int sh[256];
    int tid = threadIdx.x;
    int base = b * 1024 + tid * 4;
    int c[4]; int s = 0;
    #pragma unroll
    for (int j = 0; j < 4; j++){ c[j] = (base + j < cd.N[t]) ? cd.cnt[t][base + j] : 0; s += c[j]; }
    sh[tid] = s; __syncthreads();
    for (int d = 1; d < 256; d <<= 1){
        int v = sh[tid];
        int add = (tid >= d) ? sh[tid - d] : 0;
        __syncthreads();
        sh[tid] = v + add;
        __syncthreads();
    }
    int run = cd.partials[t][b] + sh[tid] - s;
    #pragma unroll
    for (int j = 0; j < 4; j++){
        if (base + j < cd.N[t]){ cd.offs[t][base + j] = run; cd.cursor[t][base + j] = run; run += c[j]; }
    }
}

__global__ __launch_bounds__(256) void fillAll_k(CsrDesc cd){
    int e = blockIdx.x * 256 + threadIdx.x;
    if (e >= cd.Ebase[6]) return;
    int t = 0;
    #pragma unroll
    for (int i = 1; i < 6; i++) if (e >= cd.Ebase[i]) t = i;
    int le = e - cd.Ebase[t];
    int d = cd.dst[t][le];
    int pos = atomicAdd(&cd.cursor[t][d], 1);
    cd.csr[t][pos] = cd.src[t][le];
}

// ================= prep: casts + weight transposes (fused) =================

struct CastDesc { const float* src[3]; f16* dst[3]; int base[4]; }; // in float4 units

__global__ __launch_bounds__(256) void castAll_k(CastDesc cdsc){
    int idx = blockIdx.x * 256 + threadIdx.x;
    if (idx >= cdsc.base[3]) return;
    int t = 0;
    #pragma unroll
    for (int i = 1; i < 3; i++) if (idx >= cdsc.base[i]) t = i;
    int i4 = (idx - cdsc.base[t]) * 4;
    float4 v = *reinterpret_cast<const float4*>(cdsc.src[t] + i4);
    union { uint2 u; f16 h[4]; } o;
    o.h[0] = (f16)v.x; o.h[1] = (f16)v.y; o.h[2] = (f16)v.z; o.h[3] = (f16)v.w;
    *reinterpret_cast<uint2*>(cdsc.dst[t] + i4) = o.u;
}

// Wint[3] (CxK, K=256/128/64), Wfin_t (64x128), Wcat_t (9 x 128 x 384)
struct WDesc {
    const float* W_in0; const float* W_in1; const float* W_in2;
    const float* W_fin; const float* Wl; const float* Wr;
    f16* Wint0; f16* Wint1; f16* Wint2; f16* Wfin_t; f16* Wcat_t;
};

__global__ __launch_bounds__(256) void weightAll_k(WDesc wd){
    int idx = blockIdx.x * 256 + threadIdx.x;
    // ranges: [0,32768) Wint0; [32768,49152) Wint1; [49152,57344) Wint2;
    //         [57344,65536) Wfin; [65536,507904) Wcat
    if (idx < 32768){
        int c = idx >> 8, k = idx & 255;
        wd.Wint0[idx] = (f16)wd.W_in0[k * 128 + c];
    } else if (idx < 49152){
        int l = idx - 32768; int c = l >> 7, k = l & 127;
        wd.Wint1[l] = (f16)wd.W_in1[k * 128 + c];
    } else if (idx < 57344){
        int l = idx - 49152; int c = l >> 6, k = l & 63;
        wd.Wint2[l] = (f16)wd.W_in2[k * 128 + c];
    } else if (idx < 65536){
        int l = idx - 57344; int c = l >> 7, k = l & 127;   // 64 cols x 128 k
        wd.Wfin_t[l] = (f16)wd.W_fin[k * 64 + c];
    } else if (idx < 507904){
        int l = idx - 65536;
        int g = l / (384 * 128);
        int rem = l - g * (384 * 128);
        int c = rem / 384;
        int k = rem - c * 384;
        int L = g / 3, t = g - L * 3;
        const int e1s[3] = {1, 0, 2}, e2s[3] = {5, 3, 4};
        int e1 = e1s[t], e2 = e2s[t];
        float v;
        if (k < 128)      v = wd.Wl[(((size_t)L * 6 + e1) * 128 + k) * 128 + c];
        else if (k < 256) v = wd.Wl[(((size_t)L * 6 + e2) * 128 + (k - 128)) * 128 + c];
        else {
            int kr = k - 256;
            v = wd.Wr[(((size_t)L * 6 + e1) * 128 + kr) * 128 + c]
              + wd.Wr[(((size_t)L * 6 + e2) * 128 + kr) * 128 + c];
        }
        wd.Wcat_t[l] = (f16)v;
    }
}

// ================= fused gather-mean over all 6 edge types =================

struct GSeg { const int* offs; const int* csr; const unsigned int* h; unsigned int* A; int colPair; int N; int base; };
struct GDesc { GSeg s[6]; };

__device__ __forceinline__ void acc_u(unsigned int v, float& a0, float& a1){
    union { unsigned int u; f16x2 h; } c; c.u = v;
#if HAVE_FDOT2
    const f16x2 e0 = {(f16)1.f, (f16)0.f};
    const f16x2 e1 = {(f16)0.f, (f16)1.f};
    a0 = __builtin_amdgcn_fdot2(c.h, e0, a0, false);
    a1 = __builtin_amdgcn_fdot2(c.h, e1, a1, false);
#else
    a0 += (float)c.h[0]; a1 += (float)c.h[1];
#endif
}

__global__ __launch_bounds__(256) void gatherall_k(GDesc gd){
    int bid = blockIdx.x;
    int si = 0;
    #pragma unroll
    for (int t = 1; t < 6; t++) if (bid >= gd.s[t].base) si = t;
    GSeg sg = gd.s[si];
    int node = (bid - sg.base) * 4 + (threadIdx.x >> 6);
    int lane = threadIdx.x & 63;
    if (node >= sg.N) return;
    int s = sg.offs[node], e = sg.offs[node + 1];
    const int* cp = sg.csr;
    const unsigned int* hp = sg.h;
    float a0 = 0.f, a1 = 0.f;
    int j = s;
    for (; j + 8 <= e; j += 8){
        int i0 = cp[j+0], i1 = cp[j+1], i2 = cp[j+2], i3 = cp[j+3];
        int i4 = cp[j+4], i5 = cp[j+5], i6 = cp[j+6], i7 = cp[j+7];
        unsigned int w0 = hp[(size_t)i0 * 64 + lane];
        unsigned int w1 = hp[(size_t)i1 * 64 + lane];
        unsigned int w2 = hp[(size_t)i2 * 64 + lane];
        unsigned int w3 = hp[(size_t)i3 * 64 + lane];
        unsigned int w4 = hp[(size_t)i4 * 64 + lane];
        unsigned int w5 = hp[(size_t)i5 * 64 + lane];
        unsigned int w6 = hp[(size_t)i6 * 64 + lane];
        unsigned int w7 = hp[(size_t)i7 * 64 + lane];
        acc_u(w0, a0, a1); acc_u(w1, a0, a1); acc_u(w2, a0, a1); acc_u(w3, a0, a1);
        acc_u(w4, a0, a1); acc_u(w5, a0, a1); acc_u(w6, a0, a1); acc_u(w7, a0, a1);
    }
    if (j + 4 <= e){
        int i0 = cp[j+0], i1 = cp[j+1], i2 = cp[j+2], i3 = cp[j+3];
        unsigned int w0 = hp[(size_t)i0 * 64 + lane];
        unsigned int w1 = hp[(size_t)i1 * 64 + lane];
        unsigned int w2 = hp[(size_t)i2 * 64 + lane];
        unsigned int w3 = hp[(size_t)i3 * 64 + lane];
        acc_u(w0, a0, a1); acc_u(w1, a0, a1); acc_u(w2, a0, a1); acc_u(w3, a0, a1);
        j += 4;
    }
    if (j + 2 <= e){
        int i0 = cp[j+0], i1 = cp[j+1];
        unsigned int w0 = hp[(size_t)i0 * 64 + lane];
        unsigned int w1 = hp[(size_t)i1 * 64 + lane];
        acc_u(w0, a0, a1); acc_u(w1, a0, a1);
        j += 2;
    }
    if (j < e) acc_u(hp[(size_t)cp[j] * 64 + lane], a0, a1);
    float inv = (e > s) ? 1.0f / (float)(e - s) : 0.f;
    union { unsigned int u; f16 h[2]; } o;
    o.h[0] = (f16)(a0 * inv); o.h[1] = (f16)(a1 * inv);
    sg.A[(size_t)node * 128 + sg.colPair + lane] = o.u;
}

// ================= merged MFMA fp16 GEMM (up to 3 segments) =================

struct GemmSeg {
    const f16* A1; const f16* A2; const f16* Wt;
    const float* b1; const float* b2; void* out; float* stats;
    int lda1, lda2, ksplit, N, K, tileBase; float scale;
};
struct GemmDesc { GemmSeg s[3]; };

template<int BN, bool STATS, bool OUT16>
__global__ __launch_bounds__(256) void gemmAll_k(GemmDesc gd){
    constexpr int BK = 64, PAD = 72, CF = BN / 16;
    __shared__ f16 As[128 * PAD];
    __shared__ f16 Bs[BN * PAD];
    __shared__ float ssum[BN];
    __shared__ float ssq[BN];
    int bid = blockIdx.x;
    int si = 0;
    #pragma unroll
    for (int t = 1; t < 3; t++) if (bid >= gd.s[t].tileBase) si = t;
    GemmSeg sg = gd.s[si];
    int tid = threadIdx.x;
    int wv = tid >> 6, lane = tid & 63;
    int row0 = (bid - sg.tileBase) * 128;
    int N = sg.N, K = sg.K;
    if (STATS && tid < BN){ ssum[tid] = 0.f; ssq[tid] = 0.f; }

    f32x4 acc[2][CF];
    #pragma unroll
    for (int rf = 0; rf < 2; rf++)
        #pragma unroll
        for (int cf = 0; cf < CF; cf++)
            acc[rf][cf] = (f32x4){0.f, 0.f, 0.f, 0.f};

    for (int k0 = 0; k0 < K; k0 += BK){
        const f16* Ab; int lda, kloc;
        if (k0 < sg.ksplit){ Ab = sg.A1; lda = sg.lda1; kloc = k0; }
        else               { Ab = sg.A2; lda = sg.lda2; kloc = k0 - sg.ksplit; }
        #pragma unroll
        for (int p = 0; p < 4; p++){
            int f = tid + p * 256;
            int r = f >> 3, sgm = f & 7;
            int gr = row0 + r;
            uint4 v = make_uint4(0u, 0u, 0u, 0u);
            if (gr < N) v = *reinterpret_cast<const uint4*>(Ab + (size_t)gr * lda + kloc + sgm * 8);
            *reinterpret_cast<uint4*>(As + r * PAD + sgm * 8) = v;
        }
        #pragma unroll
        for (int p = 0; p < BN / 32; p++){
            int f = tid + p * 256;
            int r = f >> 3, sgm = f & 7;
            uint4 v = *reinterpret_cast<const uint4*>(sg.Wt + (size_t)r * K + k0 + sgm * 8);
            *reinterpret_cast<uint4*>(Bs + r * PAD + sgm * 8) = v;
        }
        __syncthreads();
        #pragma unroll
        for (int kf = 0; kf < 2; kf++){
            int kb = kf * 32 + (lane >> 4) * 8;
            f16x8 a0 = *reinterpret_cast<const f16x8*>(As + (wv * 32 + (lane & 15)) * PAD + kb);
            f16x8 a1 = *reinterpret_cast<const f16x8*>(As + (wv * 32 + 16 + (lane & 15)) * PAD + kb);
            #pragma unroll
            for (int cf = 0; cf < CF; cf++){
                f16x8 b = *reinterpret_cast<const f16x8*>(Bs + (cf * 16 + (lane & 15)) * PAD + kb);
                acc[0][cf] = __builtin_amdgcn_mfma_f32_16x16x32_f16(a0, b, acc[0][cf], 0, 0, 0);
                acc[1][cf] = __builtin_amdgcn_mfma_f32_16x16x32_f16(a1, b, acc[1][cf], 0, 0, 0);
            }
        }
        __syncthreads();
    }
    int rbase = row0 + wv * 32 + ((lane >> 4) << 2);
    #pragma unroll
    for (int cf = 0; cf < CF; cf++){
        int col = cf * 16 + (lane & 15);
        float bias = 0.f;
        if (sg.b1) bias += sg.b1[col];
        if (sg.b2) bias += sg.b2[col];
        float ls = 0.f, lq = 0.f;
        #pragma unroll
        for (int rf = 0; rf < 2; rf++){
            #pragma unroll
            for (int q = 0; q < 4; q++){
                int gr = rbase + rf * 16 + q;
                if (gr < N){
                    float v = sg.scale * (acc[rf][cf][q] + bias);
                    if (OUT16) ((f16*)sg.out)[(size_t)gr * BN + col] = (f16)v;
                    else       ((float*)sg.out)[(size_t)gr * BN + col] = v;
                    ls += v; lq += v * v;
                }
            }
        }
        if (STATS){ atomicAdd(&ssum[col], ls); atomicAdd(&ssq[col], lq); }
    }
    if (STATS){
        __syncthreads();
        if (tid < BN){
            atomicAdd(&sg.stats[tid], ssum[tid]);
            atomicAdd(&sg.stats[128 + tid], ssq[tid]);
        }
    }
}

// ================= merged BN apply + ReLU (+ residual) =================

struct BnSeg { const f16* o; const float* stats; const float* g; const float* b; f16* h; int N; float invN; int residual; int idxBase; };
struct BnDesc { BnSeg s[3]; int total; };

__global__ __launch_bounds__(256) void bnAll_k(BnDesc bd){
    int idx = blockIdx.x * 256 + threadIdx.x;
    if (idx >= bd.total) return;
    int si = 0;
    #pragma unroll
    for (int t = 1; t < 3; t++) if (idx >= bd.s[t].idxBase) si = t;
    BnSeg sg = bd.s[si];
    int l = idx - sg.idxBase;
    int n = l >> 4, c8 = (l & 15) * 8;
    union { uint4 u; f16 h[8]; } ov;
    ov.u = *reinterpret_cast<const uint4*>(sg.o + (size_t)n * 128 + c8);
    float r[8];
    #pragma unroll
    for (int j = 0; j < 8; j++){
        int c = c8 + j;
        float mu  = sg.stats[c] * sg.invN;
        float var = sg.stats[128 + c] * sg.invN - mu * mu;
        float v = ((float)ov.h[j] - mu) * rsqrtf(var + BN_EPS) * sg.g[c] + sg.b[c];
        r[j] = v > 0.f ? v : 0.f;
    }
    f16* hp = sg.h + (size_t)n * 128 + c8;
    if (sg.residual){
        uint4 old = *reinterpret_cast<const uint4*>(hp);
        union { uint4 u; f16 h[8]; } ou; ou.u = old;
        #pragma unroll
        for (int j = 0; j < 8; j++) r[j] += (float)ou.h[j];
    }
    union { uint4 u; f16 h[8]; } pk;
    #pragma unroll
    for (int j = 0; j < 8; j++) pk.h[j] = (f16)r[j];
    *reinterpret_cast<uint4*>(hp) = pk.u;
}

// ================= host orchestration =================

extern "C" void kernel_launch(void* const* d_in, const int* in_sizes, int n_in,
                              void* d_out, int out_size, void* d_ws, size_t ws_size,
                              hipStream_t stream){
    const float* x_drug = (const float*)d_in[0];
    const float* x_gene = (const float*)d_in[1];
    const float* x_dis  = (const float*)d_in[2];
    const int* srcP[6] = {(const int*)d_in[3], (const int*)d_in[5], (const int*)d_in[7],
                          (const int*)d_in[9], (const int*)d_in[11], (const int*)d_in[13]};
    const int* dstP[6] = {(const int*)d_in[4], (const int*)d_in[6], (const int*)d_in[8],
                          (const int*)d_in[10], (const int*)d_in[12], (const int*)d_in[14]};
    const int  Et[6]   = {in_sizes[3], in_sizes[5], in_sizes[7], in_sizes[9], in_sizes[11], in_sizes[13]};
    const float* W_in[3] = {(const float*)d_in[15], (const float*)d_in[17], (const float*)d_in[19]};
    const float* b_in[3] = {(const float*)d_in[16], (const float*)d_in[18], (const float*)d_in[20]};
    const float* g_in  = (const float*)d_in[21];
    const float* bt_in = (const float*)d_in[22];
    const float* Wl    = (const float*)d_in[23];
    const float* Wr    = (const float*)d_in[24];
    const float* bl    = (const float*)d_in[25];
    const float* g_conv  = (const float*)d_in[26];
    const float* bt_conv = (const float*)d_in[27];
    const float* W_fin = (const float*)d_in[28];
    const float* b_fin = (const float*)d_in[29];
    float* out = (float*)d_out;

    // edge-type metadata (order: dg, gd, gs, sg, ds, sd)
    const int Ndst_t[6]    = {NG, ND, NS, NG, NS, ND};
    const int srcT[6]      = {0, 1, 1, 2, 0, 2};
    const int dstT[6]      = {1, 0, 2, 1, 2, 0};
    const int colPair_t[6] = {0, 0, 0, 64, 64, 64};

    const int Nn[3]  = {ND, NG, NS};
    const int Kin[3] = {256, 128, 64};
    const float* xin[3] = {x_drug, x_gene, x_dis};

    // ---- workspace carve ----
    char* base = (char*)d_ws;
    size_t off = 0;
    auto alloc = [&](size_t bytes) -> char* {
        char* p = base + off; off += (bytes + 255) & ~(size_t)255; return p;
    };
    f16* h[3];  for (int t = 0; t < 3; t++) h[t]  = (f16*)alloc((size_t)Nn[t] * 128 * 2); // contiguous pool
    f16* A[3];  for (int t = 0; t < 3; t++) A[t]  = (f16*)alloc((size_t)Nn[t] * 256 * 2);
    f16* xb[3]; for (int t = 0; t < 3; t++) xb[t] = (f16*)alloc((size_t)Nn[t] * Kin[t] * 2);
    f16* Wint[3]; for (int t = 0; t < 3; t++) Wint[t] = (f16*)alloc((size_t)128 * Kin[t] * 2);
    f16* Wfin_t = (f16*)alloc((size_t)64 * 128 * 2);
    f16* Wcat_t = (f16*)alloc((size_t)9 * 128 * 384 * 2);
    f16* o[3];  for (int t = 0; t < 3; t++) o[t] = (f16*)alloc((size_t)Nn[t] * 128 * 2);
    float* stats = (float*)alloc(12 * 256 * 4);
    // pooled CSR int arrays: cnt pool first (single memset)
    int cntTot = 0; for (int t = 0; t < 6; t++) cntTot += Ndst_t[t];
    int* cntPool = (int*)alloc((size_t)cntTot * 4);
    int* cnt[6]; { int a = 0; for (int t = 0; t < 6; t++){ cnt[t] = cntPool + a; a += Ndst_t[t]; } }
    int *offs[6], *cursor[6], *csr[6], *partials[6];
    for (int t = 0; t < 6; t++) offs[t]   = (int*)alloc((size_t)(Ndst_t[t] + 1) * 4);
    for (int t = 0; t < 6; t++) cursor[t] = (int*)alloc((size_t)Ndst_t[t] * 4);
    for (int t = 0; t < 6; t++) partials[t] = (int*)alloc(64 * 4);
    for (int t = 0; t < 6; t++) csr[t]    = (int*)alloc((size_t)Et[t] * 4);

    hipMemsetAsync(cntPool, 0, (size_t)cntTot * 4, stream);
    hipMemsetAsync(stats, 0, 12 * 256 * 4, stream);

    // ---- CSR descriptor ----
    CsrDesc cd;
    {
        int ecum = 0, bcum = 0;
        for (int t = 0; t < 6; t++){
            cd.src[t] = srcP[t]; cd.dst[t] = dstP[t];
            cd.cnt[t] = cnt[t]; cd.offs[t] = offs[t]; cd.cursor[t] = cursor[t];
            cd.csr[t] = csr[t]; cd.partials[t] = partials[t];
            cd.Ebase[t] = ecum; ecum += Et[t];
            cd.N[t] = Ndst_t[t];
            cd.blkBase[t] = bcum; bcum += cdiv(Ndst_t[t], 1024);
        }
        cd.Ebase[6] = ecum; cd.blkBase[6] = bcum;
    }
    countAll_k<<<cdiv(cd.Ebase[6], 256), 256, 0, stream>>>(cd);
    scan1All_k<<<cd.blkBase[6], 256, 0, stream>>>(cd);
    scan2All_k<<<6, 64, 0, stream>>>(cd);
    scan3All_k<<<cd.blkBase[6], 256, 0, stream>>>(cd);
    fillAll_k<<<cdiv(cd.Ebase[6], 256), 256, 0, stream>>>(cd);

    // ---- casts + weights ----
    CastDesc cds;
    {
        int b = 0;
        for (int t = 0; t < 3; t++){
            cds.src[t] = xin[t]; cds.dst[t] = xb[t];
            cds.base[t] = b; b += Nn[t] * Kin[t] / 4;
        }
        cds.base[3] = b;
    }
    castAll_k<<<cdiv(cds.base[3], 256), 256, 0, stream>>>(cds);
    WDesc wd = {W_in[0], W_in[1], W_in[2], W_fin, Wl, Wr,
                Wint[0], Wint[1], Wint[2], Wfin_t, Wcat_t};
    weightAll_k<<<cdiv(507904, 256), 256, 0, stream>>>(wd);

    int tiles[3]; for (int t = 0; t < 3; t++) tiles[t] = cdiv(Nn[t], 128);
    int tileBase[4] = {0, tiles[0], tiles[0] + tiles[1], tiles[0] + tiles[1] + tiles[2]};

    // ---- input stage ----
    {
        GemmDesc g{};
        for (int t = 0; t < 3; t++){
            g.s[t] = {xb[t], xb[t], Wint[t], b_in[t], nullptr, o[t], stats + t * 256,
                      Kin[t], Kin[t], Kin[t], Nn[t], Kin[t], tileBase[t], 1.0f};
        }
        gemmAll_k<128, true, true><<<tileBase[3], 256, 0, stream>>>(g);
        BnDesc bd{}; int ib = 0;
        for (int t = 0; t < 3; t++){
            bd.s[t] = {o[t], stats + t * 256, g_in + t * 128, bt_in + t * 128, h[t],
                       Nn[t], 1.0f / Nn[t], 0, ib};
            ib += Nn[t] * 16;
        }
        bd.total = ib;
        bnAll_k<<<cdiv(ib, 256), 256, 0, stream>>>(bd);
    }

    // ---- 3 conv layers ----
    const int e1s[3] = {1, 0, 2}, e2s[3] = {5, 3, 4};
    for (int L = 0; L < 3; L++){
        GDesc gd; int bacc = 0;
        for (int t = 0; t < 6; t++){
            gd.s[t].offs = offs[t];
            gd.s[t].csr  = csr[t];
            gd.s[t].h    = (const unsigned int*)h[srcT[t]];
            gd.s[t].A    = (unsigned int*)A[dstT[t]];
            gd.s[t].colPair = colPair_t[t];
            gd.s[t].N    = Ndst_t[t];
            gd.s[t].base = bacc;
            bacc += cdiv(Ndst_t[t], 4);
        }
        gatherall_k<<<bacc, 256, 0, stream>>>(gd);
        GemmDesc g{};
        for (int t = 0; t < 3; t++){
            int e1 = e1s[t], e2 = e2s[t];
            g.s[t] = {A[t], h[t], Wcat_t + (size_t)(L * 3 + t) * 128 * 384,
                      bl + (size_t)(L * 6 + e1) * 128, bl + (size_t)(L * 6 + e2) * 128,
                      o[t], stats + (size_t)(3 + L * 3 + t) * 256,
                      256, 128, 256, Nn[t], 384, tileBase[t], 0.5f};
        }
        gemmAll_k<128, true, true><<<tileBase[3], 256, 0, stream>>>(g);
        BnDesc bd{}; int ib = 0;
        for (int t = 0; t < 3; t++){
            bd.s[t] = {o[t], stats + (size_t)(3 + L * 3 + t) * 256,
                       g_conv + (size_t)(L * 3 + t) * 128, bt_conv + (size_t)(L * 3 + t) * 128,
                       h[t], Nn[t], 1.0f / Nn[t], 1, ib};
            ib += Nn[t] * 16;
        }
        bd.total = ib;
        bnAll_k<<<cdiv(ib, 256), 256, 0, stream>>>(bd);
    }

    // ---- final projection: one GEMM over contiguous h pool (105000 x 128 @ 128 x 64) ----
    {
        int Ntot = ND + NG + NS;
        GemmDesc g{};
        g.s[0] = {h[0], h[0], Wfin_t, b_fin, nullptr, out, nullptr,
                  128, 128, 128, Ntot, 128, 0, 1.0f};
        g.s[1] = g.s[0]; g.s[1].tileBase = 0x3FFFFFFF; g.s[1].N = 0;
        g.s[2] = g.s[1];
        gemmAll_k<64, false, false><<<cdiv(Ntot, 128), 256, 0, stream>>>(g);
    }
}

// Round 5
// 725.132 us; speedup vs baseline: 3.6472x; 1.1009x over previous
//
#include <hip/hip_runtime.h>
#include <cstddef>
#include <cstdint>

typedef _Float16 f16;
typedef _Float16 f16x2 __attribute__((ext_vector_type(2)));
typedef _Float16 f16x8 __attribute__((ext_vector_type(8)));
typedef float f32x4 __attribute__((ext_vector_type(4)));

#if defined(__has_builtin)
#if __has_builtin(__builtin_amdgcn_fdot2)
#define HAVE_FDOT2 1
#endif
#endif
#ifndef HAVE_FDOT2
#define HAVE_FDOT2 0
#endif

constexpr int ND = 30000, NG = 60000, NS = 15000;
constexpr float BN_EPS = 1e-5f;
constexpr int NBUCK = 64;      // buckets per edge type
constexpr int TBUCK = 6 * NBUCK;
constexpr int PCHUNK = 4096;   // edges per partition block

static inline int cdiv(int a, int b){ return (a + b - 1) / b; }

// ================= bucketed CSR construction =================
// Pass 1: histogram over 384 dst-range buckets (LDS-aggregated).
// Pass 2: scan. Pass 3: partition edges into bucket-grouped packed (src,dst).
// Pass 4/5: count + fill on the bucketed stream (cursor/csr accesses L2-local).

struct BDesc {
    const int* src[6]; const int* dst[6];
    int Ebase[7]; int shift[6];
    int* bCnt; int* bBase; int* bCursor;
    uint2* packed;
    int* cnt[6]; int* cursor[6]; int* csr[6];
};

__global__ __launch_bounds__(256) void bhist_k(BDesc bd){
    __shared__ int hist[TBUCK];
    int tid = threadIdx.x;
    for (int i = tid; i < TBUCK; i += 256) hist[i] = 0;
    __syncthreads();
    int Etot = bd.Ebase[6];
    #pragma unroll
    for (int u = 0; u < 16; u++){
        int e = blockIdx.x * PCHUNK + u * 256 + tid;
        if (e < Etot){
            int t = 0;
            #pragma unroll
            for (int i = 1; i < 6; i++) if (e >= bd.Ebase[i]) t = i;
            int d = bd.dst[t][e - bd.Ebase[t]];
            atomicAdd(&hist[t * NBUCK + (d >> bd.shift[t])], 1);
        }
    }
    __syncthreads();
    for (int i = tid; i < TBUCK; i += 256)
        if (hist[i]) atomicAdd(&bd.bCnt[i], hist[i]);
}

__global__ __launch_bounds__(512) void bscan_k(BDesc bd){
    __shared__ int sh[TBUCK];
    int tid = threadIdx.x;
    int my = (tid < TBUCK) ? bd.bCnt[tid] : 0;
    if (tid < TBUCK) sh[tid] = my;
    __syncthreads();
    for (int d = 1; d < TBUCK; d <<= 1){
        int v = (tid < TBUCK) ? sh[tid] : 0;
        int add = (tid >= d && tid < TBUCK) ? sh[tid - d] : 0;
        __syncthreads();
        if (tid < TBUCK) sh[tid] = v + add;
        __syncthreads();
    }
    if (tid < TBUCK){
        int excl = sh[tid] - my;
        bd.bBase[tid] = excl;
        bd.bCursor[tid] = excl;
    }
    if (tid == 0) bd.bBase[TBUCK] = sh[TBUCK - 1];
}

__global__ __launch_bounds__(256) void bpart_k(BDesc bd){
    __shared__ int hist[TBUCK];
    __shared__ int basesh[TBUCK];
    int tid = threadIdx.x;
    for (int i = tid; i < TBUCK; i += 256) hist[i] = 0;
    __syncthreads();
    int Etot = bd.Ebase[6];
    int mb[16], mr[16], ms[16], md[16];
    #pragma unroll
    for (int u = 0; u < 16; u++){
        int e = blockIdx.x * PCHUNK + u * 256 + tid;
        mb[u] = -1;
        if (e < Etot){
            int t = 0;
            #pragma unroll
            for (int i = 1; i < 6; i++) if (e >= bd.Ebase[i]) t = i;
            int le = e - bd.Ebase[t];
            int s = bd.src[t][le], d = bd.dst[t][le];
            int b = t * NBUCK + (d >> bd.shift[t]);
            mr[u] = atomicAdd(&hist[b], 1);
            mb[u] = b; ms[u] = s; md[u] = d;
        }
    }
    __syncthreads();
    for (int i = tid; i < TBUCK; i += 256)
        basesh[i] = hist[i] ? atomicAdd(&bd.bCursor[i], hist[i]) : 0;
    __syncthreads();
    #pragma unroll
    for (int u = 0; u < 16; u++){
        if (mb[u] >= 0){
            int pos = basesh[mb[u]] + mr[u];
            bd.packed[pos] = make_uint2((unsigned)ms[u], (unsigned)md[u]);
        }
    }
}

__global__ __launch_bounds__(256) void countB_k(BDesc bd){
    int e = blockIdx.x * 256 + threadIdx.x;
    if (e >= bd.Ebase[6]) return;
    int t = 0;
    #pragma unroll
    for (int i = 1; i < 6; i++) if (e >= bd.Ebase[i]) t = i;
    atomicAdd(&bd.cnt[t][bd.packed[e].y], 1);
}

__global__ __launch_bounds__(256) void fillB_k(BDesc bd){
    int e = blockIdx.x * 256 + threadIdx.x;
    if (e >= bd.Ebase[6]) return;
    int t = 0;
    #pragma unroll
    for (int i = 1; i < 6; i++) if (e >= bd.Ebase[i]) t = i;
    uint2 p = bd.packed[e];
    int pos = atomicAdd(&bd.cursor[t][p.y], 1);
    bd.csr[t][pos] = (int)p.x;
}

// ================= per-node offset scans (unchanged structure) =================

struct ScanDesc {
    int* cnt[6]; int* offs[6]; int* cursor[6]; int* partials[6];
    int N[6]; int blkBase[7];
};

__global__ __launch_bounds__(256) void scan1All_k(ScanDesc cd){
    int t = 0;
    #pragma unroll
    for (int i = 1; i < 6; i++) if ((int)blockIdx.x >= cd.blkBase[i]) t = i;
    int b = blockIdx.x - cd.blkBase[t];
    __shared__ int sh[256];
    int tid = threadIdx.x;
    int base = b * 1024 + tid * 4;
    int s = 0;
    #pragma unroll
    for (int j = 0; j < 4; j++) if (base + j < cd.N[t]) s += cd.cnt[t][base + j];
    sh[tid] = s; __syncthreads();
    for (int d = 128; d > 0; d >>= 1){
        if (tid < d) sh[tid] += sh[tid + d];
        __syncthreads();
    }
    if (tid == 0) cd.partials[t][b] = sh[0];
}

__global__ void scan2All_k(ScanDesc cd){
    int t = blockIdx.x;
    if (threadIdx.x == 0){
        int B = cd.blkBase[t + 1] - cd.blkBase[t];
        int run = 0;
        for (int i = 0; i < B; i++){ int v = cd.partials[t][i]; cd.partials[t][i] = run; run += v; }
        cd.offs[t][cd.N[t]] = run;
    }
}

__global__ __launch_bounds__(256) void scan3All_k(ScanDesc cd){
    int t = 0;
    #pragma unroll
    for (int i = 1; i < 6; i++) if ((int)blockIdx.x >= cd.blkBase[i]) t = i;
    int b = blockIdx.x - cd.blkBase[t];
    __shared__ int sh[256];
    int tid = threadIdx.x;
    int base = b * 1024 + tid * 4;
    int c[4]; int s = 0;
    #pragma unroll
    for (int j = 0; j < 4; j++){ c[j] = (base + j < cd.N[t]) ? cd.cnt[t][base + j] : 0; s += c[j]; }
    sh[tid] = s; __syncthreads();
    for (int d = 1; d < 256; d <<= 1){
        int v = sh[tid];
        int add = (tid >= d) ? sh[tid - d] : 0;
        __syncthreads();
        sh[tid] = v + add;
        __syncthreads();
    }
    int run = cd.partials[t][b] + sh[tid] - s;
    #pragma unroll
    for (int j = 0; j < 4; j++){
        if (base + j < cd.N[t]){ cd.offs[t][base + j] = run; cd.cursor[t][base + j] = run; run += c[j]; }
    }
}

// ================= prep: casts + weight transposes =================

struct CastDesc { const float* src[3]; f16* dst[3]; int base[4]; };

__global__ __launch_bounds__(256) void castAll_k(CastDesc cdsc){
    int idx = blockIdx.x * 256 + threadIdx.x;
    if (idx >= cdsc.base[3]) return;
    int t = 0;
    #pragma unroll
    for (int i = 1; i < 3; i++) if (idx >= cdsc.base[i]) t = i;
    int i4 = (idx - cdsc.base[t]) * 4;
    float4 v = *reinterpret_cast<const float4*>(cdsc.src[t] + i4);
    union { uint2 u; f16 h[4]; } o;
    o.h[0] = (f16)v.x; o.h[1] = (f16)v.y; o.h[2] = (f16)v.z; o.h[3] = (f16)v.w;
    *reinterpret_cast<uint2*>(cdsc.dst[t] + i4) = o.u;
}

struct WDesc {
    const float* W_in0; const float* W_in1; const float* W_in2;
    const float* W_fin; const float* Wl; const float* Wr;
    f16* Wint0; f16* Wint1; f16* Wint2; f16* Wfin_t; f16* Wcat_t;
};

__global__ __launch_bounds__(256) void weightAll_k(WDesc wd){
    int idx = blockIdx.x * 256 + threadIdx.x;
    if (idx < 32768){
        int c = idx >> 8, k = idx & 255;
        wd.Wint0[idx] = (f16)wd.W_in0[k * 128 + c];
    } else if (idx < 49152){
        int l = idx - 32768; int c = l >> 7, k = l & 127;
        wd.Wint1[l] = (f16)wd.W_in1[k * 128 + c];
    } else if (idx < 57344){
        int l = idx - 49152; int c = l >> 6, k = l & 63;
        wd.Wint2[l] = (f16)wd.W_in2[k * 128 + c];
    } else if (idx < 65536){
        int l = idx - 57344; int c = l >> 7, k = l & 127;
        wd.Wfin_t[l] = (f16)wd.W_fin[k * 64 + c];
    } else if (idx < 507904){
        int l = idx - 65536;
        int g = l / (384 * 128);
        int rem = l - g * (384 * 128);
        int c = rem / 384;
        int k = rem - c * 384;
        int L = g / 3, t = g - L * 3;
        const int e1s[3] = {1, 0, 2}, e2s[3] = {5, 3, 4};
        int e1 = e1s[t], e2 = e2s[t];
        float v;
        if (k < 128)      v = wd.Wl[(((size_t)L * 6 + e1) * 128 + k) * 128 + c];
        else if (k < 256) v = wd.Wl[(((size_t)L * 6 + e2) * 128 + (k - 128)) * 128 + c];
        else {
            int kr = k - 256;
            v = wd.Wr[(((size_t)L * 6 + e1) * 128 + kr) * 128 + c]
              + wd.Wr[(((size_t)L * 6 + e2) * 128 + kr) * 128 + c];
        }
        wd.Wcat_t[l] = (f16)v;
    }
}

// ================= fused gather-mean (edge-pair waves, uint2 loads) =================
// 64 lanes per node: lanes 0-31 read neighbor row j, lanes 32-63 row j+1.
// Each lane loads uint2 (4 f16). Halves combined via shfl_xor(32) at the end.

struct GSeg { const int* offs; const int* csr; const uint2* h; uint2* A; int colPair2; int N; int base; };
struct GDesc { GSeg s[6]; };

__device__ __forceinline__ void accp(uint2 v, float& a0, float& a1, float& a2, float& a3){
    union { unsigned u; f16x2 h; } cx, cy; cx.u = v.x; cy.u = v.y;
#if HAVE_FDOT2
    const f16x2 e0 = {(f16)1.f, (f16)0.f};
    const f16x2 e1 = {(f16)0.f, (f16)1.f};
    a0 = __builtin_amdgcn_fdot2(cx.h, e0, a0, false);
    a1 = __builtin_amdgcn_fdot2(cx.h, e1, a1, false);
    a2 = __builtin_amdgcn_fdot2(cy.h, e0, a2, false);
    a3 = __builtin_amdgcn_fdot2(cy.h, e1, a3, false);
#else
    a0 += (float)cx.h[0]; a1 += (float)cx.h[1];
    a2 += (float)cy.h[0]; a3 += (float)cy.h[1];
#endif
}

__global__ __launch_bounds__(256) void gatherall_k(GDesc gd){
    int bid = blockIdx.x;
    int si = 0;
    #pragma unroll
    for (int t = 1; t < 6; t++) if (bid >= gd.s[t].base) si = t;
    GSeg sg = gd.s[si];
    int node = (bid - sg.base) * 4 + (threadIdx.x >> 6);
    if (node >= sg.N) return;
    int lane = threadIdx.x & 63;
    int half = lane >> 5;
    int l = lane & 31;
    int s = sg.offs[node], e = sg.offs[node + 1];
    const int* cp = sg.csr;
    const uint2* hp = sg.h;
    float a0 = 0.f, a1 = 0.f, a2 = 0.f, a3 = 0.f;
    int j = s;
    for (; j + 16 <= e; j += 16){
        int i0 = cp[j +      half], i1 = cp[j + 2  + half], i2 = cp[j + 4  + half], i3 = cp[j + 6  + half];
        int i4 = cp[j + 8  + half], i5 = cp[j + 10 + half], i6 = cp[j + 12 + half], i7 = cp[j + 14 + half];
        uint2 v0 = hp[(size_t)i0 * 32 + l], v1 = hp[(size_t)i1 * 32 + l];
        uint2 v2 = hp[(size_t)i2 * 32 + l], v3 = hp[(size_t)i3 * 32 + l];
        uint2 v4 = hp[(size_t)i4 * 32 + l], v5 = hp[(size_t)i5 * 32 + l];
        uint2 v6 = hp[(size_t)i6 * 32 + l], v7 = hp[(size_t)i7 * 32 + l];
        accp(v0, a0, a1, a2, a3); accp(v1, a0, a1, a2, a3);
        accp(v2, a0, a1, a2, a3); accp(v3, a0, a1, a2, a3);
        accp(v4, a0, a1, a2, a3); accp(v5, a0, a1, a2, a3);
        accp(v6, a0, a1, a2, a3); accp(v7, a0, a1, a2, a3);
    }
    if (j + 8 <= e){
        int i0 = cp[j + half], i1 = cp[j + 2 + half], i2 = cp[j + 4 + half], i3 = cp[j + 6 + half];
        uint2 v0 = hp[(size_t)i0 * 32 + l], v1 = hp[(size_t)i1 * 32 + l];
        uint2 v2 = hp[(size_t)i2 * 32 + l], v3 = hp[(size_t)i3 * 32 + l];
        accp(v0, a0, a1, a2, a3); accp(v1, a0, a1, a2, a3);
        accp(v2, a0, a1, a2, a3); accp(v3, a0, a1, a2, a3);
        j += 8;
    }
    if (j + 4 <= e){
        int i0 = cp[j + half], i1 = cp[j + 2 + half];
        uint2 v0 = hp[(size_t)i0 * 32 + l], v1 = hp[(size_t)i1 * 32 + l];
        accp(v0, a0, a1, a2, a3); accp(v1, a0, a1, a2, a3);
        j += 4;
    }
    if (j + 2 <= e){
        int i0 = cp[j + half];
        uint2 v0 = hp[(size_t)i0 * 32 + l];
        accp(v0, a0, a1, a2, a3);
        j += 2;
    }
    if (j < e && half == 0){
        int idx = cp[j];
        accp(hp[(size_t)idx * 32 + l], a0, a1, a2, a3);
    }
    a0 += __shfl_xor(a0, 32);
    a1 += __shfl_xor(a1, 32);
    a2 += __shfl_xor(a2, 32);
    a3 += __shfl_xor(a3, 32);
    if (half == 0){
        float inv = (e > s) ? 1.0f / (float)(e - s) : 0.f;
        union { unsigned u; f16 h[2]; } px, py;
        px.h[0] = (f16)(a0 * inv); px.h[1] = (f16)(a1 * inv);
        py.h[0] = (f16)(a2 * inv); py.h[1] = (f16)(a3 * inv);
        sg.A[(size_t)node * 64 + sg.colPair2 + l] = make_uint2(px.u, py.u);
    }
}

// ================= merged MFMA fp16 GEMM (up to 3 segments) =================

struct GemmSeg {
    const f16* A1; const f16* A2; const f16* Wt;
    const float* b1; const float* b2; void* out; float* stats;
    int lda1, lda2, ksplit, N, K, tileBase; float scale;
};
struct GemmDesc { GemmSeg s[3]; };

template<int BN, bool STATS, bool OUT16>
__global__ __launch_bounds__(256) void gemmAll_k(GemmDesc gd){
    constexpr int BK = 64, PAD = 72, CF = BN / 16;
    __shared__ f16 As[128 * PAD];
    __shared__ f16 Bs[BN * PAD];
    __shared__ float ssum[BN];
    __shared__ float ssq[BN];
    int bid = blockIdx.x;
    int si = 0;
    #pragma unroll
    for (int t = 1; t < 3; t++) if (bid >= gd.s[t].tileBase) si = t;
    GemmSeg sg = gd.s[si];
    int tid = threadIdx.x;
    int wv = tid >> 6, lane = tid & 63;
    int row0 = (bid - sg.tileBase) * 128;
    int N = sg.N, K = sg.K;
    if (STATS && tid < BN){ ssum[tid] = 0.f; ssq[tid] = 0.f; }

    f32x4 acc[2][CF];
    #pragma unroll
    for (int rf = 0; rf < 2; rf++)
        #pragma unroll
        for (int cf = 0; cf < CF; cf++)
            acc[rf][cf] = (f32x4){0.f, 0.f, 0.f, 0.f};

    for (int k0 = 0; k0 < K; k0 += BK){
        const f16* Ab; int lda, kloc;
        if (k0 < sg.ksplit){ Ab = sg.A1; lda = sg.lda1; kloc = k0; }
        else               { Ab = sg.A2; lda = sg.lda2; kloc = k0 - sg.ksplit; }
        #pragma unroll
        for (int p = 0; p < 4; p++){
            int f = tid + p * 256;
            int r = f >> 3, sgm = f & 7;
            int gr = row0 + r;
            uint4 v = make_uint4(0u, 0u, 0u, 0u);
            if (gr < N) v = *reinterpret_cast<const uint4*>(Ab + (size_t)gr * lda + kloc + sgm * 8);
            *reinterpret_cast<uint4*>(As + r * PAD + sgm * 8) = v;
        }
        #pragma unroll
        for (int p = 0; p < BN / 32; p++){
            int f = tid + p * 256;
            int r = f >> 3, sgm = f & 7;
            uint4 v = *reinterpret_cast<const uint4*>(sg.Wt + (size_t)r * K + k0 + sgm * 8);
            *reinterpret_cast<uint4*>(Bs + r * PAD + sgm * 8) = v;
        }
        __syncthreads();
        #pragma unroll
        for (int kf = 0; kf < 2; kf++){
            int kb = kf * 32 + (lane >> 4) * 8;
            f16x8 a0 = *reinterpret_cast<const f16x8*>(As + (wv * 32 + (lane & 15)) * PAD + kb);
            f16x8 a1 = *reinterpret_cast<const f16x8*>(As + (wv * 32 + 16 + (lane & 15)) * PAD + kb);
            #pragma unroll
            for (int cf = 0; cf < CF; cf++){
                f16x8 b = *reinterpret_cast<const f16x8*>(Bs + (cf * 16 + (lane & 15)) * PAD + kb);
                acc[0][cf] = __builtin_amdgcn_mfma_f32_16x16x32_f16(a0, b, acc[0][cf], 0, 0, 0);
                acc[1][cf] = __builtin_amdgcn_mfma_f32_16x16x32_f16(a1, b, acc[1][cf], 0, 0, 0);
            }
        }
        __syncthreads();
    }
    int rbase = row0 + wv * 32 + ((lane >> 4) << 2);
    #pragma unroll
    for (int cf = 0; cf < CF; cf++){
        int col = cf * 16 + (lane & 15);
        float bias = 0.f;
        if (sg.b1) bias += sg.b1[col];
        if (sg.b2) bias += sg.b2[col];
        float ls = 0.f, lq = 0.f;
        #pragma unroll
        for (int rf = 0; rf < 2; rf++){
            #pragma unroll
            for (int q = 0; q < 4; q++){
                int gr = rbase + rf * 16 + q;
                if (gr < N){
                    float v = sg.scale * (acc[rf][cf][q] + bias);
                    if (OUT16) ((f16*)sg.out)[(size_t)gr * BN + col] = (f16)v;
                    else       ((float*)sg.out)[(size_t)gr * BN + col] = v;
                    ls += v; lq += v * v;
                }
            }
        }
        if (STATS){ atomicAdd(&ssum[col], ls); atomicAdd(&ssq[col], lq); }
    }
    if (STATS){
        __syncthreads();
        if (tid < BN){
            atomicAdd(&sg.stats[tid], ssum[tid]);
            atomicAdd(&sg.stats[128 + tid], ssq[tid]);
        }
    }
}

// ================= merged BN apply + ReLU (+ residual) =================

struct BnSeg { const f16* o; const float* stats; const float* g; const float* b; f16* h; int N; float invN; int residual; int idxBase; };
struct BnDesc { BnSeg s[3]; int total; };

__global__ __launch_bounds__(256) void bnAll_k(BnDesc bd){
    int idx = blockIdx.x * 256 + threadIdx.x;
    if (idx >= bd.total) return;
    int si = 0;
    #pragma unroll
    for (int t = 1; t < 3; t++) if (idx >= bd.s[t].idxBase) si = t;
    BnSeg sg = bd.s[si];
    int l = idx - sg.idxBase;
    int n = l >> 4, c8 = (l & 15) * 8;
    union { uint4 u; f16 h[8]; } ov;
    ov.u = *reinterpret_cast<const uint4*>(sg.o + (size_t)n * 128 + c8);
    float r[8];
    #pragma unroll
    for (int j = 0; j < 8; j++){
        int c = c8 + j;
        float mu  = sg.stats[c] * sg.invN;
        float var = sg.stats[128 + c] * sg.invN - mu * mu;
        float v = ((float)ov.h[j] - mu) * rsqrtf(var + BN_EPS) * sg.g[c] + sg.b[c];
        r[j] = v > 0.f ? v : 0.f;
    }
    f16* hp = sg.h + (size_t)n * 128 + c8;
    if (sg.residual){
        uint4 old = *reinterpret_cast<const uint4*>(hp);
        union { uint4 u; f16 h[8]; } ou; ou.u = old;
        #pragma unroll
        for (int j = 0; j < 8; j++) r[j] += (float)ou.h[j];
    }
    union { uint4 u; f16 h[8]; } pk;
    #pragma unroll
    for (int j = 0; j < 8; j++) pk.h[j] = (f16)r[j];
    *reinterpret_cast<uint4*>(hp) = pk.u;
}

// ================= host orchestration =================

extern "C" void kernel_launch(void* const* d_in, const int* in_sizes, int n_in,
                              void* d_out, int out_size, void* d_ws, size_t ws_size,
                              hipStream_t stream){
    const float* x_drug = (const float*)d_in[0];
    const float* x_gene = (const float*)d_in[1];
    const float* x_dis  = (const float*)d_in[2];
    const int* srcP[6] = {(const int*)d_in[3], (const int*)d_in[5], (const int*)d_in[7],
                          (const int*)d_in[9], (const int*)d_in[11], (const int*)d_in[13]};
    const int* dstP[6] = {(const int*)d_in[4], (const int*)d_in[6], (const int*)d_in[8],
                          (const int*)d_in[10], (const int*)d_in[12], (const int*)d_in[14]};
    const int  Et[6]   = {in_sizes[3], in_sizes[5], in_sizes[7], in_sizes[9], in_sizes[11], in_sizes[13]};
    const float* W_in[3] = {(const float*)d_in[15], (const float*)d_in[17], (const float*)d_in[19]};
    const float* b_in[3] = {(const float*)d_in[16], (const float*)d_in[18], (const float*)d_in[20]};
    const float* g_in  = (const float*)d_in[21];
    const float* bt_in = (const float*)d_in[22];
    const float* Wl    = (const float*)d_in[23];
    const float* Wr    = (const float*)d_in[24];
    const float* bl    = (const float*)d_in[25];
    const float* g_conv  = (const float*)d_in[26];
    const float* bt_conv = (const float*)d_in[27];
    const float* W_fin = (const float*)d_in[28];
    const float* b_fin = (const float*)d_in[29];
    float* out = (float*)d_out;

    // edge-type metadata (order: dg, gd, gs, sg, ds, sd)
    const int Ndst_t[6]     = {NG, ND, NS, NG, NS, ND};
    const int srcT[6]       = {0, 1, 1, 2, 0, 2};
    const int dstT[6]       = {1, 0, 2, 1, 2, 0};
    const int colPair2_t[6] = {0, 0, 0, 32, 32, 32};

    const int Nn[3]  = {ND, NG, NS};
    const int Kin[3] = {256, 128, 64};
    const float* xin[3] = {x_drug, x_gene, x_dis};

    // ---- workspace carve ----
    char* base = (char*)d_ws;
    size_t off = 0;
    auto alloc = [&](size_t bytes) -> char* {
        char* p = base + off; off += (bytes + 255) & ~(size_t)255; return p;
    };
    f16* h[3];  for (int t = 0; t < 3; t++) h[t]  = (f16*)alloc((size_t)Nn[t] * 128 * 2);
    f16* A[3];  for (int t = 0; t < 3; t++) A[t]  = (f16*)alloc((size_t)Nn[t] * 256 * 2);
    f16* xb[3]; for (int t = 0; t < 3; t++) xb[t] = (f16*)alloc((size_t)Nn[t] * Kin[t] * 2);
    f16* Wint[3]; for (int t = 0; t < 3; t++) Wint[t] = (f16*)alloc((size_t)128 * Kin[t] * 2);
    f16* Wfin_t = (f16*)alloc((size_t)64 * 128 * 2);
    f16* Wcat_t = (f16*)alloc((size_t)9 * 128 * 384 * 2);
    // o pool (also aliased by the packed edge buffer during CSR build, which
    // completes before any o write)
    char* oPool = alloc((size_t)(ND + NG + NS) * 128 * 2);
    f16* o[3];
    o[0] = (f16*)oPool; o[1] = o[0] + (size_t)ND * 128; o[2] = o[1] + (size_t)NG * 128;
    uint2* packed = (uint2*)oPool;
    float* stats = (float*)alloc(12 * 256 * 4);
    // zero pool: per-node cnt (all types) + bucket counters
    int cntTot = 0; for (int t = 0; t < 6; t++) cntTot += Ndst_t[t];
    int* zeroPool = (int*)alloc((size_t)(cntTot + TBUCK) * 4);
    int* cnt[6]; { int a = 0; for (int t = 0; t < 6; t++){ cnt[t] = zeroPool + a; a += Ndst_t[t]; } }
    int* bCnt = zeroPool + cntTot;
    int* bBase   = (int*)alloc((TBUCK + 1) * 4);
    int* bCursor = (int*)alloc(TBUCK * 4);
    int *offs[6], *cursor[6], *csr[6], *partials[6];
    for (int t = 0; t < 6; t++) offs[t]     = (int*)alloc((size_t)(Ndst_t[t] + 1) * 4);
    for (int t = 0; t < 6; t++) cursor[t]   = (int*)alloc((size_t)Ndst_t[t] * 4);
    for (int t = 0; t < 6; t++) partials[t] = (int*)alloc(64 * 4);
    for (int t = 0; t < 6; t++) csr[t]      = (int*)alloc((size_t)Et[t] * 4);

    hipMemsetAsync(zeroPool, 0, (size_t)(cntTot + TBUCK) * 4, stream);
    hipMemsetAsync(stats, 0, 12 * 256 * 4, stream);

    // ---- bucketed CSR build ----
    BDesc bd;
    {
        int ecum = 0;
        for (int t = 0; t < 6; t++){
            bd.src[t] = srcP[t]; bd.dst[t] = dstP[t];
            bd.Ebase[t] = ecum; ecum += Et[t];
            int sft = 0; while (((Ndst_t[t] - 1) >> sft) >= NBUCK) sft++;
            bd.shift[t] = sft;
            bd.cnt[t] = cnt[t]; bd.cursor[t] = cursor[t]; bd.csr[t] = csr[t];
        }
        bd.Ebase[6] = ecum;
        bd.bCnt = bCnt; bd.bBase = bBase; bd.bCursor = bCursor;
        bd.packed = packed;
    }
    int Etot = bd.Ebase[6];
    bhist_k<<<cdiv(Etot, PCHUNK), 256, 0, stream>>>(bd);
    bscan_k<<<1, 512, 0, stream>>>(bd);
    bpart_k<<<cdiv(Etot, PCHUNK), 256, 0, stream>>>(bd);
    countB_k<<<cdiv(Etot, 256), 256, 0, stream>>>(bd);

    ScanDesc sd;
    {
        int bcum = 0;
        for (int t = 0; t < 6; t++){
            sd.cnt[t] = cnt[t]; sd.offs[t] = offs[t]; sd.cursor[t] = cursor[t];
            sd.partials[t] = partials[t];
            sd.N[t] = Ndst_t[t];
            sd.blkBase[t] = bcum; bcum += cdiv(Ndst_t[t], 1024);
        }
        sd.blkBase[6] = bcum;
    }
    scan1All_k<<<sd.blkBase[6], 256, 0, stream>>>(sd);
    scan2All_k<<<6, 64, 0, stream>>>(sd);
    scan3All_k<<<sd.blkBase[6], 256, 0, stream>>>(sd);
    fillB_k<<<cdiv(Etot, 256), 256, 0, stream>>>(bd);

    // ---- casts + weights ----
    CastDesc cds;
    {
        int b = 0;
        for (int t = 0; t < 3; t++){
            cds.src[t] = xin[t]; cds.dst[t] = xb[t];
            cds.base[t] = b; b += Nn[t] * Kin[t] / 4;
        }
        cds.base[3] = b;
    }
    castAll_k<<<cdiv(cds.base[3], 256), 256, 0, stream>>>(cds);
    WDesc wd = {W_in[0], W_in[1], W_in[2], W_fin, Wl, Wr,
                Wint[0], Wint[1], Wint[2], Wfin_t, Wcat_t};
    weightAll_k<<<cdiv(507904, 256), 256, 0, stream>>>(wd);

    int tiles[3]; for (int t = 0; t < 3; t++) tiles[t] = cdiv(Nn[t], 128);
    int tileBase[4] = {0, tiles[0], tiles[0] + tiles[1], tiles[0] + tiles[1] + tiles[2]};

    // ---- input stage ----
    {
        GemmDesc g{};
        for (int t = 0; t < 3; t++){
            g.s[t] = {xb[t], xb[t], Wint[t], b_in[t], nullptr, o[t], stats + t * 256,
                      Kin[t], Kin[t], Kin[t], Nn[t], Kin[t], tileBase[t], 1.0f};
        }
        gemmAll_k<128, true, true><<<tileBase[3], 256, 0, stream>>>(g);
        BnDesc bnd{}; int ib = 0;
        for (int t = 0; t < 3; t++){
            bnd.s[t] = {o[t], stats + t * 256, g_in + t * 128, bt_in + t * 128, h[t],
                        Nn[t], 1.0f / Nn[t], 0, ib};
            ib += Nn[t] * 16;
        }
        bnd.total = ib;
        bnAll_k<<<cdiv(ib, 256), 256, 0, stream>>>(bnd);
    }

    // ---- 3 conv layers ----
    const int e1s[3] = {1, 0, 2}, e2s[3] = {5, 3, 4};
    for (int L = 0; L < 3; L++){
        GDesc gd; int bacc = 0;
        for (int t = 0; t < 6; t++){
            gd.s[t].offs = offs[t];
            gd.s[t].csr  = csr[t];
            gd.s[t].h    = (const uint2*)h[srcT[t]];
            gd.s[t].A    = (uint2*)A[dstT[t]];
            gd.s[t].colPair2 = colPair2_t[t];
            gd.s[t].N    = Ndst_t[t];
            gd.s[t].base = bacc;
            bacc += cdiv(Ndst_t[t], 4);
        }
        gatherall_k<<<bacc, 256, 0, stream>>>(gd);
        GemmDesc g{};
        for (int t = 0; t < 3; t++){
            int e1 = e1s[t], e2 = e2s[t];
            g.s[t] = {A[t], h[t], Wcat_t + (size_t)(L * 3 + t) * 128 * 384,
                      bl + (size_t)(L * 6 + e1) * 128, bl + (size_t)(L * 6 + e2) * 128,
                      o[t], stats + (size_t)(3 + L * 3 + t) * 256,
                      256, 128, 256, Nn[t], 384, tileBase[t], 0.5f};
        }
        gemmAll_k<128, true, true><<<tileBase[3], 256, 0, stream>>>(g);
        BnDesc bnd{}; int ib = 0;
        for (int t = 0; t < 3; t++){
            bnd.s[t] = {o[t], stats + (size_t)(3 + L * 3 + t) * 256,
                        g_conv + (size_t)(L * 3 + t) * 128, bt_conv + (size_t)(L * 3 + t) * 128,
                        h[t], Nn[t], 1.0f / Nn[t], 1, ib};
            ib += Nn[t] * 16;
        }
        bnd.total = ib;
        bnAll_k<<<cdiv(ib, 256), 256, 0, stream>>>(bnd);
    }

    // ---- final projection: one GEMM over contiguous h pool ----
    {
        int Ntot = ND + NG + NS;
        GemmDesc g{};
        g.s[0] = {h[0], h[0], Wfin_t, b_fin, nullptr, out, nullptr,
                  128, 128, 128, Ntot, 128, 0, 1.0f};
        g.s[1] = g.s[0]; g.s[1].tileBase = 0x3FFFFFFF; g.s[1].N = 0;
        g.s[2] = g.s[1];
        gemmAll_k<64, false, false><<<cdiv(Ntot, 128), 256, 0, stream>>>(g);
    }
}

// Round 6
// 719.420 us; speedup vs baseline: 3.6761x; 1.0079x over previous
//
#include <hip/hip_runtime.h>
#include <cstddef>
#include <cstdint>

typedef _Float16 f16;
typedef _Float16 f16x2 __attribute__((ext_vector_type(2)));
typedef _Float16 f16x8 __attribute__((ext_vector_type(8)));
typedef float f32x4 __attribute__((ext_vector_type(4)));

#if defined(__has_builtin)
#if __has_builtin(__builtin_amdgcn_fdot2)
#define HAVE_FDOT2 1
#endif
#endif
#ifndef HAVE_FDOT2
#define HAVE_FDOT2 0
#endif

constexpr int ND = 30000, NG = 60000, NS = 15000;
constexpr float BN_EPS = 1e-5f;
constexpr int NBUCK = 64;      // buckets per edge type
constexpr int TBUCK = 6 * NBUCK;
constexpr int PCHUNK = 4096;   // edges per partition block

static inline int cdiv(int a, int b){ return (a + b - 1) / b; }

// ================= bucketed CSR construction =================

struct BDesc {
    const int* src[6]; const int* dst[6];
    int Ebase[7]; int shift[6];
    int* bCnt; int* bBase; int* bCursor;
    uint2* packed;
    int* cnt[6]; int* cursor[6]; int* csr[6];
};

__global__ __launch_bounds__(256) void bhist_k(BDesc bd){
    __shared__ int hist[TBUCK];
    int tid = threadIdx.x;
    for (int i = tid; i < TBUCK; i += 256) hist[i] = 0;
    __syncthreads();
    int Etot = bd.Ebase[6];
    #pragma unroll
    for (int u = 0; u < 16; u++){
        int e = blockIdx.x * PCHUNK + u * 256 + tid;
        if (e < Etot){
            int t = 0;
            #pragma unroll
            for (int i = 1; i < 6; i++) if (e >= bd.Ebase[i]) t = i;
            int d = bd.dst[t][e - bd.Ebase[t]];
            atomicAdd(&hist[t * NBUCK + (d >> bd.shift[t])], 1);
        }
    }
    __syncthreads();
    for (int i = tid; i < TBUCK; i += 256)
        if (hist[i]) atomicAdd(&bd.bCnt[i], hist[i]);
}

__global__ __launch_bounds__(512) void bscan_k(BDesc bd){
    __shared__ int sh[TBUCK];
    int tid = threadIdx.x;
    int my = (tid < TBUCK) ? bd.bCnt[tid] : 0;
    if (tid < TBUCK) sh[tid] = my;
    __syncthreads();
    for (int d = 1; d < TBUCK; d <<= 1){
        int v = (tid < TBUCK) ? sh[tid] : 0;
        int add = (tid >= d && tid < TBUCK) ? sh[tid - d] : 0;
        __syncthreads();
        if (tid < TBUCK) sh[tid] = v + add;
        __syncthreads();
    }
    if (tid < TBUCK){
        int excl = sh[tid] - my;
        bd.bBase[tid] = excl;
        bd.bCursor[tid] = excl;
    }
    if (tid == 0) bd.bBase[TBUCK] = sh[TBUCK - 1];
}

__global__ __launch_bounds__(256) void bpart_k(BDesc bd){
    __shared__ int hist[TBUCK];
    __shared__ int basesh[TBUCK];
    int tid = threadIdx.x;
    for (int i = tid; i < TBUCK; i += 256) hist[i] = 0;
    __syncthreads();
    int Etot = bd.Ebase[6];
    int mb[16], mr[16], ms[16], md[16];
    #pragma unroll
    for (int u = 0; u < 16; u++){
        int e = blockIdx.x * PCHUNK + u * 256 + tid;
        mb[u] = -1;
        if (e < Etot){
            int t = 0;
            #pragma unroll
            for (int i = 1; i < 6; i++) if (e >= bd.Ebase[i]) t = i;
            int le = e - bd.Ebase[t];
            int s = bd.src[t][le], d = bd.dst[t][le];
            int b = t * NBUCK + (d >> bd.shift[t]);
            mr[u] = atomicAdd(&hist[b], 1);
            mb[u] = b; ms[u] = s; md[u] = d;
        }
    }
    __syncthreads();
    for (int i = tid; i < TBUCK; i += 256)
        basesh[i] = hist[i] ? atomicAdd(&bd.bCursor[i], hist[i]) : 0;
    __syncthreads();
    #pragma unroll
    for (int u = 0; u < 16; u++){
        if (mb[u] >= 0){
            int pos = basesh[mb[u]] + mr[u];
            bd.packed[pos] = make_uint2((unsigned)ms[u], (unsigned)md[u]);
        }
    }
}

__global__ __launch_bounds__(256) void countB_k(BDesc bd){
    int e = blockIdx.x * 256 + threadIdx.x;
    if (e >= bd.Ebase[6]) return;
    int t = 0;
    #pragma unroll
    for (int i = 1; i < 6; i++) if (e >= bd.Ebase[i]) t = i;
    atomicAdd(&bd.cnt[t][bd.packed[e].y], 1);
}

__global__ __launch_bounds__(256) void fillB_k(BDesc bd){
    int e = blockIdx.x * 256 + threadIdx.x;
    if (e >= bd.Ebase[6]) return;
    int t = 0;
    #pragma unroll
    for (int i = 1; i < 6; i++) if (e >= bd.Ebase[i]) t = i;
    uint2 p = bd.packed[e];
    int pos = atomicAdd(&bd.cursor[t][p.y], 1);
    bd.csr[t][pos] = (int)p.x;
}

// ================= per-node offset scans =================

struct ScanDesc {
    int* cnt[6]; int* offs[6]; int* cursor[6]; int* partials[6];
    int N[6]; int blkBase[7];
};

__global__ __launch_bounds__(256) void scan1All_k(ScanDesc cd){
    int t = 0;
    #pragma unroll
    for (int i = 1; i < 6; i++) if ((int)blockIdx.x >= cd.blkBase[i]) t = i;
    int b = blockIdx.x - cd.blkBase[t];
    __shared__ int sh[256];
    int tid = threadIdx.x;
    int base = b * 1024 + tid * 4;
    int s = 0;
    #pragma unroll
    for (int j = 0; j < 4; j++) if (base + j < cd.N[t]) s += cd.cnt[t][base + j];
    sh[tid] = s; __syncthreads();
    for (int d = 128; d > 0; d >>= 1){
        if (tid < d) sh[tid] += sh[tid + d];
        __syncthreads();
    }
    if (tid == 0) cd.partials[t][b] = sh[0];
}

__global__ void scan2All_k(ScanDesc cd){
    int t = blockIdx.x;
    if (threadIdx.x == 0){
        int B = cd.blkBase[t + 1] - cd.blkBase[t];
        int run = 0;
        for (int i = 0; i < B; i++){ int v = cd.partials[t][i]; cd.partials[t][i] = run; run += v; }
        cd.offs[t][cd.N[t]] = run;
    }
}

__global__ __launch_bounds__(256) void scan3All_k(ScanDesc cd){
    int t = 0;
    #pragma unroll
    for (int i = 1; i < 6; i++) if ((int)blockIdx.x >= cd.blkBase[i]) t = i;
    int b = blockIdx.x - cd.blkBase[t];
    __shared__ int sh[256];
    int tid = threadIdx.x;
    int base = b * 1024 + tid * 4;
    int c[4]; int s = 0;
    #pragma unroll
    for (int j = 0; j < 4; j++){ c[j] = (base + j < cd.N[t]) ? cd.cnt[t][base + j] : 0; s += c[j]; }
    sh[tid] = s; __syncthreads();
    for (int d = 1; d < 256; d <<= 1){
        int v = sh[tid];
        int add = (tid >= d) ? sh[tid - d] : 0;
        __syncthreads();
        sh[tid] = v + add;
        __syncthreads();
    }
    int run = cd.partials[t][b] + sh[tid] - s;
    #pragma unroll
    for (int j = 0; j < 4; j++){
        if (base + j < cd.N[t]){ cd.offs[t][base + j] = run; cd.cursor[t][base + j] = run; run += c[j]; }
    }
}

// ================= prep: casts + weight transposes =================

struct CastDesc { const float* src[3]; f16* dst[3]; int base[4]; };

__global__ __launch_bounds__(256) void castAll_k(CastDesc cdsc){
    int idx = blockIdx.x * 256 + threadIdx.x;
    if (idx >= cdsc.base[3]) return;
    int t = 0;
    #pragma unroll
    for (int i = 1; i < 3; i++) if (idx >= cdsc.base[i]) t = i;
    int i4 = (idx - cdsc.base[t]) * 4;
    float4 v = *reinterpret_cast<const float4*>(cdsc.src[t] + i4);
    union { uint2 u; f16 h[4]; } o;
    o.h[0] = (f16)v.x; o.h[1] = (f16)v.y; o.h[2] = (f16)v.z; o.h[3] = (f16)v.w;
    *reinterpret_cast<uint2*>(cdsc.dst[t] + i4) = o.u;
}

struct WDesc {
    const float* W_in0; const float* W_in1; const float* W_in2;
    const float* W_fin; const float* Wl; const float* Wr;
    f16* Wint0; f16* Wint1; f16* Wint2; f16* Wfin_t; f16* Wcat_t;
};

__global__ __launch_bounds__(256) void weightAll_k(WDesc wd){
    int idx = blockIdx.x * 256 + threadIdx.x;
    if (idx < 32768){
        int c = idx >> 8, k = idx & 255;
        wd.Wint0[idx] = (f16)wd.W_in0[k * 128 + c];
    } else if (idx < 49152){
        int l = idx - 32768; int c = l >> 7, k = l & 127;
        wd.Wint1[l] = (f16)wd.W_in1[k * 128 + c];
    } else if (idx < 57344){
        int l = idx - 49152; int c = l >> 6, k = l & 63;
        wd.Wint2[l] = (f16)wd.W_in2[k * 128 + c];
    } else if (idx < 65536){
        int l = idx - 57344; int c = l >> 7, k = l & 127;
        wd.Wfin_t[l] = (f16)wd.W_fin[k * 64 + c];
    } else if (idx < 507904){
        int l = idx - 65536;
        int g = l / (384 * 128);
        int rem = l - g * (384 * 128);
        int c = rem / 384;
        int k = rem - c * 384;
        int L = g / 3, t = g - L * 3;
        const int e1s[3] = {1, 0, 2}, e2s[3] = {5, 3, 4};
        int e1 = e1s[t], e2 = e2s[t];
        float v;
        if (k < 128)      v = wd.Wl[(((size_t)L * 6 + e1) * 128 + k) * 128 + c];
        else if (k < 256) v = wd.Wl[(((size_t)L * 6 + e2) * 128 + (k - 128)) * 128 + c];
        else {
            int kr = k - 256;
            v = wd.Wr[(((size_t)L * 6 + e1) * 128 + kr) * 128 + c]
              + wd.Wr[(((size_t)L * 6 + e2) * 128 + kr) * 128 + c];
        }
        wd.Wcat_t[l] = (f16)v;
    }
}

// ================= fused gather-mean: wave/node, 16 lanes/row, shfl indices =================
// Wave = 1 node. Lane = (grp: lane>>4, li: lane&15). Group g reads neighbor row
// (r+g) as uint4 (16B); indices coalesced-loaded once per 64-edge chunk and
// broadcast via shfl. 4-round unroll -> 16 rows in flight per wave.

struct GSeg { const int* offs; const int* csr; const uint4* h; uint4* A; int colPair4; int N; int base; };
struct GDesc { GSeg s[6]; const uint4* zrow; };

__device__ __forceinline__ void acc8(uint4 v, float* a){
    union { unsigned u; f16x2 h; } c;
#if HAVE_FDOT2
    const f16x2 e0 = {(f16)1.f, (f16)0.f};
    const f16x2 e1 = {(f16)0.f, (f16)1.f};
    c.u = v.x; a[0] = __builtin_amdgcn_fdot2(c.h, e0, a[0], false);
               a[1] = __builtin_amdgcn_fdot2(c.h, e1, a[1], false);
    c.u = v.y; a[2] = __builtin_amdgcn_fdot2(c.h, e0, a[2], false);
               a[3] = __builtin_amdgcn_fdot2(c.h, e1, a[3], false);
    c.u = v.z; a[4] = __builtin_amdgcn_fdot2(c.h, e0, a[4], false);
               a[5] = __builtin_amdgcn_fdot2(c.h, e1, a[5], false);
    c.u = v.w; a[6] = __builtin_amdgcn_fdot2(c.h, e0, a[6], false);
               a[7] = __builtin_amdgcn_fdot2(c.h, e1, a[7], false);
#else
    c.u = v.x; a[0] += (float)c.h[0]; a[1] += (float)c.h[1];
    c.u = v.y; a[2] += (float)c.h[0]; a[3] += (float)c.h[1];
    c.u = v.z; a[4] += (float)c.h[0]; a[5] += (float)c.h[1];
    c.u = v.w; a[6] += (float)c.h[0]; a[7] += (float)c.h[1];
#endif
}

__global__ __launch_bounds__(256) void gatherall_k(GDesc gd){
    int bid = blockIdx.x;
    int si = 0;
    #pragma unroll
    for (int t = 1; t < 6; t++) if (bid >= gd.s[t].base) si = t;
    GSeg sg = gd.s[si];
    int node = (bid - sg.base) * 4 + (threadIdx.x >> 6);
    if (node >= sg.N) return;
    int lane = threadIdx.x & 63;
    int grp = lane >> 4, li = lane & 15;
    int s = sg.offs[node], e = sg.offs[node + 1];
    const int* cp = sg.csr;
    const uint4* hp = sg.h;
    float a[8] = {0.f, 0.f, 0.f, 0.f, 0.f, 0.f, 0.f, 0.f};
    for (int c = s; c < e; c += 64){
        int nchunk = e - c; if (nchunk > 64) nchunk = 64;
        int idx = (lane < nchunk) ? cp[c + lane] : 0;
        int r = 0;
        for (; r + 16 <= nchunk; r += 16){
            int i0 = __shfl(idx, r + grp);
            int i1 = __shfl(idx, r + 4 + grp);
            int i2 = __shfl(idx, r + 8 + grp);
            int i3 = __shfl(idx, r + 12 + grp);
            uint4 v0 = hp[(size_t)i0 * 16 + li];
            uint4 v1 = hp[(size_t)i1 * 16 + li];
            uint4 v2 = hp[(size_t)i2 * 16 + li];
            uint4 v3 = hp[(size_t)i3 * 16 + li];
            acc8(v0, a); acc8(v1, a); acc8(v2, a); acc8(v3, a);
        }
        for (; r < nchunk; r += 4){
            int ei = __shfl(idx, r + grp);
            const uint4* rp = ((r + grp) < nchunk) ? (hp + (size_t)ei * 16) : gd.zrow;
            uint4 v = rp[li];
            acc8(v, a);
        }
    }
    #pragma unroll
    for (int i = 0; i < 8; i++){
        a[i] += __shfl_xor(a[i], 16);
        a[i] += __shfl_xor(a[i], 32);
    }
    if (grp == 0){
        float inv = (e > s) ? 1.0f / (float)(e - s) : 0.f;
        union { uint4 u; f16 h[8]; } pk;
        #pragma unroll
        for (int i = 0; i < 8; i++) pk.h[i] = (f16)(a[i] * inv);
        sg.A[(size_t)node * 32 + sg.colPair4 + li] = pk.u;
    }
}

// ================= merged MFMA fp16 GEMM (up to 3 segments) =================

struct GemmSeg {
    const f16* A1; const f16* A2; const f16* Wt;
    const float* b1; const float* b2; void* out; float* stats;
    int lda1, lda2, ksplit, N, K, tileBase; float scale;
};
struct GemmDesc { GemmSeg s[3]; };

template<int BN, bool STATS, bool OUT16>
__global__ __launch_bounds__(256) void gemmAll_k(GemmDesc gd){
    constexpr int BK = 64, PAD = 72, CF = BN / 16;
    __shared__ f16 As[128 * PAD];
    __shared__ f16 Bs[BN * PAD];
    __shared__ float ssum[BN];
    __shared__ float ssq[BN];
    int bid = blockIdx.x;
    int si = 0;
    #pragma unroll
    for (int t = 1; t < 3; t++) if (bid >= gd.s[t].tileBase) si = t;
    GemmSeg sg = gd.s[si];
    int tid = threadIdx.x;
    int wv = tid >> 6, lane = tid & 63;
    int row0 = (bid - sg.tileBase) * 128;
    int N = sg.N, K = sg.K;
    if (STATS && tid < BN){ ssum[tid] = 0.f; ssq[tid] = 0.f; }

    f32x4 acc[2][CF];
    #pragma unroll
    for (int rf = 0; rf < 2; rf++)
        #pragma unroll
        for (int cf = 0; cf < CF; cf++)
            acc[rf][cf] = (f32x4){0.f, 0.f, 0.f, 0.f};

    for (int k0 = 0; k0 < K; k0 += BK){
        const f16* Ab; int lda, kloc;
        if (k0 < sg.ksplit){ Ab = sg.A1; lda = sg.lda1; kloc = k0; }
        else               { Ab = sg.A2; lda = sg.lda2; kloc = k0 - sg.ksplit; }
        #pragma unroll
        for (int p = 0; p < 4; p++){
            int f = tid + p * 256;
            int r = f >> 3, sgm = f & 7;
            int gr = row0 + r;
            uint4 v = make_uint4(0u, 0u, 0u, 0u);
            if (gr < N) v = *reinterpret_cast<const uint4*>(Ab + (size_t)gr * lda + kloc + sgm * 8);
            *reinterpret_cast<uint4*>(As + r * PAD + sgm * 8) = v;
        }
        #pragma unroll
        for (int p = 0; p < BN / 32; p++){
            int f = tid + p * 256;
            int r = f >> 3, sgm = f & 7;
            uint4 v = *reinterpret_cast<const uint4*>(sg.Wt + (size_t)r * K + k0 + sgm * 8);
            *reinterpret_cast<uint4*>(Bs + r * PAD + sgm * 8) = v;
        }
        __syncthreads();
        #pragma unroll
        for (int kf = 0; kf < 2; kf++){
            int kb = kf * 32 + (lane >> 4) * 8;
            f16x8 a0 = *reinterpret_cast<const f16x8*>(As + (wv * 32 + (lane & 15)) * PAD + kb);
            f16x8 a1 = *reinterpret_cast<const f16x8*>(As + (wv * 32 + 16 + (lane & 15)) * PAD + kb);
            #pragma unroll
            for (int cf = 0; cf < CF; cf++){
                f16x8 b = *reinterpret_cast<const f16x8*>(Bs + (cf * 16 + (lane & 15)) * PAD + kb);
                acc[0][cf] = __builtin_amdgcn_mfma_f32_16x16x32_f16(a0, b, acc[0][cf], 0, 0, 0);
                acc[1][cf] = __builtin_amdgcn_mfma_f32_16x16x32_f16(a1, b, acc[1][cf], 0, 0, 0);
            }
        }
        __syncthreads();
    }
    int rbase = row0 + wv * 32 + ((lane >> 4) << 2);
    #pragma unroll
    for (int cf = 0; cf < CF; cf++){
        int col = cf * 16 + (lane & 15);
        float bias = 0.f;
        if (sg.b1) bias += sg.b1[col];
        if (sg.b2) bias += sg.b2[col];
        float ls = 0.f, lq = 0.f;
        #pragma unroll
        for (int rf = 0; rf < 2; rf++){
            #pragma unroll
            for (int q = 0; q < 4; q++){
                int gr = rbase + rf * 16 + q;
                if (gr < N){
                    float v = sg.scale * (acc[rf][cf][q] + bias);
                    if (OUT16) ((f16*)sg.out)[(size_t)gr * BN + col] = (f16)v;
                    else       ((float*)sg.out)[(size_t)gr * BN + col] = v;
                    ls += v; lq += v * v;
                }
            }
        }
        if (STATS){ atomicAdd(&ssum[col], ls); atomicAdd(&ssq[col], lq); }
    }
    if (STATS){
        __syncthreads();
        if (tid < BN){
            atomicAdd(&sg.stats[tid], ssum[tid]);
            atomicAdd(&sg.stats[128 + tid], ssq[tid]);
        }
    }
}

// ================= merged BN apply + ReLU (+ residual) =================

struct BnSeg { const f16* o; const float* stats; const float* g; const float* b; f16* h; int N; float invN; int residual; int idxBase; };
struct BnDesc { BnSeg s[3]; int total; };

__global__ __launch_bounds__(256) void bnAll_k(BnDesc bd){
    int idx = blockIdx.x * 256 + threadIdx.x;
    if (idx >= bd.total) return;
    int si = 0;
    #pragma unroll
    for (int t = 1; t < 3; t++) if (idx >= bd.s[t].idxBase) si = t;
    BnSeg sg = bd.s[si];
    int l = idx - sg.idxBase;
    int n = l >> 4, c8 = (l & 15) * 8;
    union { uint4 u; f16 h[8]; } ov;
    ov.u = *reinterpret_cast<const uint4*>(sg.o + (size_t)n * 128 + c8);
    float r[8];
    #pragma unroll
    for (int j = 0; j < 8; j++){
        int c = c8 + j;
        float mu  = sg.stats[c] * sg.invN;
        float var = sg.stats[128 + c] * sg.invN - mu * mu;
        float v = ((float)ov.h[j] - mu) * rsqrtf(var + BN_EPS) * sg.g[c] + sg.b[c];
        r[j] = v > 0.f ? v : 0.f;
    }
    f16* hp = sg.h + (size_t)n * 128 + c8;
    if (sg.residual){
        uint4 old = *reinterpret_cast<const uint4*>(hp);
        union { uint4 u; f16 h[8]; } ou; ou.u = old;
        #pragma unroll
        for (int j = 0; j < 8; j++) r[j] += (float)ou.h[j];
    }
    union { uint4 u; f16 h[8]; } pk;
    #pragma unroll
    for (int j = 0; j < 8; j++) pk.h[j] = (f16)r[j];
    *reinterpret_cast<uint4*>(hp) = pk.u;
}

// ================= host orchestration =================

extern "C" void kernel_launch(void* const* d_in, const int* in_sizes, int n_in,
                              void* d_out, int out_size, void* d_ws, size_t ws_size,
                              hipStream_t stream){
    const float* x_drug = (const float*)d_in[0];
    const float* x_gene = (const float*)d_in[1];
    const float* x_dis  = (const float*)d_in[2];
    const int* srcP[6] = {(const int*)d_in[3], (const int*)d_in[5], (const int*)d_in[7],
                          (const int*)d_in[9], (const int*)d_in[11], (const int*)d_in[13]};
    const int* dstP[6] = {(const int*)d_in[4], (const int*)d_in[6], (const int*)d_in[8],
                          (const int*)d_in[10], (const int*)d_in[12], (const int*)d_in[14]};
    const int  Et[6]   = {in_sizes[3], in_sizes[5], in_sizes[7], in_sizes[9], in_sizes[11], in_sizes[13]};
    const float* W_in[3] = {(const float*)d_in[15], (const float*)d_in[17], (const float*)d_in[19]};
    const float* b_in[3] = {(const float*)d_in[16], (const float*)d_in[18], (const float*)d_in[20]};
    const float* g_in  = (const float*)d_in[21];
    const float* bt_in = (const float*)d_in[22];
    const float* Wl    = (const float*)d_in[23];
    const float* Wr    = (const float*)d_in[24];
    const float* bl    = (const float*)d_in[25];
    const float* g_conv  = (const float*)d_in[26];
    const float* bt_conv = (const float*)d_in[27];
    const float* W_fin = (const float*)d_in[28];
    const float* b_fin = (const float*)d_in[29];
    float* out = (float*)d_out;

    // edge-type metadata (order: dg, gd, gs, sg, ds, sd)
    const int Ndst_t[6]     = {NG, ND, NS, NG, NS, ND};
    const int srcT[6]       = {0, 1, 1, 2, 0, 2};
    const int dstT[6]       = {1, 0, 2, 1, 2, 0};
    const int colPair4_t[6] = {0, 0, 0, 16, 16, 16};

    const int Nn[3]  = {ND, NG, NS};
    const int Kin[3] = {256, 128, 64};
    const float* xin[3] = {x_drug, x_gene, x_dis};

    // ---- workspace carve ----
    char* base = (char*)d_ws;
    size_t off = 0;
    auto alloc = [&](size_t bytes) -> char* {
        char* p = base + off; off += (bytes + 255) & ~(size_t)255; return p;
    };
    f16* h[3];  for (int t = 0; t < 3; t++) h[t]  = (f16*)alloc((size_t)Nn[t] * 128 * 2);
    f16* A[3];  for (int t = 0; t < 3; t++) A[t]  = (f16*)alloc((size_t)Nn[t] * 256 * 2);
    f16* xb[3]; for (int t = 0; t < 3; t++) xb[t] = (f16*)alloc((size_t)Nn[t] * Kin[t] * 2);
    f16* Wint[3]; for (int t = 0; t < 3; t++) Wint[t] = (f16*)alloc((size_t)128 * Kin[t] * 2);
    f16* Wfin_t = (f16*)alloc((size_t)64 * 128 * 2);
    f16* Wcat_t = (f16*)alloc((size_t)9 * 128 * 384 * 2);
    // o pool (aliased by packed edge buffer during CSR build, which finishes first)
    char* oPool = alloc((size_t)(ND + NG + NS) * 128 * 2);
    f16* o[3];
    o[0] = (f16*)oPool; o[1] = o[0] + (size_t)ND * 128; o[2] = o[1] + (size_t)NG * 128;
    uint2* packed = (uint2*)oPool;
    float* stats = (float*)alloc(12 * 256 * 4);
    // zero pool: per-node cnt (all types) + bucket counters + 256B zero row
    int cntTot = 0; for (int t = 0; t < 6; t++) cntTot += Ndst_t[t];
    int* zeroPool = (int*)alloc((size_t)(cntTot + TBUCK + 64) * 4);
    int* cnt[6]; { int a = 0; for (int t = 0; t < 6; t++){ cnt[t] = zeroPool + a; a += Ndst_t[t]; } }
    int* bCnt = zeroPool + cntTot;
    const uint4* zrow = (const uint4*)(zeroPool + cntTot + TBUCK);
    int* bBase   = (int*)alloc((TBUCK + 1) * 4);
    int* bCursor = (int*)alloc(TBUCK * 4);
    int *offs[6], *cursor[6], *csr[6], *partials[6];
    for (int t = 0; t < 6; t++) offs[t]     = (int*)alloc((size_t)(Ndst_t[t] + 1) * 4);
    for (int t = 0; t < 6; t++) cursor[t]   = (int*)alloc((size_t)Ndst_t[t] * 4);
    for (int t = 0; t < 6; t++) partials[t] = (int*)alloc(64 * 4);
    for (int t = 0; t < 6; t++) csr[t]      = (int*)alloc((size_t)Et[t] * 4);

    hipMemsetAsync(zeroPool, 0, (size_t)(cntTot + TBUCK + 64) * 4, stream);
    hipMemsetAsync(stats, 0, 12 * 256 * 4, stream);

    // ---- bucketed CSR build ----
    BDesc bd;
    {
        int ecum = 0;
        for (int t = 0; t < 6; t++){
            bd.src[t] = srcP[t]; bd.dst[t] = dstP[t];
            bd.Ebase[t] = ecum; ecum += Et[t];
            int sft = 0; while (((Ndst_t[t] - 1) >> sft) >= NBUCK) sft++;
            bd.shift[t] = sft;
            bd.cnt[t] = cnt[t]; bd.cursor[t] = cursor[t]; bd.csr[t] = csr[t];
        }
        bd.Ebase[6] = ecum;
        bd.bCnt = bCnt; bd.bBase = bBase; bd.bCursor = bCursor;
        bd.packed = packed;
    }
    int Etot = bd.Ebase[6];
    bhist_k<<<cdiv(Etot, PCHUNK), 256, 0, stream>>>(bd);
    bscan_k<<<1, 512, 0, stream>>>(bd);
    bpart_k<<<cdiv(Etot, PCHUNK), 256, 0, stream>>>(bd);
    countB_k<<<cdiv(Etot, 256), 256, 0, stream>>>(bd);

    ScanDesc sd;
    {
        int bcum = 0;
        for (int t = 0; t < 6; t++){
            sd.cnt[t] = cnt[t]; sd.offs[t] = offs[t]; sd.cursor[t] = cursor[t];
            sd.partials[t] = partials[t];
            sd.N[t] = Ndst_t[t];
            sd.blkBase[t] = bcum; bcum += cdiv(Ndst_t[t], 1024);
        }
        sd.blkBase[6] = bcum;
    }
    scan1All_k<<<sd.blkBase[6], 256, 0, stream>>>(sd);
    scan2All_k<<<6, 64, 0, stream>>>(sd);
    scan3All_k<<<sd.blkBase[6], 256, 0, stream>>>(sd);
    fillB_k<<<cdiv(Etot, 256), 256, 0, stream>>>(bd);

    // ---- casts + weights ----
    CastDesc cds;
    {
        int b = 0;
        for (int t = 0; t < 3; t++){
            cds.src[t] = xin[t]; cds.dst[t] = xb[t];
            cds.base[t] = b; b += Nn[t] * Kin[t] / 4;
        }
        cds.base[3] = b;
    }
    castAll_k<<<cdiv(cds.base[3], 256), 256, 0, stream>>>(cds);
    WDesc wd = {W_in[0], W_in[1], W_in[2], W_fin, Wl, Wr,
                Wint[0], Wint[1], Wint[2], Wfin_t, Wcat_t};
    weightAll_k<<<cdiv(507904, 256), 256, 0, stream>>>(wd);

    int tiles[3]; for (int t = 0; t < 3; t++) tiles[t] = cdiv(Nn[t], 128);
    int tileBase[4] = {0, tiles[0], tiles[0] + tiles[1], tiles[0] + tiles[1] + tiles[2]};

    // ---- input stage ----
    {
        GemmDesc g{};
        for (int t = 0; t < 3; t++){
            g.s[t] = {xb[t], xb[t], Wint[t], b_in[t], nullptr, o[t], stats + t * 256,
                      Kin[t], Kin[t], Kin[t], Nn[t], Kin[t], tileBase[t], 1.0f};
        }
        gemmAll_k<128, true, true><<<tileBase[3], 256, 0, stream>>>(g);
        BnDesc bnd{}; int ib = 0;
        for (int t = 0; t < 3; t++){
            bnd.s[t] = {o[t], stats + t * 256, g_in + t * 128, bt_in + t * 128, h[t],
                        Nn[t], 1.0f / Nn[t], 0, ib};
            ib += Nn[t] * 16;
        }
        bnd.total = ib;
        bnAll_k<<<cdiv(ib, 256), 256, 0, stream>>>(bnd);
    }

    // ---- 3 conv layers ----
    const int e1s[3] = {1, 0, 2}, e2s[3] = {5, 3, 4};
    for (int L = 0; L < 3; L++){
        GDesc gd; int bacc = 0;
        gd.zrow = zrow;
        for (int t = 0; t < 6; t++){
            gd.s[t].offs = offs[t];
            gd.s[t].csr  = csr[t];
            gd.s[t].h    = (const uint4*)h[srcT[t]];
            gd.s[t].A    = (uint4*)A[dstT[t]];
            gd.s[t].colPair4 = colPair4_t[t];
            gd.s[t].N    = Ndst_t[t];
            gd.s[t].base = bacc;
            bacc += cdiv(Ndst_t[t], 4);
        }
        gatherall_k<<<bacc, 256, 0, stream>>>(gd);
        GemmDesc g{};
        for (int t = 0; t < 3; t++){
            int e1 = e1s[t], e2 = e2s[t];
            g.s[t] = {A[t], h[t], Wcat_t + (size_t)(L * 3 + t) * 128 * 384,
                      bl + (size_t)(L * 6 + e1) * 128, bl + (size_t)(L * 6 + e2) * 128,
                      o[t], stats + (size_t)(3 + L * 3 + t) * 256,
                      256, 128, 256, Nn[t], 384, tileBase[t], 0.5f};
        }
        gemmAll_k<128, true, true><<<tileBase[3], 256, 0, stream>>>(g);
        BnDesc bnd{}; int ib = 0;
        for (int t = 0; t < 3; t++){
            bnd.s[t] = {o[t], stats + (size_t)(3 + L * 3 + t) * 256,
                        g_conv + (size_t)(L * 3 + t) * 128, bt_conv + (size_t)(L * 3 + t) * 128,
                        h[t], Nn[t], 1.0f / Nn[t], 1, ib};
            ib += Nn[t] * 16;
        }
        bnd.total = ib;
        bnAll_k<<<cdiv(ib, 256), 256, 0, stream>>>(bnd);
    }

    // ---- final projection: one GEMM over contiguous h pool ----
    {
        int Ntot = ND + NG + NS;
        GemmDesc g{};
        g.s[0] = {h[0], h[0], Wfin_t, b_fin, nullptr, out, nullptr,
                  128, 128, 128, Ntot, 128, 0, 1.0f};
        g.s[1] = g.s[0]; g.s[1].tileBase = 0x3FFFFFFF; g.s[1].N = 0;
        g.s[2] = g.s[1];
        gemmAll_k<64, false, false><<<cdiv(Ntot, 128), 256, 0, stream>>>(g);
    }
}

// Round 7
// 712.846 us; speedup vs baseline: 3.7100x; 1.0092x over previous
//
#include <hip/hip_runtime.h>
#include <cstddef>
#include <cstdint>

typedef _Float16 f16;
typedef _Float16 f16x2 __attribute__((ext_vector_type(2)));
typedef _Float16 f16x8 __attribute__((ext_vector_type(8)));
typedef float f32x4 __attribute__((ext_vector_type(4)));

constexpr int ND = 30000, NG = 60000, NS = 15000;
constexpr float BN_EPS = 1e-5f;
constexpr int NBUCK = 64;      // buckets per edge type
constexpr int TBUCK = 6 * NBUCK;
constexpr int PCHUNK = 4096;   // edges per partition block

static inline int cdiv(int a, int b){ return (a + b - 1) / b; }

// ================= bucketed CSR construction =================

struct BDesc {
    const int* src[6]; const int* dst[6];
    int Ebase[7]; int shift[6];
    int* bCnt; int* bBase; int* bCursor;
    uint2* packed;
    int* cnt[6]; int* cursor[6]; int* csr[6];
};

__global__ __launch_bounds__(256) void bhist_k(BDesc bd){
    __shared__ int hist[TBUCK];
    int tid = threadIdx.x;
    for (int i = tid; i < TBUCK; i += 256) hist[i] = 0;
    __syncthreads();
    int Etot = bd.Ebase[6];
    #pragma unroll
    for (int u = 0; u < 16; u++){
        int e = blockIdx.x * PCHUNK + u * 256 + tid;
        if (e < Etot){
            int t = 0;
            #pragma unroll
            for (int i = 1; i < 6; i++) if (e >= bd.Ebase[i]) t = i;
            int d = bd.dst[t][e - bd.Ebase[t]];
            atomicAdd(&hist[t * NBUCK + (d >> bd.shift[t])], 1);
        }
    }
    __syncthreads();
    for (int i = tid; i < TBUCK; i += 256)
        if (hist[i]) atomicAdd(&bd.bCnt[i], hist[i]);
}

__global__ __launch_bounds__(512) void bscan_k(BDesc bd){
    __shared__ int sh[TBUCK];
    int tid = threadIdx.x;
    int my = (tid < TBUCK) ? bd.bCnt[tid] : 0;
    if (tid < TBUCK) sh[tid] = my;
    __syncthreads();
    for (int d = 1; d < TBUCK; d <<= 1){
        int v = (tid < TBUCK) ? sh[tid] : 0;
        int add = (tid >= d && tid < TBUCK) ? sh[tid - d] : 0;
        __syncthreads();
        if (tid < TBUCK) sh[tid] = v + add;
        __syncthreads();
    }
    if (tid < TBUCK){
        int excl = sh[tid] - my;
        bd.bBase[tid] = excl;
        bd.bCursor[tid] = excl;
    }
    if (tid == 0) bd.bBase[TBUCK] = sh[TBUCK - 1];
}

__global__ __launch_bounds__(256) void bpart_k(BDesc bd){
    __shared__ int hist[TBUCK];
    __shared__ int basesh[TBUCK];
    int tid = threadIdx.x;
    for (int i = tid; i < TBUCK; i += 256) hist[i] = 0;
    __syncthreads();
    int Etot = bd.Ebase[6];
    int mb[16], mr[16], ms[16], md[16];
    #pragma unroll
    for (int u = 0; u < 16; u++){
        int e = blockIdx.x * PCHUNK + u * 256 + tid;
        mb[u] = -1;
        if (e < Etot){
            int t = 0;
            #pragma unroll
            for (int i = 1; i < 6; i++) if (e >= bd.Ebase[i]) t = i;
            int le = e - bd.Ebase[t];
            int s = bd.src[t][le], d = bd.dst[t][le];
            int b = t * NBUCK + (d >> bd.shift[t]);
            mr[u] = atomicAdd(&hist[b], 1);
            mb[u] = b; ms[u] = s; md[u] = d;
        }
    }
    __syncthreads();
    for (int i = tid; i < TBUCK; i += 256)
        basesh[i] = hist[i] ? atomicAdd(&bd.bCursor[i], hist[i]) : 0;
    __syncthreads();
    #pragma unroll
    for (int u = 0; u < 16; u++){
        if (mb[u] >= 0){
            int pos = basesh[mb[u]] + mr[u];
            bd.packed[pos] = make_uint2((unsigned)ms[u], (unsigned)md[u]);
        }
    }
}

__global__ __launch_bounds__(256) void countB_k(BDesc bd){
    int e = blockIdx.x * 256 + threadIdx.x;
    if (e >= bd.Ebase[6]) return;
    int t = 0;
    #pragma unroll
    for (int i = 1; i < 6; i++) if (e >= bd.Ebase[i]) t = i;
    atomicAdd(&bd.cnt[t][bd.packed[e].y], 1);
}

__global__ __launch_bounds__(256) void fillB_k(BDesc bd){
    int e = blockIdx.x * 256 + threadIdx.x;
    if (e >= bd.Ebase[6]) return;
    int t = 0;
    #pragma unroll
    for (int i = 1; i < 6; i++) if (e >= bd.Ebase[i]) t = i;
    uint2 p = bd.packed[e];
    int pos = atomicAdd(&bd.cursor[t][p.y], 1);
    bd.csr[t][pos] = (int)p.x;
}

// ================= per-node offset scans =================

struct ScanDesc {
    int* cnt[6]; int* offs[6]; int* cursor[6]; int* partials[6];
    int N[6]; int blkBase[7];
};

__global__ __launch_bounds__(256) void scan1All_k(ScanDesc cd){
    int t = 0;
    #pragma unroll
    for (int i = 1; i < 6; i++) if ((int)blockIdx.x >= cd.blkBase[i]) t = i;
    int b = blockIdx.x - cd.blkBase[t];
    __shared__ int sh[256];
    int tid = threadIdx.x;
    int base = b * 1024 + tid * 4;
    int s = 0;
    #pragma unroll
    for (int j = 0; j < 4; j++) if (base + j < cd.N[t]) s += cd.cnt[t][base + j];
    sh[tid] = s; __syncthreads();
    for (int d = 128; d > 0; d >>= 1){
        if (tid < d) sh[tid] += sh[tid + d];
        __syncthreads();
    }
    if (tid == 0) cd.partials[t][b] = sh[0];
}

__global__ void scan2All_k(ScanDesc cd){
    int t = blockIdx.x;
    if (threadIdx.x == 0){
        int B = cd.blkBase[t + 1] - cd.blkBase[t];
        int run = 0;
        for (int i = 0; i < B; i++){ int v = cd.partials[t][i]; cd.partials[t][i] = run; run += v; }
        cd.offs[t][cd.N[t]] = run;
    }
}

__global__ __launch_bounds__(256) void scan3All_k(ScanDesc cd){
    int t = 0;
    #pragma unroll
    for (int i = 1; i < 6; i++) if ((int)blockIdx.x >= cd.blkBase[i]) t = i;
    int b = blockIdx.x - cd.blkBase[t];
    __shared__ int sh[256];
    int tid = threadIdx.x;
    int base = b * 1024 + tid * 4;
    int c[4]; int s = 0;
    #pragma unroll
    for (int j = 0; j < 4; j++){ c[j] = (base + j < cd.N[t]) ? cd.cnt[t][base + j] : 0; s += c[j]; }
    sh[tid] = s; __syncthreads();
    for (int d = 1; d < 256; d <<= 1){
        int v = sh[tid];
        int add = (tid >= d) ? sh[tid - d] : 0;
        __syncthreads();
        sh[tid] = v + add;
        __syncthreads();
    }
    int run = cd.partials[t][b] + sh[tid] - s;
    #pragma unroll
    for (int j = 0; j < 4; j++){
        if (base + j < cd.N[t]){ cd.offs[t][base + j] = run; cd.cursor[t][base + j] = run; run += c[j]; }
    }
}

// ================= prep: casts + weight transposes =================

struct CastDesc { const float* src[3]; f16* dst[3]; int base[4]; };

__global__ __launch_bounds__(256) void castAll_k(CastDesc cdsc){
    int idx = blockIdx.x * 256 + threadIdx.x;
    if (idx >= cdsc.base[3]) return;
    int t = 0;
    #pragma unroll
    for (int i = 1; i < 3; i++) if (idx >= cdsc.base[i]) t = i;
    int i4 = (idx - cdsc.base[t]) * 4;
    float4 v = *reinterpret_cast<const float4*>(cdsc.src[t] + i4);
    union { uint2 u; f16 h[4]; } o;
    o.h[0] = (f16)v.x; o.h[1] = (f16)v.y; o.h[2] = (f16)v.z; o.h[3] = (f16)v.w;
    *reinterpret_cast<uint2*>(cdsc.dst[t] + i4) = o.u;
}

struct WDesc {
    const float* W_in0; const float* W_in1; const float* W_in2;
    const float* W_fin; const float* Wl; const float* Wr;
    f16* Wint0; f16* Wint1; f16* Wint2; f16* Wfin_t; f16* Wcat_t;
};

__global__ __launch_bounds__(256) void weightAll_k(WDesc wd){
    int idx = blockIdx.x * 256 + threadIdx.x;
    if (idx < 32768){
        int c = idx >> 8, k = idx & 255;
        wd.Wint0[idx] = (f16)wd.W_in0[k * 128 + c];
    } else if (idx < 49152){
        int l = idx - 32768; int c = l >> 7, k = l & 127;
        wd.Wint1[l] = (f16)wd.W_in1[k * 128 + c];
    } else if (idx < 57344){
        int l = idx - 49152; int c = l >> 6, k = l & 63;
        wd.Wint2[l] = (f16)wd.W_in2[k * 128 + c];
    } else if (idx < 65536){
        int l = idx - 57344; int c = l >> 7, k = l & 127;
        wd.Wfin_t[l] = (f16)wd.W_fin[k * 64 + c];
    } else if (idx < 507904){
        int l = idx - 65536;
        int g = l / (384 * 128);
        int rem = l - g * (384 * 128);
        int c = rem / 384;
        int k = rem - c * 384;
        int L = g / 3, t = g - L * 3;
        const int e1s[3] = {1, 0, 2}, e2s[3] = {5, 3, 4};
        int e1 = e1s[t], e2 = e2s[t];
        float v;
        if (k < 128)      v = wd.Wl[(((size_t)L * 6 + e1) * 128 + k) * 128 + c];
        else if (k < 256) v = wd.Wl[(((size_t)L * 6 + e2) * 128 + (k - 128)) * 128 + c];
        else {
            int kr = k - 256;
            v = wd.Wr[(((size_t)L * 6 + e1) * 128 + kr) * 128 + c]
              + wd.Wr[(((size_t)L * 6 + e2) * 128 + kr) * 128 + c];
        }
        wd.Wcat_t[l] = (f16)v;
    }
}

// ================= fused gather-mean: wave/node, 16 lanes/row, packed f16 accumulate =================
// Wave = 1 node. Lane = (grp: lane>>4, li: lane&15). Group g reads neighbor rows as
// uint4 (16B = 8 f16); running sum kept as f16x8 (v_pk_add_f16, 4 VALU per row-fragment).
// Indices coalesced-loaded once per 64-edge chunk, broadcast via shfl. 8 rows in flight.

struct GSeg { const int* offs; const int* csr; const uint4* h; uint4* A; int colPair4; int N; int base; };
struct GDesc { GSeg s[6]; const uint4* zrow; };

__device__ __forceinline__ f16x8 as_h8(uint4 v){
    union { uint4 u; f16x8 h; } c; c.u = v; return c.h;
}

__device__ __forceinline__ f16x8 shfl_xor8(f16x8 v, int mask){
    union { f16x8 h; int u[4]; } c; c.h = v;
    #pragma unroll
    for (int i = 0; i < 4; i++) c.u[i] = __shfl_xor(c.u[i], mask);
    return c.h;
}

__global__ __launch_bounds__(256) void gatherall_k(GDesc gd){
    int bid = blockIdx.x;
    int si = 0;
    #pragma unroll
    for (int t = 1; t < 6; t++) if (bid >= gd.s[t].base) si = t;
    GSeg sg = gd.s[si];
    int node = (bid - sg.base) * 4 + (threadIdx.x >> 6);
    if (node >= sg.N) return;
    int lane = threadIdx.x & 63;
    int grp = lane >> 4, li = lane & 15;
    int s = sg.offs[node], e = sg.offs[node + 1];
    const int* cp = sg.csr;
    const uint4* hp = sg.h;
    f16x8 a = {};
    for (int c = s; c < e; c += 64){
        int nchunk = e - c; if (nchunk > 64) nchunk = 64;
        int idx = (lane < nchunk) ? cp[c + lane] : 0;
        int r = 0;
        for (; r + 32 <= nchunk; r += 32){
            int i0 = __shfl(idx, r + grp);
            int i1 = __shfl(idx, r + 4  + grp);
            int i2 = __shfl(idx, r + 8  + grp);
            int i3 = __shfl(idx, r + 12 + grp);
            int i4 = __shfl(idx, r + 16 + grp);
            int i5 = __shfl(idx, r + 20 + grp);
            int i6 = __shfl(idx, r + 24 + grp);
            int i7 = __shfl(idx, r + 28 + grp);
            uint4 v0 = hp[(size_t)i0 * 16 + li];
            uint4 v1 = hp[(size_t)i1 * 16 + li];
            uint4 v2 = hp[(size_t)i2 * 16 + li];
            uint4 v3 = hp[(size_t)i3 * 16 + li];
            uint4 v4 = hp[(size_t)i4 * 16 + li];
            uint4 v5 = hp[(size_t)i5 * 16 + li];
            uint4 v6 = hp[(size_t)i6 * 16 + li];
            uint4 v7 = hp[(size_t)i7 * 16 + li];
            a = a + as_h8(v0); a = a + as_h8(v1); a = a + as_h8(v2); a = a + as_h8(v3);
            a = a + as_h8(v4); a = a + as_h8(v5); a = a + as_h8(v6); a = a + as_h8(v7);
        }
        if (r + 16 <= nchunk){
            int i0 = __shfl(idx, r + grp);
            int i1 = __shfl(idx, r + 4  + grp);
            int i2 = __shfl(idx, r + 8  + grp);
            int i3 = __shfl(idx, r + 12 + grp);
            uint4 v0 = hp[(size_t)i0 * 16 + li];
            uint4 v1 = hp[(size_t)i1 * 16 + li];
            uint4 v2 = hp[(size_t)i2 * 16 + li];
            uint4 v3 = hp[(size_t)i3 * 16 + li];
            a = a + as_h8(v0); a = a + as_h8(v1); a = a + as_h8(v2); a = a + as_h8(v3);
            r += 16;
        }
        for (; r < nchunk; r += 4){
            int ei = __shfl(idx, r + grp);
            const uint4* rp = ((r + grp) < nchunk) ? (hp + (size_t)ei * 16) : gd.zrow;
            a = a + as_h8(rp[li]);
        }
    }
    a = a + shfl_xor8(a, 16);
    a = a + shfl_xor8(a, 32);
    if (grp == 0){
        float inv = (e > s) ? 1.0f / (float)(e - s) : 0.f;
        union { uint4 u; f16 h[8]; } pk;
        #pragma unroll
        for (int i = 0; i < 8; i++) pk.h[i] = (f16)((float)a[i] * inv);
        sg.A[(size_t)node * 32 + sg.colPair4 + li] = pk.u;
    }
}

// ================= merged MFMA fp16 GEMM (up to 3 segments) =================

struct GemmSeg {
    const f16* A1; const f16* A2; const f16* Wt;
    const float* b1; const float* b2; void* out; float* stats;
    int lda1, lda2, ksplit, N, K, tileBase; float scale;
};
struct GemmDesc { GemmSeg s[3]; };

template<int BN, bool STATS, bool OUT16>
__global__ __launch_bounds__(256) void gemmAll_k(GemmDesc gd){
    constexpr int BK = 64, PAD = 72, CF = BN / 16;
    __shared__ f16 As[128 * PAD];
    __shared__ f16 Bs[BN * PAD];
    __shared__ float ssum[BN];
    __shared__ float ssq[BN];
    int bid = blockIdx.x;
    int si = 0;
    #pragma unroll
    for (int t = 1; t < 3; t++) if (bid >= gd.s[t].tileBase) si = t;
    GemmSeg sg = gd.s[si];
    int tid = threadIdx.x;
    int wv = tid >> 6, lane = tid & 63;
    int row0 = (bid - sg.tileBase) * 128;
    int N = sg.N, K = sg.K;
    if (STATS && tid < BN){ ssum[tid] = 0.f; ssq[tid] = 0.f; }

    f32x4 acc[2][CF];
    #pragma unroll
    for (int rf = 0; rf < 2; rf++)
        #pragma unroll
        for (int cf = 0; cf < CF; cf++)
            acc[rf][cf] = (f32x4){0.f, 0.f, 0.f, 0.f};

    for (int k0 = 0; k0 < K; k0 += BK){
        const f16* Ab; int lda, kloc;
        if (k0 < sg.ksplit){ Ab = sg.A1; lda = sg.lda1; kloc = k0; }
        else               { Ab = sg.A2; lda = sg.lda2; kloc = k0 - sg.ksplit; }
        #pragma unroll
        for (int p = 0; p < 4; p++){
            int f = tid + p * 256;
            int r = f >> 3, sgm = f & 7;
            int gr = row0 + r;
            uint4 v = make_uint4(0u, 0u, 0u, 0u);
            if (gr < N) v = *reinterpret_cast<const uint4*>(Ab + (size_t)gr * lda + kloc + sgm * 8);
            *reinterpret_cast<uint4*>(As + r * PAD + sgm * 8) = v;
        }
        #pragma unroll
        for (int p = 0; p < BN / 32; p++){
            int f = tid + p * 256;
            int r = f >> 3, sgm = f & 7;
            uint4 v = *reinterpret_cast<const uint4*>(sg.Wt + (size_t)r * K + k0 + sgm * 8);
            *reinterpret_cast<uint4*>(Bs + r * PAD + sgm * 8) = v;
        }
        __syncthreads();
        #pragma unroll
        for (int kf = 0; kf < 2; kf++){
            int kb = kf * 32 + (lane >> 4) * 8;
            f16x8 a0 = *reinterpret_cast<const f16x8*>(As + (wv * 32 + (lane & 15)) * PAD + kb);
            f16x8 a1 = *reinterpret_cast<const f16x8*>(As + (wv * 32 + 16 + (lane & 15)) * PAD + kb);
            #pragma unroll
            for (int cf = 0; cf < CF; cf++){
                f16x8 b = *reinterpret_cast<const f16x8*>(Bs + (cf * 16 + (lane & 15)) * PAD + kb);
                acc[0][cf] = __builtin_amdgcn_mfma_f32_16x16x32_f16(a0, b, acc[0][cf], 0, 0, 0);
                acc[1][cf] = __builtin_amdgcn_mfma_f32_16x16x32_f16(a1, b, acc[1][cf], 0, 0, 0);
            }
        }
        __syncthreads();
    }
    int rbase = row0 + wv * 32 + ((lane >> 4) << 2);
    #pragma unroll
    for (int cf = 0; cf < CF; cf++){
        int col = cf * 16 + (lane & 15);
        float bias = 0.f;
        if (sg.b1) bias += sg.b1[col];
        if (sg.b2) bias += sg.b2[col];
        float ls = 0.f, lq = 0.f;
        #pragma unroll
        for (int rf = 0; rf < 2; rf++){
            #pragma unroll
            for (int q = 0; q < 4; q++){
                int gr = rbase + rf * 16 + q;
                if (gr < N){
                    float v = sg.scale * (acc[rf][cf][q] + bias);
                    if (OUT16) ((f16*)sg.out)[(size_t)gr * BN + col] = (f16)v;
                    else       ((float*)sg.out)[(size_t)gr * BN + col] = v;
                    ls += v; lq += v * v;
                }
            }
        }
        if (STATS){ atomicAdd(&ssum[col], ls); atomicAdd(&ssq[col], lq); }
    }
    if (STATS){
        __syncthreads();
        if (tid < BN){
            atomicAdd(&sg.stats[tid], ssum[tid]);
            atomicAdd(&sg.stats[128 + tid], ssq[tid]);
        }
    }
}

// ================= merged BN apply + ReLU (+ residual) =================

struct BnSeg { const f16* o; const float* stats; const float* g; const float* b; f16* h; int N; float invN; int residual; int idxBase; };
struct BnDesc { BnSeg s[3]; int total; };

__global__ __launch_bounds__(256) void bnAll_k(BnDesc bd){
    int idx = blockIdx.x * 256 + threadIdx.x;
    if (idx >= bd.total) return;
    int si = 0;
    #pragma unroll
    for (int t = 1; t < 3; t++) if (idx >= bd.s[t].idxBase) si = t;
    BnSeg sg = bd.s[si];
    int l = idx - sg.idxBase;
    int n = l >> 4, c8 = (l & 15) * 8;
    union { uint4 u; f16 h[8]; } ov;
    ov.u = *reinterpret_cast<const uint4*>(sg.o + (size_t)n * 128 + c8);
    float r[8];
    #pragma unroll
    for (int j = 0; j < 8; j++){
        int c = c8 + j;
        float mu  = sg.stats[c] * sg.invN;
        float var = sg.stats[128 + c] * sg.invN - mu * mu;
        float v = ((float)ov.h[j] - mu) * rsqrtf(var + BN_EPS) * sg.g[c] + sg.b[c];
        r[j] = v > 0.f ? v : 0.f;
    }
    f16* hp = sg.h + (size_t)n * 128 + c8;
    if (sg.residual){
        uint4 old = *reinterpret_cast<const uint4*>(hp);
        union { uint4 u; f16 h[8]; } ou; ou.u = old;
        #pragma unroll
        for (int j = 0; j < 8; j++) r[j] += (float)ou.h[j];
    }
    union { uint4 u; f16 h[8]; } pk;
    #pragma unroll
    for (int j = 0; j < 8; j++) pk.h[j] = (f16)r[j];
    *reinterpret_cast<uint4*>(hp) = pk.u;
}

// ================= host orchestration =================

extern "C" void kernel_launch(void* const* d_in, const int* in_sizes, int n_in,
                              void* d_out, int out_size, void* d_ws, size_t ws_size,
                              hipStream_t stream){
    const float* x_drug = (const float*)d_in[0];
    const float* x_gene = (const float*)d_in[1];
    const float* x_dis  = (const float*)d_in[2];
    const int* srcP[6] = {(const int*)d_in[3], (const int*)d_in[5], (const int*)d_in[7],
                          (const int*)d_in[9], (const int*)d_in[11], (const int*)d_in[13]};
    const int* dstP[6] = {(const int*)d_in[4], (const int*)d_in[6], (const int*)d_in[8],
                          (const int*)d_in[10], (const int*)d_in[12], (const int*)d_in[14]};
    const int  Et[6]   = {in_sizes[3], in_sizes[5], in_sizes[7], in_sizes[9], in_sizes[11], in_sizes[13]};
    const float* W_in[3] = {(const float*)d_in[15], (const float*)d_in[17], (const float*)d_in[19]};
    const float* b_in[3] = {(const float*)d_in[16], (const float*)d_in[18], (const float*)d_in[20]};
    const float* g_in  = (const float*)d_in[21];
    const float* bt_in = (const float*)d_in[22];
    const float* Wl    = (const float*)d_in[23];
    const float* Wr    = (const float*)d_in[24];
    const float* bl    = (const float*)d_in[25];
    const float* g_conv  = (const float*)d_in[26];
    const float* bt_conv = (const float*)d_in[27];
    const float* W_fin = (const float*)d_in[28];
    const float* b_fin = (const float*)d_in[29];
    float* out = (float*)d_out;

    // edge-type metadata (order: dg, gd, gs, sg, ds, sd)
    const int Ndst_t[6]     = {NG, ND, NS, NG, NS, ND};
    const int srcT[6]       = {0, 1, 1, 2, 0, 2};
    const int dstT[6]       = {1, 0, 2, 1, 2, 0};
    const int colPair4_t[6] = {0, 0, 0, 16, 16, 16};

    const int Nn[3]  = {ND, NG, NS};
    const int Kin[3] = {256, 128, 64};
    const float* xin[3] = {x_drug, x_gene, x_dis};

    // ---- workspace carve ----
    char* base = (char*)d_ws;
    size_t off = 0;
    auto alloc = [&](size_t bytes) -> char* {
        char* p = base + off; off += (bytes + 255) & ~(size_t)255; return p;
    };
    f16* h[3];  for (int t = 0; t < 3; t++) h[t]  = (f16*)alloc((size_t)Nn[t] * 128 * 2);
    f16* A[3];  for (int t = 0; t < 3; t++) A[t]  = (f16*)alloc((size_t)Nn[t] * 256 * 2);
    f16* xb[3]; for (int t = 0; t < 3; t++) xb[t] = (f16*)alloc((size_t)Nn[t] * Kin[t] * 2);
    f16* Wint[3]; for (int t = 0; t < 3; t++) Wint[t] = (f16*)alloc((size_t)128 * Kin[t] * 2);
    f16* Wfin_t = (f16*)alloc((size_t)64 * 128 * 2);
    f16* Wcat_t = (f16*)alloc((size_t)9 * 128 * 384 * 2);
    // o pool (aliased by packed edge buffer during CSR build, which finishes first)
    char* oPool = alloc((size_t)(ND + NG + NS) * 128 * 2);
    f16* o[3];
    o[0] = (f16*)oPool; o[1] = o[0] + (size_t)ND * 128; o[2] = o[1] + (size_t)NG * 128;
    uint2* packed = (uint2*)oPool;
    float* stats = (float*)alloc(12 * 256 * 4);
    // zero pool: per-node cnt (all types) + bucket counters + 256B zero row
    int cntTot = 0; for (int t = 0; t < 6; t++) cntTot += Ndst_t[t];
    int* zeroPool = (int*)alloc((size_t)(cntTot + TBUCK + 64) * 4);
    int* cnt[6]; { int a = 0; for (int t = 0; t < 6; t++){ cnt[t] = zeroPool + a; a += Ndst_t[t]; } }
    int* bCnt = zeroPool + cntTot;
    const uint4* zrow = (const uint4*)(zeroPool + cntTot + TBUCK);
    int* bBase   = (int*)alloc((TBUCK + 1) * 4);
    int* bCursor = (int*)alloc(TBUCK * 4);
    int *offs[6], *cursor[6], *csr[6], *partials[6];
    for (int t = 0; t < 6; t++) offs[t]     = (int*)alloc((size_t)(Ndst_t[t] + 1) * 4);
    for (int t = 0; t < 6; t++) cursor[t]   = (int*)alloc((size_t)Ndst_t[t] * 4);
    for (int t = 0; t < 6; t++) partials[t] = (int*)alloc(64 * 4);
    for (int t = 0; t < 6; t++) csr[t]      = (int*)alloc((size_t)Et[t] * 4);

    hipMemsetAsync(zeroPool, 0, (size_t)(cntTot + TBUCK + 64) * 4, stream);
    hipMemsetAsync(stats, 0, 12 * 256 * 4, stream);

    // ---- bucketed CSR build ----
    BDesc bd;
    {
        int ecum = 0;
        for (int t = 0; t < 6; t++){
            bd.src[t] = srcP[t]; bd.dst[t] = dstP[t];
            bd.Ebase[t] = ecum; ecum += Et[t];
            int sft = 0; while (((Ndst_t[t] - 1) >> sft) >= NBUCK) sft++;
            bd.shift[t] = sft;
            bd.cnt[t] = cnt[t]; bd.cursor[t] = cursor[t]; bd.csr[t] = csr[t];
        }
        bd.Ebase[6] = ecum;
        bd.bCnt = bCnt; bd.bBase = bBase; bd.bCursor = bCursor;
        bd.packed = packed;
    }
    int Etot = bd.Ebase[6];
    bhist_k<<<cdiv(Etot, PCHUNK), 256, 0, stream>>>(bd);
    bscan_k<<<1, 512, 0, stream>>>(bd);
    bpart_k<<<cdiv(Etot, PCHUNK), 256, 0, stream>>>(bd);
    countB_k<<<cdiv(Etot, 256), 256, 0, stream>>>(bd);

    ScanDesc sd;
    {
        int bcum = 0;
        for (int t = 0; t < 6; t++){
            sd.cnt[t] = cnt[t]; sd.offs[t] = offs[t]; sd.cursor[t] = cursor[t];
            sd.partials[t] = partials[t];
            sd.N[t] = Ndst_t[t];
            sd.blkBase[t] = bcum; bcum += cdiv(Ndst_t[t], 1024);
        }
        sd.blkBase[6] = bcum;
    }
    scan1All_k<<<sd.blkBase[6], 256, 0, stream>>>(sd);
    scan2All_k<<<6, 64, 0, stream>>>(sd);
    scan3All_k<<<sd.blkBase[6], 256, 0, stream>>>(sd);
    fillB_k<<<cdiv(Etot, 256), 256, 0, stream>>>(bd);

    // ---- casts + weights ----
    CastDesc cds;
    {
        int b = 0;
        for (int t = 0; t < 3; t++){
            cds.src[t] = xin[t]; cds.dst[t] = xb[t];
            cds.base[t] = b; b += Nn[t] * Kin[t] / 4;
        }
        cds.base[3] = b;
    }
    castAll_k<<<cdiv(cds.base[3], 256), 256, 0, stream>>>(cds);
    WDesc wd = {W_in[0], W_in[1], W_in[2], W_fin, Wl, Wr,
                Wint[0], Wint[1], Wint[2], Wfin_t, Wcat_t};
    weightAll_k<<<cdiv(507904, 256), 256, 0, stream>>>(wd);

    int tiles[3]; for (int t = 0; t < 3; t++) tiles[t] = cdiv(Nn[t], 128);
    int tileBase[4] = {0, tiles[0], tiles[0] + tiles[1], tiles[0] + tiles[1] + tiles[2]};

    // ---- input stage ----
    {
        GemmDesc g{};
        for (int t = 0; t < 3; t++){
            g.s[t] = {xb[t], xb[t], Wint[t], b_in[t], nullptr, o[t], stats + t * 256,
                      Kin[t], Kin[t], Kin[t], Nn[t], Kin[t], tileBase[t], 1.0f};
        }
        gemmAll_k<128, true, true><<<tileBase[3], 256, 0, stream>>>(g);
        BnDesc bnd{}; int ib = 0;
        for (int t = 0; t < 3; t++){
            bnd.s[t] = {o[t], stats + t * 256, g_in + t * 128, bt_in + t * 128, h[t],
                        Nn[t], 1.0f / Nn[t], 0, ib};
            ib += Nn[t] * 16;
        }
        bnd.total = ib;
        bnAll_k<<<cdiv(ib, 256), 256, 0, stream>>>(bnd);
    }

    // ---- 3 conv layers ----
    const int e1s[3] = {1, 0, 2}, e2s[3] = {5, 3, 4};
    for (int L = 0; L < 3; L++){
        GDesc gd; int bacc = 0;
        gd.zrow = zrow;
        for (int t = 0; t < 6; t++){
            gd.s[t].offs = offs[t];
            gd.s[t].csr  = csr[t];
            gd.s[t].h    = (const uint4*)h[srcT[t]];
            gd.s[t].A    = (uint4*)A[dstT[t]];
            gd.s[t].colPair4 = colPair4_t[t];
            gd.s[t].N    = Ndst_t[t];
            gd.s[t].base = bacc;
            bacc += cdiv(Ndst_t[t], 4);
        }
        gatherall_k<<<bacc, 256, 0, stream>>>(gd);
        GemmDesc g{};
        for (int t = 0; t < 3; t++){
            int e1 = e1s[t], e2 = e2s[t];
            g.s[t] = {A[t], h[t], Wcat_t + (size_t)(L * 3 + t) * 128 * 384,
                      bl + (size_t)(L * 6 + e1) * 128, bl + (size_t)(L * 6 + e2) * 128,
                      o[t], stats + (size_t)(3 + L * 3 + t) * 256,
                      256, 128, 256, Nn[t], 384, tileBase[t], 0.5f};
        }
        gemmAll_k<128, true, true><<<tileBase[3], 256, 0, stream>>>(g);
        BnDesc bnd{}; int ib = 0;
        for (int t = 0; t < 3; t++){
            bnd.s[t] = {o[t], stats + (size_t)(3 + L * 3 + t) * 256,
                        g_conv + (size_t)(L * 3 + t) * 128, bt_conv + (size_t)(L * 3 + t) * 128,
                        h[t], Nn[t], 1.0f / Nn[t], 1, ib};
            ib += Nn[t] * 16;
        }
        bnd.total = ib;
        bnAll_k<<<cdiv(ib, 256), 256, 0, stream>>>(bnd);
    }

    // ---- final projection: one GEMM over contiguous h pool ----
    {
        int Ntot = ND + NG + NS;
        GemmDesc g{};
        g.s[0] = {h[0], h[0], Wfin_t, b_fin, nullptr, out, nullptr,
                  128, 128, 128, Ntot, 128, 0, 1.0f};
        g.s[1] = g.s[0]; g.s[1].tileBase = 0x3FFFFFFF; g.s[1].N = 0;
        g.s[2] = g.s[1];
        gemmAll_k<64, false, false><<<cdiv(Ntot, 128), 256, 0, stream>>>(g);
    }
}

// Round 8
// 612.296 us; speedup vs baseline: 4.3193x; 1.1642x over previous
//
#include <hip/hip_runtime.h>
#include <cstddef>
#include <cstdint>

typedef _Float16 f16;
typedef _Float16 f16x8 __attribute__((ext_vector_type(8)));
typedef float f32x4 __attribute__((ext_vector_type(4)));

constexpr int ND = 30000, NG = 60000, NS = 15000;
constexpr float BN_EPS = 1e-5f;
constexpr int NBUCK = 64;      // buckets per edge type
constexpr int TBUCK = 6 * NBUCK;
constexpr int PCHUNK = 4096;   // edges per partition block

static inline int cdiv(int a, int b){ return (a + b - 1) / b; }

// ================= bucketed CSR construction =================

struct BDesc {
    const int* src[6]; const int* dst[6];
    int Ebase[7]; int shift[6]; int N[6];
    int* bCnt; int* bBase; int* bCursor;
    uint2* packed;
    int* offs[6]; int* csr[6];
};

__global__ __launch_bounds__(256) void bhist_k(BDesc bd){
    __shared__ int hist[TBUCK];
    int tid = threadIdx.x;
    for (int i = tid; i < TBUCK; i += 256) hist[i] = 0;
    __syncthreads();
    int Etot = bd.Ebase[6];
    #pragma unroll
    for (int u = 0; u < 16; u++){
        int e = blockIdx.x * PCHUNK + u * 256 + tid;
        if (e < Etot){
            int t = 0;
            #pragma unroll
            for (int i = 1; i < 6; i++) if (e >= bd.Ebase[i]) t = i;
            int d = bd.dst[t][e - bd.Ebase[t]];
            atomicAdd(&hist[t * NBUCK + (d >> bd.shift[t])], 1);
        }
    }
    __syncthreads();
    for (int i = tid; i < TBUCK; i += 256)
        if (hist[i]) atomicAdd(&bd.bCnt[i], hist[i]);
}

__global__ __launch_bounds__(512) void bscan_k(BDesc bd){
    __shared__ int sh[TBUCK];
    int tid = threadIdx.x;
    int my = (tid < TBUCK) ? bd.bCnt[tid] : 0;
    if (tid < TBUCK) sh[tid] = my;
    __syncthreads();
    for (int d = 1; d < TBUCK; d <<= 1){
        int v = (tid < TBUCK) ? sh[tid] : 0;
        int add = (tid >= d && tid < TBUCK) ? sh[tid - d] : 0;
        __syncthreads();
        if (tid < TBUCK) sh[tid] = v + add;
        __syncthreads();
    }
    if (tid < TBUCK){
        int excl = sh[tid] - my;
        bd.bBase[tid] = excl;
        bd.bCursor[tid] = excl;
    }
    if (tid == 0) bd.bBase[TBUCK] = sh[TBUCK - 1];
}

__global__ __launch_bounds__(256) void bpart_k(BDesc bd){
    __shared__ int hist[TBUCK];
    __shared__ int basesh[TBUCK];
    int tid = threadIdx.x;
    for (int i = tid; i < TBUCK; i += 256) hist[i] = 0;
    __syncthreads();
    int Etot = bd.Ebase[6];
    int mb[16], mr[16], ms[16], md[16];
    #pragma unroll
    for (int u = 0; u < 16; u++){
        int e = blockIdx.x * PCHUNK + u * 256 + tid;
        mb[u] = -1;
        if (e < Etot){
            int t = 0;
            #pragma unroll
            for (int i = 1; i < 6; i++) if (e >= bd.Ebase[i]) t = i;
            int le = e - bd.Ebase[t];
            int s = bd.src[t][le], d = bd.dst[t][le];
            int b = t * NBUCK + (d >> bd.shift[t]);
            mr[u] = atomicAdd(&hist[b], 1);
            mb[u] = b; ms[u] = s; md[u] = d;
        }
    }
    __syncthreads();
    for (int i = tid; i < TBUCK; i += 256)
        basesh[i] = hist[i] ? atomicAdd(&bd.bCursor[i], hist[i]) : 0;
    __syncthreads();
    #pragma unroll
    for (int u = 0; u < 16; u++){
        if (mb[u] >= 0){
            int pos = basesh[mb[u]] + mr[u];
            bd.packed[pos] = make_uint2((unsigned)ms[u], (unsigned)md[u]);
        }
    }
}

// one block per bucket: count -> scan -> offs -> fill (all LDS-local)
__global__ __launch_bounds__(256) void bucketCsr_k(BDesc bd){
    __shared__ int cnt[1024];
    __shared__ int sh[256];
    int b = blockIdx.x;
    int t = b >> 6;          // /NBUCK
    int bb = b & 63;
    int tid = threadIdx.x;
    int shift = bd.shift[t];
    int nodeBase = bb << shift;
    int Nt = bd.N[t];
    int span = 1 << shift;   // <= 1024
    int tbase = bd.bBase[t * NBUCK];
    int eBeg = bd.bBase[b], eEnd = bd.bBase[b + 1];
    int bLocal = eBeg - tbase;
    #pragma unroll
    for (int i = 0; i < 4; i++) cnt[tid + i * 256] = 0;
    __syncthreads();
    for (int e = eBeg + tid; e < eEnd; e += 256)
        atomicAdd(&cnt[(int)bd.packed[e].y - nodeBase], 1);
    __syncthreads();
    // scan 1024 entries (4 per thread, compile-time indices)
    int c0 = cnt[tid * 4], c1 = cnt[tid * 4 + 1], c2 = cnt[tid * 4 + 2], c3 = cnt[tid * 4 + 3];
    int s = c0 + c1 + c2 + c3;
    sh[tid] = s;
    __syncthreads();
    for (int d = 1; d < 256; d <<= 1){
        int v = sh[tid];
        int add = (tid >= d) ? sh[tid - d] : 0;
        __syncthreads();
        sh[tid] = v + add;
        __syncthreads();
    }
    int run = sh[tid] - s;
    int idx = tid * 4;
    int ex0 = run, ex1 = run + c0, ex2 = ex1 + c1, ex3 = ex2 + c2;
    if (idx     < span && nodeBase + idx     < Nt) bd.offs[t][nodeBase + idx]     = bLocal + ex0;
    if (idx + 1 < span && nodeBase + idx + 1 < Nt) bd.offs[t][nodeBase + idx + 1] = bLocal + ex1;
    if (idx + 2 < span && nodeBase + idx + 2 < Nt) bd.offs[t][nodeBase + idx + 2] = bLocal + ex2;
    if (idx + 3 < span && nodeBase + idx + 3 < Nt) bd.offs[t][nodeBase + idx + 3] = bLocal + ex3;
    cnt[idx] = ex0; cnt[idx + 1] = ex1; cnt[idx + 2] = ex2; cnt[idx + 3] = ex3;
    __syncthreads();
    for (int e = eBeg + tid; e < eEnd; e += 256){
        uint2 p = bd.packed[e];
        int lpos = atomicAdd(&cnt[(int)p.y - nodeBase], 1);
        bd.csr[t][bLocal + lpos] = (int)p.x;
    }
    if (bb == NBUCK - 1 && tid == 0)
        bd.offs[t][Nt] = bd.bBase[(t + 1) * NBUCK] - tbase;
}

// ================= prep: casts + weight transposes =================

struct CastDesc { const float* src[3]; f16* dst[3]; int base[4]; };

__global__ __launch_bounds__(256) void castAll_k(CastDesc cdsc){
    int idx = blockIdx.x * 256 + threadIdx.x;
    if (idx >= cdsc.base[3]) return;
    int t = 0;
    #pragma unroll
    for (int i = 1; i < 3; i++) if (idx >= cdsc.base[i]) t = i;
    int i4 = (idx - cdsc.base[t]) * 4;
    float4 v = *reinterpret_cast<const float4*>(cdsc.src[t] + i4);
    union { uint2 u; f16 h[4]; } o;
    o.h[0] = (f16)v.x; o.h[1] = (f16)v.y; o.h[2] = (f16)v.z; o.h[3] = (f16)v.w;
    *reinterpret_cast<uint2*>(cdsc.dst[t] + i4) = o.u;
}

struct WDesc {
    const float* W_in0; const float* W_in1; const float* W_in2;
    const float* W_fin; const float* Wl; const float* Wr;
    f16* Wint0; f16* Wint1; f16* Wint2; f16* Wfin_t; f16* Wcat_t;
};

__global__ __launch_bounds__(256) void weightAll_k(WDesc wd){
    int idx = blockIdx.x * 256 + threadIdx.x;
    if (idx < 32768){
        int c = idx >> 8, k = idx & 255;
        wd.Wint0[idx] = (f16)wd.W_in0[k * 128 + c];
    } else if (idx < 49152){
        int l = idx - 32768; int c = l >> 7, k = l & 127;
        wd.Wint1[l] = (f16)wd.W_in1[k * 128 + c];
    } else if (idx < 57344){
        int l = idx - 49152; int c = l >> 6, k = l & 63;
        wd.Wint2[l] = (f16)wd.W_in2[k * 128 + c];
    } else if (idx < 65536){
        int l = idx - 57344; int c = l >> 7, k = l & 127;
        wd.Wfin_t[l] = (f16)wd.W_fin[k * 64 + c];
    } else if (idx < 507904){
        int l = idx - 65536;
        int g = l / (384 * 128);
        int rem = l - g * (384 * 128);
        int c = rem / 384;
        int k = rem - c * 384;
        int L = g / 3, t = g - L * 3;
        const int e1s[3] = {1, 0, 2}, e2s[3] = {5, 3, 4};
        int e1 = e1s[t], e2 = e2s[t];
        float v;
        if (k < 128)      v = wd.Wl[(((size_t)L * 6 + e1) * 128 + k) * 128 + c];
        else if (k < 256) v = wd.Wl[(((size_t)L * 6 + e2) * 128 + (k - 128)) * 128 + c];
        else {
            int kr = k - 256;
            v = wd.Wr[(((size_t)L * 6 + e1) * 128 + kr) * 128 + c]
              + wd.Wr[(((size_t)L * 6 + e2) * 128 + kr) * 128 + c];
        }
        wd.Wcat_t[l] = (f16)v;
    }
}

// ================= fused gather-mean (unchanged round-7 structure) =================

struct GSeg { const int* offs; const int* csr; const uint4* h; uint4* A; int colPair4; int N; int base; };
struct GDesc { GSeg s[6]; const uint4* zrow; };

__device__ __forceinline__ f16x8 as_h8(uint4 v){
    union { uint4 u; f16x8 h; } c; c.u = v; return c.h;
}

__device__ __forceinline__ f16x8 shfl_xor8(f16x8 v, int mask){
    union { f16x8 h; int u[4]; } c; c.h = v;
    #pragma unroll
    for (int i = 0; i < 4; i++) c.u[i] = __shfl_xor(c.u[i], mask);
    return c.h;
}

__global__ __launch_bounds__(256) void gatherall_k(GDesc gd){
    int bid = blockIdx.x;
    int si = 0;
    #pragma unroll
    for (int t = 1; t < 6; t++) if (bid >= gd.s[t].base) si = t;
    GSeg sg = gd.s[si];
    int node = (bid - sg.base) * 4 + (threadIdx.x >> 6);
    if (node >= sg.N) return;
    int lane = threadIdx.x & 63;
    int grp = lane >> 4, li = lane & 15;
    int s = sg.offs[node], e = sg.offs[node + 1];
    const int* cp = sg.csr;
    const uint4* hp = sg.h;
    f16x8 a = {};
    for (int c = s; c < e; c += 64){
        int nchunk = e - c; if (nchunk > 64) nchunk = 64;
        int idx = (lane < nchunk) ? cp[c + lane] : 0;
        int r = 0;
        for (; r + 32 <= nchunk; r += 32){
            int i0 = __shfl(idx, r + grp);
            int i1 = __shfl(idx, r + 4  + grp);
            int i2 = __shfl(idx, r + 8  + grp);
            int i3 = __shfl(idx, r + 12 + grp);
            int i4 = __shfl(idx, r + 16 + grp);
            int i5 = __shfl(idx, r + 20 + grp);
            int i6 = __shfl(idx, r + 24 + grp);
            int i7 = __shfl(idx, r + 28 + grp);
            uint4 v0 = hp[(size_t)i0 * 16 + li];
            uint4 v1 = hp[(size_t)i1 * 16 + li];
            uint4 v2 = hp[(size_t)i2 * 16 + li];
            uint4 v3 = hp[(size_t)i3 * 16 + li];
            uint4 v4 = hp[(size_t)i4 * 16 + li];
            uint4 v5 = hp[(size_t)i5 * 16 + li];
            uint4 v6 = hp[(size_t)i6 * 16 + li];
            uint4 v7 = hp[(size_t)i7 * 16 + li];
            a = a + as_h8(v0); a = a + as_h8(v1); a = a + as_h8(v2); a = a + as_h8(v3);
            a = a + as_h8(v4); a = a + as_h8(v5); a = a + as_h8(v6); a = a + as_h8(v7);
        }
        if (r + 16 <= nchunk){
            int i0 = __shfl(idx, r + grp);
            int i1 = __shfl(idx, r + 4  + grp);
            int i2 = __shfl(idx, r + 8  + grp);
            int i3 = __shfl(idx, r + 12 + grp);
            uint4 v0 = hp[(size_t)i0 * 16 + li];
            uint4 v1 = hp[(size_t)i1 * 16 + li];
            uint4 v2 = hp[(size_t)i2 * 16 + li];
            uint4 v3 = hp[(size_t)i3 * 16 + li];
            a = a + as_h8(v0); a = a + as_h8(v1); a = a + as_h8(v2); a = a + as_h8(v3);
            r += 16;
        }
        for (; r < nchunk; r += 4){
            int ei = __shfl(idx, r + grp);
            const uint4* rp = ((r + grp) < nchunk) ? (hp + (size_t)ei * 16) : gd.zrow;
            a = a + as_h8(rp[li]);
        }
    }
    a = a + shfl_xor8(a, 16);
    a = a + shfl_xor8(a, 32);
    if (grp == 0){
        float inv = (e > s) ? 1.0f / (float)(e - s) : 0.f;
        union { uint4 u; f16 h[8]; } pk;
        #pragma unroll
        for (int i = 0; i < 8; i++) pk.h[i] = (f16)((float)a[i] * inv);
        sg.A[(size_t)node * 32 + sg.colPair4 + li] = pk.u;
    }
}

// ================= merged MFMA fp16 GEMM: global_load_lds + XOR swizzle =================
// LDS layout: As[r][seg] (linear, 64 f16/row) holds GLOBAL segment (seg ^ (r&7)) of row r.
// Reader fetches G[row][kidx] from LDS slot (kidx ^ (row&7)). Conflict-free b128 reads.
// OOB tile rows read adjacent ws memory (valid); their outputs are discarded (gr<N guards).

struct GemmSeg {
    const f16* A1; const f16* A2; const f16* Wt;
    const float* b1; const float* b2; void* out; float* stats;
    int lda1, lda2, ksplit, N, K, tileBase; float scale;
};
struct GemmDesc { GemmSeg s[3]; };

template<int BN, bool STATS, bool OUT16>
__global__ __launch_bounds__(256) void gemmAll_k(GemmDesc gd){
    constexpr int CF = BN / 16;
    __shared__ f16 As[128 * 64];
    __shared__ f16 Bs[BN * 64];
    __shared__ float ssum[BN];
    __shared__ float ssq[BN];
    int bid = blockIdx.x;
    int si = 0;
    #pragma unroll
    for (int t = 1; t < 3; t++) if (bid >= gd.s[t].tileBase) si = t;
    GemmSeg sg = gd.s[si];
    int tid = threadIdx.x;
    int wv = tid >> 6, lane = tid & 63;
    int row0 = (bid - sg.tileBase) * 128;
    int N = sg.N, K = sg.K;
    if (STATS && tid < BN){ ssum[tid] = 0.f; ssq[tid] = 0.f; }

    int rsub = lane >> 3;          // 0..7
    int seg  = lane & 7;
    int sseg = seg ^ rsub;         // inverse-swizzled global segment

    f32x4 acc[2][CF];
    #pragma unroll
    for (int rf = 0; rf < 2; rf++)
        #pragma unroll
        for (int cf = 0; cf < CF; cf++)
            acc[rf][cf] = (f32x4){0.f, 0.f, 0.f, 0.f};

    for (int k0 = 0; k0 < K; k0 += 64){
        const f16* Ab; int lda, kloc;
        if (k0 < sg.ksplit){ Ab = sg.A1; lda = sg.lda1; kloc = k0; }
        else               { Ab = sg.A2; lda = sg.lda2; kloc = k0 - sg.ksplit; }
        // A stage: 128 rows x 64 f16, 4 wave-issues of 1KB each
        #pragma unroll
        for (int p = 0; p < 4; p++){
            int r = wv * 32 + p * 8 + rsub;
            const f16* srca = Ab + (size_t)(row0 + r) * lda + kloc + sseg * 8;
            __builtin_amdgcn_global_load_lds(
                (const __attribute__((address_space(1))) void*)srca,
                (__attribute__((address_space(3))) void*)&As[(wv * 32 + p * 8) * 64],
                16, 0, 0);
        }
        // B stage: BN cols x 64 f16
        #pragma unroll
        for (int p = 0; p < BN / 32; p++){
            int c0 = wv * (BN / 4) + p * 8;
            const f16* srcb = sg.Wt + (size_t)(c0 + rsub) * K + k0 + sseg * 8;
            __builtin_amdgcn_global_load_lds(
                (const __attribute__((address_space(1))) void*)srcb,
                (__attribute__((address_space(3))) void*)&Bs[c0 * 64],
                16, 0, 0);
        }
        __syncthreads();
        #pragma unroll
        for (int kf = 0; kf < 2; kf++){
            int kidx = kf * 4 + (lane >> 4);
            int ar0 = wv * 32 + (lane & 15);
            int ar1 = ar0 + 16;
            f16x8 a0 = *reinterpret_cast<const f16x8*>(&As[ar0 * 64 + ((kidx ^ (ar0 & 7)) * 8)]);
            f16x8 a1 = *reinterpret_cast<const f16x8*>(&As[ar1 * 64 + ((kidx ^ (ar1 & 7)) * 8)]);
            #pragma unroll
            for (int cf = 0; cf < CF; cf++){
                int bc = cf * 16 + (lane & 15);
                f16x8 b = *reinterpret_cast<const f16x8*>(&Bs[bc * 64 + ((kidx ^ (bc & 7)) * 8)]);
                acc[0][cf] = __builtin_amdgcn_mfma_f32_16x16x32_f16(a0, b, acc[0][cf], 0, 0, 0);
                acc[1][cf] = __builtin_amdgcn_mfma_f32_16x16x32_f16(a1, b, acc[1][cf], 0, 0, 0);
            }
        }
        __syncthreads();
    }
    int rbase = row0 + wv * 32 + ((lane >> 4) << 2);
    #pragma unroll
    for (int cf = 0; cf < CF; cf++){
        int col = cf * 16 + (lane & 15);
        float bias = 0.f;
        if (sg.b1) bias += sg.b1[col];
        if (sg.b2) bias += sg.b2[col];
        float ls = 0.f, lq = 0.f;
        #pragma unroll
        for (int rf = 0; rf < 2; rf++){
            #pragma unroll
            for (int q = 0; q < 4; q++){
                int gr = rbase + rf * 16 + q;
                if (gr < N){
                    float v = sg.scale * (acc[rf][cf][q] + bias);
                    if (OUT16) ((f16*)sg.out)[(size_t)gr * BN + col] = (f16)v;
                    else       ((float*)sg.out)[(size_t)gr * BN + col] = v;
                    ls += v; lq += v * v;
                }
            }
        }
        if (STATS){ atomicAdd(&ssum[col], ls); atomicAdd(&ssq[col], lq); }
    }
    if (STATS){
        __syncthreads();
        if (tid < BN){
            atomicAdd(&sg.stats[tid], ssum[tid]);
            atomicAdd(&sg.stats[128 + tid], ssq[tid]);
        }
    }
}

// ================= merged BN apply + ReLU (+ residual) =================

struct BnSeg { const f16* o; const float* stats; const float* g; const float* b; f16* h; int N; float invN; int residual; int idxBase; };
struct BnDesc { BnSeg s[3]; int total; };

__global__ __launch_bounds__(256) void bnAll_k(BnDesc bd){
    int idx = blockIdx.x * 256 + threadIdx.x;
    if (idx >= bd.total) return;
    int si = 0;
    #pragma unroll
    for (int t = 1; t < 3; t++) if (idx >= bd.s[t].idxBase) si = t;
    BnSeg sg = bd.s[si];
    int l = idx - sg.idxBase;
    int n = l >> 4, c8 = (l & 15) * 8;
    union { uint4 u; f16 h[8]; } ov;
    ov.u = *reinterpret_cast<const uint4*>(sg.o + (size_t)n * 128 + c8);
    float r[8];
    #pragma unroll
    for (int j = 0; j < 8; j++){
        int c = c8 + j;
        float mu  = sg.stats[c] * sg.invN;
        float var = sg.stats[128 + c] * sg.invN - mu * mu;
        float v = ((float)ov.h[j] - mu) * rsqrtf(var + BN_EPS) * sg.g[c] + sg.b[c];
        r[j] = v > 0.f ? v : 0.f;
    }
    f16* hp = sg.h + (size_t)n * 128 + c8;
    if (sg.residual){
        uint4 old = *reinterpret_cast<const uint4*>(hp);
        union { uint4 u; f16 h[8]; } ou; ou.u = old;
        #pragma unroll
        for (int j = 0; j < 8; j++) r[j] += (float)ou.h[j];
    }
    union { uint4 u; f16 h[8]; } pk;
    #pragma unroll
    for (int j = 0; j < 8; j++) pk.h[j] = (f16)r[j];
    *reinterpret_cast<uint4*>(hp) = pk.u;
}

// ================= host orchestration =================

extern "C" void kernel_launch(void* const* d_in, const int* in_sizes, int n_in,
                              void* d_out, int out_size, void* d_ws, size_t ws_size,
                              hipStream_t stream){
    const float* x_drug = (const float*)d_in[0];
    const float* x_gene = (const float*)d_in[1];
    const float* x_dis  = (const float*)d_in[2];
    const int* srcP[6] = {(const int*)d_in[3], (const int*)d_in[5], (const int*)d_in[7],
                          (const int*)d_in[9], (const int*)d_in[11], (const int*)d_in[13]};
    const int* dstP[6] = {(const int*)d_in[4], (const int*)d_in[6], (const int*)d_in[8],
                          (const int*)d_in[10], (const int*)d_in[12], (const int*)d_in[14]};
    const int  Et[6]   = {in_sizes[3], in_sizes[5], in_sizes[7], in_sizes[9], in_sizes[11], in_sizes[13]};
    const float* W_in[3] = {(const float*)d_in[15], (const float*)d_in[17], (const float*)d_in[19]};
    const float* b_in[3] = {(const float*)d_in[16], (const float*)d_in[18], (const float*)d_in[20]};
    const float* g_in  = (const float*)d_in[21];
    const float* bt_in = (const float*)d_in[22];
    const float* Wl    = (const float*)d_in[23];
    const float* Wr    = (const float*)d_in[24];
    const float* bl    = (const float*)d_in[25];
    const float* g_conv  = (const float*)d_in[26];
    const float* bt_conv = (const float*)d_in[27];
    const float* W_fin = (const float*)d_in[28];
    const float* b_fin = (const float*)d_in[29];
    float* out = (float*)d_out;

    // edge-type metadata (order: dg, gd, gs, sg, ds, sd)
    const int Ndst_t[6]     = {NG, ND, NS, NG, NS, ND};
    const int srcT[6]       = {0, 1, 1, 2, 0, 2};
    const int dstT[6]       = {1, 0, 2, 1, 2, 0};
    const int colPair4_t[6] = {0, 0, 0, 16, 16, 16};

    const int Nn[3]  = {ND, NG, NS};
    const int Kin[3] = {256, 128, 64};
    const float* xin[3] = {x_drug, x_gene, x_dis};

    // ---- workspace carve ----
    char* base = (char*)d_ws;
    size_t off = 0;
    auto alloc = [&](size_t bytes) -> char* {
        char* p = base + off; off += (bytes + 255) & ~(size_t)255; return p;
    };
    f16* h[3];  for (int t = 0; t < 3; t++) h[t]  = (f16*)alloc((size_t)Nn[t] * 128 * 2);
    f16* A[3];  for (int t = 0; t < 3; t++) A[t]  = (f16*)alloc((size_t)Nn[t] * 256 * 2);
    f16* xb[3]; for (int t = 0; t < 3; t++) xb[t] = (f16*)alloc((size_t)Nn[t] * Kin[t] * 2);
    f16* Wint[3]; for (int t = 0; t < 3; t++) Wint[t] = (f16*)alloc((size_t)128 * Kin[t] * 2);
    f16* Wfin_t = (f16*)alloc((size_t)64 * 128 * 2);
    f16* Wcat_t = (f16*)alloc((size_t)9 * 128 * 384 * 2);
    // o pool (aliased by packed edge buffer during CSR build, which finishes first)
    char* oPool = alloc((size_t)(ND + NG + NS) * 128 * 2);
    f16* o[3];
    o[0] = (f16*)oPool; o[1] = o[0] + (size_t)ND * 128; o[2] = o[1] + (size_t)NG * 128;
    uint2* packed = (uint2*)oPool;
    float* stats = (float*)alloc(12 * 256 * 4);
    // zero pool: bucket counters + 256B zero row
    int* zeroPool = (int*)alloc((size_t)(TBUCK + 64) * 4);
    int* bCnt = zeroPool;
    const uint4* zrow = (const uint4*)(zeroPool + TBUCK);
    int* bBase   = (int*)alloc((TBUCK + 1) * 4);
    int* bCursor = (int*)alloc(TBUCK * 4);
    int *offs[6], *csr[6];
    for (int t = 0; t < 6; t++) offs[t] = (int*)alloc((size_t)(Ndst_t[t] + 1) * 4);
    for (int t = 0; t < 6; t++) csr[t]  = (int*)alloc((size_t)Et[t] * 4);

    hipMemsetAsync(zeroPool, 0, (size_t)(TBUCK + 64) * 4, stream);
    hipMemsetAsync(stats, 0, 12 * 256 * 4, stream);

    // ---- bucketed CSR build ----
    BDesc bd;
    {
        int ecum = 0;
        for (int t = 0; t < 6; t++){
            bd.src[t] = srcP[t]; bd.dst[t] = dstP[t];
            bd.Ebase[t] = ecum; ecum += Et[t];
            int sft = 0; while (((Ndst_t[t] - 1) >> sft) >= NBUCK) sft++;
            bd.shift[t] = sft;
            bd.N[t] = Ndst_t[t];
            bd.offs[t] = offs[t]; bd.csr[t] = csr[t];
        }
        bd.Ebase[6] = ecum;
        bd.bCnt = bCnt; bd.bBase = bBase; bd.bCursor = bCursor;
        bd.packed = packed;
    }
    int Etot = bd.Ebase[6];
    bhist_k<<<cdiv(Etot, PCHUNK), 256, 0, stream>>>(bd);
    bscan_k<<<1, 512, 0, stream>>>(bd);
    bpart_k<<<cdiv(Etot, PCHUNK), 256, 0, stream>>>(bd);
    bucketCsr_k<<<TBUCK, 256, 0, stream>>>(bd);

    // ---- casts + weights ----
    CastDesc cds;
    {
        int b = 0;
        for (int t = 0; t < 3; t++){
            cds.src[t] = xin[t]; cds.dst[t] = xb[t];
            cds.base[t] = b; b += Nn[t] * Kin[t] / 4;
        }
        cds.base[3] = b;
    }
    castAll_k<<<cdiv(cds.base[3], 256), 256, 0, stream>>>(cds);
    WDesc wd = {W_in[0], W_in[1], W_in[2], W_fin, Wl, Wr,
                Wint[0], Wint[1], Wint[2], Wfin_t, Wcat_t};
    weightAll_k<<<cdiv(507904, 256), 256, 0, stream>>>(wd);

    int tiles[3]; for (int t = 0; t < 3; t++) tiles[t] = cdiv(Nn[t], 128);
    int tileBase[4] = {0, tiles[0], tiles[0] + tiles[1], tiles[0] + tiles[1] + tiles[2]};

    // ---- input stage ----
    {
        GemmDesc g{};
        for (int t = 0; t < 3; t++){
            g.s[t] = {xb[t], xb[t], Wint[t], b_in[t], nullptr, o[t], stats + t * 256,
                      Kin[t], Kin[t], Kin[t], Nn[t], Kin[t], tileBase[t], 1.0f};
        }
        gemmAll_k<128, true, true><<<tileBase[3], 256, 0, stream>>>(g);
        BnDesc bnd{}; int ib = 0;
        for (int t = 0; t < 3; t++){
            bnd.s[t] = {o[t], stats + t * 256, g_in + t * 128, bt_in + t * 128, h[t],
                        Nn[t], 1.0f / Nn[t], 0, ib};
            ib += Nn[t] * 16;
        }
        bnd.total = ib;
        bnAll_k<<<cdiv(ib, 256), 256, 0, stream>>>(bnd);
    }

    // ---- 3 conv layers ----
    const int e1s[3] = {1, 0, 2}, e2s[3] = {5, 3, 4};
    for (int L = 0; L < 3; L++){
        GDesc gd; int bacc = 0;
        gd.zrow = zrow;
        for (int t = 0; t < 6; t++){
            gd.s[t].offs = offs[t];
            gd.s[t].csr  = csr[t];
            gd.s[t].h    = (const uint4*)h[srcT[t]];
            gd.s[t].A    = (uint4*)A[dstT[t]];
            gd.s[t].colPair4 = colPair4_t[t];
            gd.s[t].N    = Ndst_t[t];
            gd.s[t].base = bacc;
            bacc += cdiv(Ndst_t[t], 4);
        }
        gatherall_k<<<bacc, 256, 0, stream>>>(gd);
        GemmDesc g{};
        for (int t = 0; t < 3; t++){
            int e1 = e1s[t], e2 = e2s[t];
            g.s[t] = {A[t], h[t], Wcat_t + (size_t)(L * 3 + t) * 128 * 384,
                      bl + (size_t)(L * 6 + e1) * 128, bl + (size_t)(L * 6 + e2) * 128,
                      o[t], stats + (size_t)(3 + L * 3 + t) * 256,
                      256, 128, 256, Nn[t], 384, tileBase[t], 0.5f};
        }
        gemmAll_k<128, true, true><<<tileBase[3], 256, 0, stream>>>(g);
        BnDesc bnd{}; int ib = 0;
        for (int t = 0; t < 3; t++){
            bnd.s[t] = {o[t], stats + (size_t)(3 + L * 3 + t) * 256,
                        g_conv + (size_t)(L * 3 + t) * 128, bt_conv + (size_t)(L * 3 + t) * 128,
                        h[t], Nn[t], 1.0f / Nn[t], 1, ib};
            ib += Nn[t] * 16;
        }
        bnd.total = ib;
        bnAll_k<<<cdiv(ib, 256), 256, 0, stream>>>(bnd);
    }

    // ---- final projection: one GEMM over contiguous h pool ----
    {
        int Ntot = ND + NG + NS;
        GemmDesc g{};
        g.s[0] = {h[0], h[0], Wfin_t, b_fin, nullptr, out, nullptr,
                  128, 128, 128, Ntot, 128, 0, 1.0f};
        g.s[1] = g.s[0]; g.s[1].tileBase = 0x3FFFFFFF; g.s[1].N = 0;
        g.s[2] = g.s[1];
        gemmAll_k<64, false, false><<<cdiv(Ntot, 128), 256, 0, stream>>>(g);
    }
}

// Round 9
// 556.067 us; speedup vs baseline: 4.7560x; 1.1011x over previous
//
#include <hip/hip_runtime.h>
#include <cstddef>
#include <cstdint>

typedef _Float16 f16;
typedef _Float16 f16x8 __attribute__((ext_vector_type(8)));
typedef float f32x4 __attribute__((ext_vector_type(4)));

constexpr int ND = 30000, NG = 60000, NS = 15000;
constexpr float BN_EPS = 1e-5f;
constexpr int NBUCK = 64;      // buckets per edge type
constexpr int TBUCK = 6 * NBUCK;
constexpr int PCHUNK = 4096;   // edges per partition block

static inline int cdiv(int a, int b){ return (a + b - 1) / b; }

// ================= bucketed CSR construction =================

struct BDesc {
    const int* src[6]; const int* dst[6];
    int Ebase[7]; int shift[6]; int N[6];
    int* bCnt; int* bBase; int* bCursor;
    uint2* packed;
    int* offs[6]; int* csr[6];
};

__global__ __launch_bounds__(256) void bhist_k(BDesc bd){
    __shared__ int hist[TBUCK];
    int tid = threadIdx.x;
    for (int i = tid; i < TBUCK; i += 256) hist[i] = 0;
    __syncthreads();
    int Etot = bd.Ebase[6];
    #pragma unroll
    for (int u = 0; u < 16; u++){
        int e = blockIdx.x * PCHUNK + u * 256 + tid;
        if (e < Etot){
            int t = 0;
            #pragma unroll
            for (int i = 1; i < 6; i++) if (e >= bd.Ebase[i]) t = i;
            int d = bd.dst[t][e - bd.Ebase[t]];
            atomicAdd(&hist[t * NBUCK + (d >> bd.shift[t])], 1);
        }
    }
    __syncthreads();
    for (int i = tid; i < TBUCK; i += 256)
        if (hist[i]) atomicAdd(&bd.bCnt[i], hist[i]);
}

__global__ __launch_bounds__(512) void bscan_k(BDesc bd){
    __shared__ int sh[TBUCK];
    int tid = threadIdx.x;
    int my = (tid < TBUCK) ? bd.bCnt[tid] : 0;
    if (tid < TBUCK) sh[tid] = my;
    __syncthreads();
    for (int d = 1; d < TBUCK; d <<= 1){
        int v = (tid < TBUCK) ? sh[tid] : 0;
        int add = (tid >= d && tid < TBUCK) ? sh[tid - d] : 0;
        __syncthreads();
        if (tid < TBUCK) sh[tid] = v + add;
        __syncthreads();
    }
    if (tid < TBUCK){
        int excl = sh[tid] - my;
        bd.bBase[tid] = excl;
        bd.bCursor[tid] = excl;
    }
    if (tid == 0) bd.bBase[TBUCK] = sh[TBUCK - 1];
}

__global__ __launch_bounds__(256) void bpart_k(BDesc bd){
    __shared__ int hist[TBUCK];
    __shared__ int basesh[TBUCK];
    int tid = threadIdx.x;
    for (int i = tid; i < TBUCK; i += 256) hist[i] = 0;
    __syncthreads();
    int Etot = bd.Ebase[6];
    int mb[16], mr[16], ms[16], md[16];
    #pragma unroll
    for (int u = 0; u < 16; u++){
        int e = blockIdx.x * PCHUNK + u * 256 + tid;
        mb[u] = -1;
        if (e < Etot){
            int t = 0;
            #pragma unroll
            for (int i = 1; i < 6; i++) if (e >= bd.Ebase[i]) t = i;
            int le = e - bd.Ebase[t];
            int s = bd.src[t][le], d = bd.dst[t][le];
            int b = t * NBUCK + (d >> bd.shift[t]);
            mr[u] = atomicAdd(&hist[b], 1);
            mb[u] = b; ms[u] = s; md[u] = d;
        }
    }
    __syncthreads();
    for (int i = tid; i < TBUCK; i += 256)
        basesh[i] = hist[i] ? atomicAdd(&bd.bCursor[i], hist[i]) : 0;
    __syncthreads();
    #pragma unroll
    for (int u = 0; u < 16; u++){
        if (mb[u] >= 0){
            int pos = basesh[mb[u]] + mr[u];
            bd.packed[pos] = make_uint2((unsigned)ms[u], (unsigned)md[u]);
        }
    }
}

// one block per bucket: count -> scan -> offs -> fill (all LDS-local)
__global__ __launch_bounds__(256) void bucketCsr_k(BDesc bd){
    __shared__ int cnt[1024];
    __shared__ int sh[256];
    int b = blockIdx.x;
    int t = b >> 6;          // /NBUCK
    int bb = b & 63;
    int tid = threadIdx.x;
    int shift = bd.shift[t];
    int nodeBase = bb << shift;
    int Nt = bd.N[t];
    int span = 1 << shift;   // <= 1024
    int tbase = bd.bBase[t * NBUCK];
    int eBeg = bd.bBase[b], eEnd = bd.bBase[b + 1];
    int bLocal = eBeg - tbase;
    #pragma unroll
    for (int i = 0; i < 4; i++) cnt[tid + i * 256] = 0;
    __syncthreads();
    for (int e = eBeg + tid; e < eEnd; e += 256)
        atomicAdd(&cnt[(int)bd.packed[e].y - nodeBase], 1);
    __syncthreads();
    int c0 = cnt[tid * 4], c1 = cnt[tid * 4 + 1], c2 = cnt[tid * 4 + 2], c3 = cnt[tid * 4 + 3];
    int s = c0 + c1 + c2 + c3;
    sh[tid] = s;
    __syncthreads();
    for (int d = 1; d < 256; d <<= 1){
        int v = sh[tid];
        int add = (tid >= d) ? sh[tid - d] : 0;
        __syncthreads();
        sh[tid] = v + add;
        __syncthreads();
    }
    int run = sh[tid] - s;
    int idx = tid * 4;
    int ex0 = run, ex1 = run + c0, ex2 = ex1 + c1, ex3 = ex2 + c2;
    if (idx     < span && nodeBase + idx     < Nt) bd.offs[t][nodeBase + idx]     = bLocal + ex0;
    if (idx + 1 < span && nodeBase + idx + 1 < Nt) bd.offs[t][nodeBase + idx + 1] = bLocal + ex1;
    if (idx + 2 < span && nodeBase + idx + 2 < Nt) bd.offs[t][nodeBase + idx + 2] = bLocal + ex2;
    if (idx + 3 < span && nodeBase + idx + 3 < Nt) bd.offs[t][nodeBase + idx + 3] = bLocal + ex3;
    cnt[idx] = ex0; cnt[idx + 1] = ex1; cnt[idx + 2] = ex2; cnt[idx + 3] = ex3;
    __syncthreads();
    for (int e = eBeg + tid; e < eEnd; e += 256){
        uint2 p = bd.packed[e];
        int lpos = atomicAdd(&cnt[(int)p.y - nodeBase], 1);
        bd.csr[t][bLocal + lpos] = (int)p.x;
    }
    if (bb == NBUCK - 1 && tid == 0)
        bd.offs[t][Nt] = bd.bBase[(t + 1) * NBUCK] - tbase;
}

// ================= prep: casts + weight transposes =================

struct CastDesc { const float* src[3]; f16* dst[3]; int base[4]; };

__global__ __launch_bounds__(256) void castAll_k(CastDesc cdsc){
    int idx = blockIdx.x * 256 + threadIdx.x;
    if (idx >= cdsc.base[3]) return;
    int t = 0;
    #pragma unroll
    for (int i = 1; i < 3; i++) if (idx >= cdsc.base[i]) t = i;
    int i4 = (idx - cdsc.base[t]) * 4;
    float4 v = *reinterpret_cast<const float4*>(cdsc.src[t] + i4);
    union { uint2 u; f16 h[4]; } o;
    o.h[0] = (f16)v.x; o.h[1] = (f16)v.y; o.h[2] = (f16)v.z; o.h[3] = (f16)v.w;
    *reinterpret_cast<uint2*>(cdsc.dst[t] + i4) = o.u;
}

struct WDesc {
    const float* W_in0; const float* W_in1; const float* W_in2;
    const float* W_fin; const float* Wl; const float* Wr;
    f16* Wint0; f16* Wint1; f16* Wint2; f16* Wfin_t; f16* Wcat_t;
};

__global__ __launch_bounds__(256) void weightAll_k(WDesc wd){
    int idx = blockIdx.x * 256 + threadIdx.x;
    if (idx < 32768){
        int c = idx >> 8, k = idx & 255;
        wd.Wint0[idx] = (f16)wd.W_in0[k * 128 + c];
    } else if (idx < 49152){
        int l = idx - 32768; int c = l >> 7, k = l & 127;
        wd.Wint1[l] = (f16)wd.W_in1[k * 128 + c];
    } else if (idx < 57344){
        int l = idx - 49152; int c = l >> 6, k = l & 63;
        wd.Wint2[l] = (f16)wd.W_in2[k * 128 + c];
    } else if (idx < 65536){
        int l = idx - 57344; int c = l >> 7, k = l & 127;
        wd.Wfin_t[l] = (f16)wd.W_fin[k * 64 + c];
    } else if (idx < 507904){
        int l = idx - 65536;
        int g = l / (384 * 128);
        int rem = l - g * (384 * 128);
        int c = rem / 384;
        int k = rem - c * 384;
        int L = g / 3, t = g - L * 3;
        const int e1s[3] = {1, 0, 2}, e2s[3] = {5, 3, 4};
        int e1 = e1s[t], e2 = e2s[t];
        float v;
        if (k < 128)      v = wd.Wl[(((size_t)L * 6 + e1) * 128 + k) * 128 + c];
        else if (k < 256) v = wd.Wl[(((size_t)L * 6 + e2) * 128 + (k - 128)) * 128 + c];
        else {
            int kr = k - 256;
            v = wd.Wr[(((size_t)L * 6 + e1) * 128 + kr) * 128 + c]
              + wd.Wr[(((size_t)L * 6 + e2) * 128 + kr) * 128 + c];
        }
        wd.Wcat_t[l] = (f16)v;
    }
}

// ================= fused gather-mean: 16-lane group per node, 8 rows in flight =================
// Group (16 lanes) owns one node; lane li reads 16B segment li of each neighbor row.
// 8-slot batches; invalid slots read the L1-resident zero row. No cross-lane reduce.

struct GSeg { const int* offs; const int* csr; const uint4* h; uint4* A; int colPair4; int N; int base; };
struct GDesc { GSeg s[6]; const uint4* zrow; };

__device__ __forceinline__ f16x8 as_h8(uint4 v){
    union { uint4 u; f16x8 h; } c; c.u = v; return c.h;
}

__global__ __launch_bounds__(256) void gatherall_k(GDesc gd){
    int bid = blockIdx.x;
    int si = 0;
    #pragma unroll
    for (int t = 1; t < 6; t++) if (bid >= gd.s[t].base) si = t;
    GSeg sg = gd.s[si];
    int node = (bid - sg.base) * 16 + (threadIdx.x >> 4);
    if (node >= sg.N) return;
    int li = threadIdx.x & 15;
    int s = sg.offs[node], e = sg.offs[node + 1];
    const int* cp = sg.csr;
    const uint4* hp = sg.h;
    const uint4* zr = gd.zrow;
    f16x8 a = {};
    for (int j = s; j < e; j += 8){
        const uint4* p0 = (j + 0 < e) ? (hp + (size_t)cp[j + 0] * 16) : zr;
        const uint4* p1 = (j + 1 < e) ? (hp + (size_t)cp[j + 1] * 16) : zr;
        const uint4* p2 = (j + 2 < e) ? (hp + (size_t)cp[j + 2] * 16) : zr;
        const uint4* p3 = (j + 3 < e) ? (hp + (size_t)cp[j + 3] * 16) : zr;
        const uint4* p4 = (j + 4 < e) ? (hp + (size_t)cp[j + 4] * 16) : zr;
        const uint4* p5 = (j + 5 < e) ? (hp + (size_t)cp[j + 5] * 16) : zr;
        const uint4* p6 = (j + 6 < e) ? (hp + (size_t)cp[j + 6] * 16) : zr;
        const uint4* p7 = (j + 7 < e) ? (hp + (size_t)cp[j + 7] * 16) : zr;
        uint4 v0 = p0[li], v1 = p1[li], v2 = p2[li], v3 = p3[li];
        uint4 v4 = p4[li], v5 = p5[li], v6 = p6[li], v7 = p7[li];
        a = a + as_h8(v0); a = a + as_h8(v1); a = a + as_h8(v2); a = a + as_h8(v3);
        a = a + as_h8(v4); a = a + as_h8(v5); a = a + as_h8(v6); a = a + as_h8(v7);
    }
    float inv = (e > s) ? 1.0f / (float)(e - s) : 0.f;
    union { uint4 u; f16 h[8]; } pk;
    #pragma unroll
    for (int i = 0; i < 8; i++) pk.h[i] = (f16)((float)a[i] * inv);
    sg.A[(size_t)node * 32 + sg.colPair4 + li] = pk.u;
}

// ================= merged MFMA fp16 GEMM: global_load_lds + XOR swizzle =================

struct GemmSeg {
    const f16* A1; const f16* A2; const f16* Wt;
    const float* b1; const float* b2; void* out; float* stats;
    int lda1, lda2, ksplit, N, K, tileBase; float scale;
};
struct GemmDesc { GemmSeg s[3]; };

template<int BN, bool STATS, bool OUT16>
__global__ __launch_bounds__(256) void gemmAll_k(GemmDesc gd){
    constexpr int CF = BN / 16;
    __shared__ f16 As[128 * 64];
    __shared__ f16 Bs[BN * 64];
    __shared__ float ssum[BN];
    __shared__ float ssq[BN];
    int bid = blockIdx.x;
    int si = 0;
    #pragma unroll
    for (int t = 1; t < 3; t++) if (bid >= gd.s[t].tileBase) si = t;
    GemmSeg sg = gd.s[si];
    int tid = threadIdx.x;
    int wv = tid >> 6, lane = tid & 63;
    int row0 = (bid - sg.tileBase) * 128;
    int N = sg.N, K = sg.K;
    if (STATS && tid < BN){ ssum[tid] = 0.f; ssq[tid] = 0.f; }

    int rsub = lane >> 3;          // 0..7
    int seg  = lane & 7;
    int sseg = seg ^ rsub;         // inverse-swizzled global segment

    f32x4 acc[2][CF];
    #pragma unroll
    for (int rf = 0; rf < 2; rf++)
        #pragma unroll
        for (int cf = 0; cf < CF; cf++)
            acc[rf][cf] = (f32x4){0.f, 0.f, 0.f, 0.f};

    for (int k0 = 0; k0 < K; k0 += 64){
        const f16* Ab; int lda, kloc;
        if (k0 < sg.ksplit){ Ab = sg.A1; lda = sg.lda1; kloc = k0; }
        else               { Ab = sg.A2; lda = sg.lda2; kloc = k0 - sg.ksplit; }
        #pragma unroll
        for (int p = 0; p < 4; p++){
            int r = wv * 32 + p * 8 + rsub;
            const f16* srca = Ab + (size_t)(row0 + r) * lda + kloc + sseg * 8;
            __builtin_amdgcn_global_load_lds(
                (const __attribute__((address_space(1))) void*)srca,
                (__attribute__((address_space(3))) void*)&As[(wv * 32 + p * 8) * 64],
                16, 0, 0);
        }
        #pragma unroll
        for (int p = 0; p < BN / 32; p++){
            int c0 = wv * (BN / 4) + p * 8;
            const f16* srcb = sg.Wt + (size_t)(c0 + rsub) * K + k0 + sseg * 8;
            __builtin_amdgcn_global_load_lds(
                (const __attribute__((address_space(1))) void*)srcb,
                (__attribute__((address_space(3))) void*)&Bs[c0 * 64],
                16, 0, 0);
        }
        __syncthreads();
        #pragma unroll
        for (int kf = 0; kf < 2; kf++){
            int kidx = kf * 4 + (lane >> 4);
            int ar0 = wv * 32 + (lane & 15);
            int ar1 = ar0 + 16;
            f16x8 a0 = *reinterpret_cast<const f16x8*>(&As[ar0 * 64 + ((kidx ^ (ar0 & 7)) * 8)]);
            f16x8 a1 = *reinterpret_cast<const f16x8*>(&As[ar1 * 64 + ((kidx ^ (ar1 & 7)) * 8)]);
            #pragma unroll
            for (int cf = 0; cf < CF; cf++){
                int bc = cf * 16 + (lane & 15);
                f16x8 b = *reinterpret_cast<const f16x8*>(&Bs[bc * 64 + ((kidx ^ (bc & 7)) * 8)]);
                acc[0][cf] = __builtin_amdgcn_mfma_f32_16x16x32_f16(a0, b, acc[0][cf], 0, 0, 0);
                acc[1][cf] = __builtin_amdgcn_mfma_f32_16x16x32_f16(a1, b, acc[1][cf], 0, 0, 0);
            }
        }
        __syncthreads();
    }
    int rbase = row0 + wv * 32 + ((lane >> 4) << 2);
    #pragma unroll
    for (int cf = 0; cf < CF; cf++){
        int col = cf * 16 + (lane & 15);
        float bias = 0.f;
        if (sg.b1) bias += sg.b1[col];
        if (sg.b2) bias += sg.b2[col];
        float ls = 0.f, lq = 0.f;
        #pragma unroll
        for (int rf = 0; rf < 2; rf++){
            #pragma unroll
            for (int q = 0; q < 4; q++){
                int gr = rbase + rf * 16 + q;
                if (gr < N){
                    float v = sg.scale * (acc[rf][cf][q] + bias);
                    if (OUT16) ((f16*)sg.out)[(size_t)gr * BN + col] = (f16)v;
                    else       ((float*)sg.out)[(size_t)gr * BN + col] = v;
                    ls += v; lq += v * v;
                }
            }
        }
        if (STATS){ atomicAdd(&ssum[col], ls); atomicAdd(&ssq[col], lq); }
    }
    if (STATS){
        __syncthreads();
        if (tid < BN){
            atomicAdd(&sg.stats[tid], ssum[tid]);
            atomicAdd(&sg.stats[128 + tid], ssq[tid]);
        }
    }
}

// ================= merged BN apply + ReLU (+ residual) =================

struct BnSeg { const f16* o; const float* stats; const float* g; const float* b; f16* h; int N; float invN; int residual; int idxBase; };
struct BnDesc { BnSeg s[3]; int total; };

__global__ __launch_bounds__(256) void bnAll_k(BnDesc bd){
    int idx = blockIdx.x * 256 + threadIdx.x;
    if (idx >= bd.total) return;
    int si = 0;
    #pragma unroll
    for (int t = 1; t < 3; t++) if (idx >= bd.s[t].idxBase) si = t;
    BnSeg sg = bd.s[si];
    int l = idx - sg.idxBase;
    int n = l >> 4, c8 = (l & 15) * 8;
    union { uint4 u; f16 h[8]; } ov;
    ov.u = *reinterpret_cast<const uint4*>(sg.o + (size_t)n * 128 + c8);
    float r[8];
    #pragma unroll
    for (int j = 0; j < 8; j++){
        int c = c8 + j;
        float mu  = sg.stats[c] * sg.invN;
        float var = sg.stats[128 + c] * sg.invN - mu * mu;
        float v = ((float)ov.h[j] - mu) * rsqrtf(var + BN_EPS) * sg.g[c] + sg.b[c];
        r[j] = v > 0.f ? v : 0.f;
    }
    f16* hp = sg.h + (size_t)n * 128 + c8;
    if (sg.residual){
        uint4 old = *reinterpret_cast<const uint4*>(hp);
        union { uint4 u; f16 h[8]; } ou; ou.u = old;
        #pragma unroll
        for (int j = 0; j < 8; j++) r[j] += (float)ou.h[j];
    }
    union { uint4 u; f16 h[8]; } pk;
    #pragma unroll
    for (int j = 0; j < 8; j++) pk.h[j] = (f16)r[j];
    *reinterpret_cast<uint4*>(hp) = pk.u;
}

// ================= host orchestration =================

extern "C" void kernel_launch(void* const* d_in, const int* in_sizes, int n_in,
                              void* d_out, int out_size, void* d_ws, size_t ws_size,
                              hipStream_t stream){
    const float* x_drug = (const float*)d_in[0];
    const float* x_gene = (const float*)d_in[1];
    const float* x_dis  = (const float*)d_in[2];
    const int* srcP[6] = {(const int*)d_in[3], (const int*)d_in[5], (const int*)d_in[7],
                          (const int*)d_in[9], (const int*)d_in[11], (const int*)d_in[13]};
    const int* dstP[6] = {(const int*)d_in[4], (const int*)d_in[6], (const int*)d_in[8],
                          (const int*)d_in[10], (const int*)d_in[12], (const int*)d_in[14]};
    const int  Et[6]   = {in_sizes[3], in_sizes[5], in_sizes[7], in_sizes[9], in_sizes[11], in_sizes[13]};
    const float* W_in[3] = {(const float*)d_in[15], (const float*)d_in[17], (const float*)d_in[19]};
    const float* b_in[3] = {(const float*)d_in[16], (const float*)d_in[18], (const float*)d_in[20]};
    const float* g_in  = (const float*)d_in[21];
    const float* bt_in = (const float*)d_in[22];
    const float* Wl    = (const float*)d_in[23];
    const float* Wr    = (const float*)d_in[24];
    const float* bl    = (const float*)d_in[25];
    const float* g_conv  = (const float*)d_in[26];
    const float* bt_conv = (const float*)d_in[27];
    const float* W_fin = (const float*)d_in[28];
    const float* b_fin = (const float*)d_in[29];
    float* out = (float*)d_out;

    // edge-type metadata (order: dg, gd, gs, sg, ds, sd)
    const int Ndst_t[6]     = {NG, ND, NS, NG, NS, ND};
    const int srcT[6]       = {0, 1, 1, 2, 0, 2};
    const int dstT[6]       = {1, 0, 2, 1, 2, 0};
    const int colPair4_t[6] = {0, 0, 0, 16, 16, 16};

    const int Nn[3]  = {ND, NG, NS};
    const int Kin[3] = {256, 128, 64};
    const float* xin[3] = {x_drug, x_gene, x_dis};

    // ---- workspace carve ----
    char* base = (char*)d_ws;
    size_t off = 0;
    auto alloc = [&](size_t bytes) -> char* {
        char* p = base + off; off += (bytes + 255) & ~(size_t)255; return p;
    };
    f16* h[3];  for (int t = 0; t < 3; t++) h[t]  = (f16*)alloc((size_t)Nn[t] * 128 * 2);
    f16* A[3];  for (int t = 0; t < 3; t++) A[t]  = (f16*)alloc((size_t)Nn[t] * 256 * 2);
    f16* xb[3]; for (int t = 0; t < 3; t++) xb[t] = (f16*)alloc((size_t)Nn[t] * Kin[t] * 2);
    f16* Wint[3]; for (int t = 0; t < 3; t++) Wint[t] = (f16*)alloc((size_t)128 * Kin[t] * 2);
    f16* Wfin_t = (f16*)alloc((size_t)64 * 128 * 2);
    f16* Wcat_t = (f16*)alloc((size_t)9 * 128 * 384 * 2);
    // o pool (aliased by packed edge buffer during CSR build, which finishes first)
    char* oPool = alloc((size_t)(ND + NG + NS) * 128 * 2);
    f16* o[3];
    o[0] = (f16*)oPool; o[1] = o[0] + (size_t)ND * 128; o[2] = o[1] + (size_t)NG * 128;
    uint2* packed = (uint2*)oPool;
    float* stats = (float*)alloc(12 * 256 * 4);
    // zero pool: bucket counters + 256B zero row
    int* zeroPool = (int*)alloc((size_t)(TBUCK + 64) * 4);
    int* bCnt = zeroPool;
    const uint4* zrow = (const uint4*)(zeroPool + TBUCK);
    int* bBase   = (int*)alloc((TBUCK + 1) * 4);
    int* bCursor = (int*)alloc(TBUCK * 4);
    int *offs[6], *csr[6];
    for (int t = 0; t < 6; t++) offs[t] = (int*)alloc((size_t)(Ndst_t[t] + 1) * 4);
    for (int t = 0; t < 6; t++) csr[t]  = (int*)alloc((size_t)Et[t] * 4);

    hipMemsetAsync(zeroPool, 0, (size_t)(TBUCK + 64) * 4, stream);
    hipMemsetAsync(stats, 0, 12 * 256 * 4, stream);

    // ---- bucketed CSR build ----
    BDesc bd;
    {
        int ecum = 0;
        for (int t = 0; t < 6; t++){
            bd.src[t] = srcP[t]; bd.dst[t] = dstP[t];
            bd.Ebase[t] = ecum; ecum += Et[t];
            int sft = 0; while (((Ndst_t[t] - 1) >> sft) >= NBUCK) sft++;
            bd.shift[t] = sft;
            bd.N[t] = Ndst_t[t];
            bd.offs[t] = offs[t]; bd.csr[t] = csr[t];
        }
        bd.Ebase[6] = ecum;
        bd.bCnt = bCnt; bd.bBase = bBase; bd.bCursor = bCursor;
        bd.packed = packed;
    }
    int Etot = bd.Ebase[6];
    bhist_k<<<cdiv(Etot, PCHUNK), 256, 0, stream>>>(bd);
    bscan_k<<<1, 512, 0, stream>>>(bd);
    bpart_k<<<cdiv(Etot, PCHUNK), 256, 0, stream>>>(bd);
    bucketCsr_k<<<TBUCK, 256, 0, stream>>>(bd);

    // ---- casts + weights ----
    CastDesc cds;
    {
        int b = 0;
        for (int t = 0; t < 3; t++){
            cds.src[t] = xin[t]; cds.dst[t] = xb[t];
            cds.base[t] = b; b += Nn[t] * Kin[t] / 4;
        }
        cds.base[3] = b;
    }
    castAll_k<<<cdiv(cds.base[3], 256), 256, 0, stream>>>(cds);
    WDesc wd = {W_in[0], W_in[1], W_in[2], W_fin, Wl, Wr,
                Wint[0], Wint[1], Wint[2], Wfin_t, Wcat_t};
    weightAll_k<<<cdiv(507904, 256), 256, 0, stream>>>(wd);

    int tiles[3]; for (int t = 0; t < 3; t++) tiles[t] = cdiv(Nn[t], 128);
    int tileBase[4] = {0, tiles[0], tiles[0] + tiles[1], tiles[0] + tiles[1] + tiles[2]};

    // ---- input stage ----
    {
        GemmDesc g{};
        for (int t = 0; t < 3; t++){
            g.s[t] = {xb[t], xb[t], Wint[t], b_in[t], nullptr, o[t], stats + t * 256,
                      Kin[t], Kin[t], Kin[t], Nn[t], Kin[t], tileBase[t], 1.0f};
        }
        gemmAll_k<128, true, true><<<tileBase[3], 256, 0, stream>>>(g);
        BnDesc bnd{}; int ib = 0;
        for (int t = 0; t < 3; t++){
            bnd.s[t] = {o[t], stats + t * 256, g_in + t * 128, bt_in + t * 128, h[t],
                        Nn[t], 1.0f / Nn[t], 0, ib};
            ib += Nn[t] * 16;
        }
        bnd.total = ib;
        bnAll_k<<<cdiv(ib, 256), 256, 0, stream>>>(bnd);
    }

    // ---- 3 conv layers ----
    const int e1s[3] = {1, 0, 2}, e2s[3] = {5, 3, 4};
    for (int L = 0; L < 3; L++){
        GDesc gd; int bacc = 0;
        gd.zrow = zrow;
        for (int t = 0; t < 6; t++){
            gd.s[t].offs = offs[t];
            gd.s[t].csr  = csr[t];
            gd.s[t].h    = (const uint4*)h[srcT[t]];
            gd.s[t].A    = (uint4*)A[dstT[t]];
            gd.s[t].colPair4 = colPair4_t[t];
            gd.s[t].N    = Ndst_t[t];
            gd.s[t].base = bacc;
            bacc += cdiv(Ndst_t[t], 16);
        }
        gatherall_k<<<bacc, 256, 0, stream>>>(gd);
        GemmDesc g{};
        for (int t = 0; t < 3; t++){
            int e1 = e1s[t], e2 = e2s[t];
            g.s[t] = {A[t], h[t], Wcat_t + (size_t)(L * 3 + t) * 128 * 384,
                      bl + (size_t)(L * 6 + e1) * 128, bl + (size_t)(L * 6 + e2) * 128,
                      o[t], stats + (size_t)(3 + L * 3 + t) * 256,
                      256, 128, 256, Nn[t], 384, tileBase[t], 0.5f};
        }
        gemmAll_k<128, true, true><<<tileBase[3], 256, 0, stream>>>(g);
        BnDesc bnd{}; int ib = 0;
        for (int t = 0; t < 3; t++){
            bnd.s[t] = {o[t], stats + (size_t)(3 + L * 3 + t) * 256,
                        g_conv + (size_t)(L * 3 + t) * 128, bt_conv + (size_t)(L * 3 + t) * 128,
                        h[t], Nn[t], 1.0f / Nn[t], 1, ib};
            ib += Nn[t] * 16;
        }
        bnd.total = ib;
        bnAll_k<<<cdiv(ib, 256), 256, 0, stream>>>(bnd);
    }

    // ---- final projection: one GEMM over contiguous h pool ----
    {
        int Ntot = ND + NG + NS;
        GemmDesc g{};
        g.s[0] = {h[0], h[0], Wfin_t, b_fin, nullptr, out, nullptr,
                  128, 128, 128, Ntot, 128, 0, 1.0f};
        g.s[1] = g.s[0]; g.s[1].tileBase = 0x3FFFFFFF; g.s[1].N = 0;
        g.s[2] = g.s[1];
        gemmAll_k<64, false, false><<<cdiv(Ntot, 128), 256, 0, stream>>>(g);
    }
}